// Round 1
// baseline (845.734 us; speedup 1.0000x reference)
//
#include <hip/hip_runtime.h>
#include <hip/hip_bf16.h>
#include <math.h>

// Problem constants
#define BB 2
#define NN 2048
#define CC 128
#define HH 4
#define HD 32
#define C4 32
#define KK_TOP 1365   // int(2048/3*2)

__device__ inline float wave_max_f(float v) {
    #pragma unroll
    for (int m = 1; m < 64; m <<= 1) v = fmaxf(v, __shfl_xor(v, m));
    return v;
}
__device__ inline float wave_sum_f(float v) {
    #pragma unroll
    for (int m = 1; m < 64; m <<= 1) v += __shfl_xor(v, m);
    return v;
}
__device__ inline int wave_sum_i(int v) {
    #pragma unroll
    for (int m = 1; m < 64; m <<= 1) v += __shfl_xor(v, m);
    return v;
}

// ---------------------------------------------------------------------------
// Generic 128-K GEMM: out = X[M,128] @ W[NC,128]^T, various epilogues.
// BM=64 rows, BN=32 cols per block, 256 threads, thread tile 4x2.
// ---------------------------------------------------------------------------
enum { MODE_QKV = 0, MODE_PROJ = 1, MODE_QG = 2, MODE_KG = 3, MODE_SUP = 4 };

template <int MODE>
__global__ __launch_bounds__(256) void gemm128_k(
    const float* __restrict__ X, const float* __restrict__ W0,
    const float* __restrict__ W1, const float* __restrict__ bias,
    const float* __restrict__ resid, float* __restrict__ out0,
    float* __restrict__ out1, float* __restrict__ out2)
{
    __shared__ __align__(16) float Xs[64][132];
    __shared__ __align__(16) float Ws[32][132];
    const int tid = threadIdx.x;
    const int m0 = blockIdx.x * 64;
    const int n0 = blockIdx.y * 32;

    #pragma unroll
    for (int i = 0; i < 32; ++i) {
        int idx = tid + i * 256;
        int row = idx >> 7, col = idx & 127;
        Xs[row][col] = X[(size_t)(m0 + row) * 128 + col];
    }
    #pragma unroll
    for (int i = 0; i < 16; ++i) {
        int idx = tid + i * 256;
        int r = idx >> 7, col = idx & 127;
        int gr = n0 + r;
        const float* wp;
        if (MODE == MODE_QKV)
            wp = (gr < 128) ? (W0 + (size_t)gr * 128) : (W1 + (size_t)(gr - 128) * 128);
        else
            wp = W0 + (size_t)gr * 128;
        Ws[r][col] = wp[col];
    }
    __syncthreads();

    const int r = tid >> 4;   // 0..15
    const int c = tid & 15;   // 0..15
    float acc[4][2] = {{0.f, 0.f}, {0.f, 0.f}, {0.f, 0.f}, {0.f, 0.f}};

    #pragma unroll
    for (int k = 0; k < 128; k += 4) {
        float4 w0 = *(const float4*)&Ws[c][k];
        float4 w1 = *(const float4*)&Ws[c + 16][k];
        #pragma unroll
        for (int i = 0; i < 4; ++i) {
            float4 xv = *(const float4*)&Xs[r + 16 * i][k];
            acc[i][0] += xv.x * w0.x + xv.y * w0.y + xv.z * w0.z + xv.w * w0.w;
            acc[i][1] += xv.x * w1.x + xv.y * w1.y + xv.z * w1.z + xv.w * w1.w;
        }
    }

    #pragma unroll
    for (int i = 0; i < 4; ++i) {
        int m = m0 + r + 16 * i;
        int b = m >> 11, n = m & 2047;
        #pragma unroll
        for (int jj = 0; jj < 2; ++jj) {
            int ccol = n0 + c + 16 * jj;
            float v = acc[i][jj];
            if (MODE == MODE_QKV) {
                if (ccol < 128) {
                    int hh = ccol >> 5, d = ccol & 31;
                    out0[((size_t)(b * 4 + hh) * 2048 + n) * 32 + d] = v;           // Q [b,h,n,d]
                } else if (ccol < 256) {
                    int c2 = ccol - 128; int hh = c2 >> 5, d = c2 & 31;
                    out1[((size_t)(b * 4 + hh) * 32 + d) * 2048 + n] = v;           // Kt [b,h,d,n]
                } else {
                    int c2 = ccol - 256; int hh = c2 >> 5, d = c2 & 31;
                    out2[((size_t)(b * 4 + hh) * 2048 + n) * 32 + d] = v;           // V [b,h,n,d]
                }
            } else if (MODE == MODE_PROJ) {
                out0[(size_t)m * 128 + ccol] = v + bias[ccol] + resid[(size_t)m * 128 + ccol];
            } else if (MODE == MODE_QG) {
                out0[((size_t)b * 32 + ccol) * 2048 + n] = v + bias[ccol];          // QgT [b,o,n]
            } else if (MODE == MODE_KG) {
                out0[(size_t)m * 32 + ccol] = v + bias[ccol];                        // Kg [b,n,o]
            } else { // MODE_SUP
                out0[(size_t)m * 128 + ccol] = v + bias[ccol];                       // support
            }
        }
    }
}

// ---------------------------------------------------------------------------
// Attention: per block = one (b,h), 4 query rows, full 2048 keys in LDS.
// ---------------------------------------------------------------------------
__global__ __launch_bounds__(256) void attn_k(
    const float* __restrict__ Q, const float* __restrict__ Kt,
    const float* __restrict__ V, const int* __restrict__ A,
    float* __restrict__ O)
{
    __shared__ float q_s[4][32];
    __shared__ float scores[4][2048];
    __shared__ float redm[4][4], reds[4][4];
    __shared__ float red2[16][33];

    const int tid = threadIdx.x;
    const int wg = blockIdx.x;        // 0..4095
    const int b = wg >> 11;
    const int h = (wg >> 9) & 3;
    const int r0 = (wg & 511) << 2;

    if (tid < 128) {
        int rr = tid >> 5, d = tid & 31;
        q_s[rr][d] = Q[((size_t)(b * 4 + h) * 2048 + r0 + rr) * 32 + d];
    }
    __syncthreads();

    const float* KtBH = Kt + (size_t)(b * 4 + h) * 32 * 2048;
    float acc[4][8];
    #pragma unroll
    for (int rr = 0; rr < 4; ++rr)
        #pragma unroll
        for (int s = 0; s < 8; ++s) acc[rr][s] = 0.f;

    #pragma unroll
    for (int d0 = 0; d0 < 32; d0 += 8) {
        float qr[4][8];
        #pragma unroll
        for (int rr = 0; rr < 4; ++rr)
            #pragma unroll
            for (int dd = 0; dd < 8; ++dd) qr[rr][dd] = q_s[rr][d0 + dd];
        #pragma unroll
        for (int dd = 0; dd < 8; ++dd) {
            const float* kp = KtBH + (size_t)(d0 + dd) * 2048 + tid;
            #pragma unroll
            for (int s = 0; s < 8; ++s) {
                float kv = kp[s * 256];
                acc[0][s] = fmaf(qr[0][dd], kv, acc[0][s]);
                acc[1][s] = fmaf(qr[1][dd], kv, acc[1][s]);
                acc[2][s] = fmaf(qr[2][dd], kv, acc[2][s]);
                acc[3][s] = fmaf(qr[3][dd], kv, acc[3][s]);
            }
        }
    }

    const float SCALE = 0.17677669529663687f;  // 32^-0.5 rounded to f32
    #pragma unroll
    for (int s = 0; s < 8; ++s) {
        int jj = tid + 256 * s;
        #pragma unroll
        for (int rr = 0; rr < 4; ++rr) {
            int am = A[(size_t)(r0 + rr) * 2048 + jj];
            scores[rr][jj] = (am > 0) ? acc[rr][s] * SCALE : -9e15f;
        }
    }
    __syncthreads();

    const int lane = tid & 63, wid = tid >> 6;
    #pragma unroll
    for (int rr = 0; rr < 4; ++rr) {
        float m = -3.0e38f;
        #pragma unroll
        for (int s = 0; s < 8; ++s) m = fmaxf(m, scores[rr][tid + 256 * s]);
        m = wave_max_f(m);
        if (lane == 0) redm[rr][wid] = m;
    }
    __syncthreads();
    float mx[4];
    #pragma unroll
    for (int rr = 0; rr < 4; ++rr)
        mx[rr] = fmaxf(fmaxf(redm[rr][0], redm[rr][1]), fmaxf(redm[rr][2], redm[rr][3]));

    #pragma unroll
    for (int rr = 0; rr < 4; ++rr) {
        float sm = 0.f;
        #pragma unroll
        for (int s = 0; s < 8; ++s) {
            int jj = tid + 256 * s;
            float p = expf(scores[rr][jj] - mx[rr]);
            scores[rr][jj] = p;
            sm += p;
        }
        sm = wave_sum_f(sm);
        if (lane == 0) reds[rr][wid] = sm;
    }
    __syncthreads();
    float inv[4];
    #pragma unroll
    for (int rr = 0; rr < 4; ++rr)
        inv[rr] = 1.f / (reds[rr][0] + reds[rr][1] + reds[rr][2] + reds[rr][3]);

    // PV: thread (jl = tid>>2, dq = tid&3) accumulates 8 dims for 4 rows.
    const int dq = tid & 3, jl = tid >> 2;
    const float* Vbh = V + (size_t)(b * 4 + h) * 2048 * 32;
    float pacc[4][8];
    #pragma unroll
    for (int rr = 0; rr < 4; ++rr)
        #pragma unroll
        for (int u = 0; u < 8; ++u) pacc[rr][u] = 0.f;

    for (int i = 0; i < 32; ++i) {
        int j = jl + i * 64;
        float pr[4] = {scores[0][j], scores[1][j], scores[2][j], scores[3][j]};
        const float* vp = Vbh + (size_t)j * 32 + dq * 8;
        float4 va = *(const float4*)vp;
        float4 vb = *(const float4*)(vp + 4);
        float vv[8] = {va.x, va.y, va.z, va.w, vb.x, vb.y, vb.z, vb.w};
        #pragma unroll
        for (int rr = 0; rr < 4; ++rr)
            #pragma unroll
            for (int u = 0; u < 8; ++u)
                pacc[rr][u] = fmaf(pr[rr], vv[u], pacc[rr][u]);
    }
    // reduce over the 16 jl lanes within each wave (lane = (jl&15)*4 + dq)
    #pragma unroll
    for (int m = 4; m <= 32; m <<= 1)
        #pragma unroll
        for (int rr = 0; rr < 4; ++rr)
            #pragma unroll
            for (int u = 0; u < 8; ++u)
                pacc[rr][u] += __shfl_xor(pacc[rr][u], m);

    if ((tid & 63) < 4) {
        int wrow = wid * 4 + (tid & 3);
        #pragma unroll
        for (int rr = 0; rr < 4; ++rr)
            #pragma unroll
            for (int u = 0; u < 8; ++u) red2[wrow][rr * 8 + u] = pacc[rr][u];
    }
    __syncthreads();
    if (tid < 128) {
        int rr = tid >> 5, d = tid & 31;
        int dqq = d >> 3, u = d & 7;
        float s = red2[0 + dqq][rr * 8 + u] + red2[4 + dqq][rr * 8 + u] +
                  red2[8 + dqq][rr * 8 + u] + red2[12 + dqq][rr * 8 + u];
        O[((size_t)b * 2048 + r0 + rr) * 128 + h * 32 + d] = s * inv[rr];
    }
}

// ---------------------------------------------------------------------------
// Graph adjacency: logits = Kg[b,n,:]·QgT[b,:,m], row softmax -> ADJ.
// ---------------------------------------------------------------------------
__global__ __launch_bounds__(256) void gadj_k(
    const float* __restrict__ Kg, const float* __restrict__ QgT,
    float* __restrict__ ADJ)
{
    __shared__ float kg_s[4][32];
    __shared__ float scores[4][2048];
    __shared__ float redm[4][4], reds[4][4];

    const int tid = threadIdx.x;
    const int wg = blockIdx.x;     // 0..1023
    const int b = wg >> 9;
    const int r0 = (wg & 511) << 2;

    if (tid < 128) {
        int rr = tid >> 5, d = tid & 31;
        kg_s[rr][d] = Kg[((size_t)b * 2048 + r0 + rr) * 32 + d];
    }
    __syncthreads();

    const float* Qb = QgT + (size_t)b * 32 * 2048;
    float acc[4][8];
    #pragma unroll
    for (int rr = 0; rr < 4; ++rr)
        #pragma unroll
        for (int s = 0; s < 8; ++s) acc[rr][s] = 0.f;

    #pragma unroll
    for (int d0 = 0; d0 < 32; d0 += 8) {
        float qr[4][8];
        #pragma unroll
        for (int rr = 0; rr < 4; ++rr)
            #pragma unroll
            for (int dd = 0; dd < 8; ++dd) qr[rr][dd] = kg_s[rr][d0 + dd];
        #pragma unroll
        for (int dd = 0; dd < 8; ++dd) {
            const float* kp = Qb + (size_t)(d0 + dd) * 2048 + tid;
            #pragma unroll
            for (int s = 0; s < 8; ++s) {
                float kv = kp[s * 256];
                acc[0][s] = fmaf(qr[0][dd], kv, acc[0][s]);
                acc[1][s] = fmaf(qr[1][dd], kv, acc[1][s]);
                acc[2][s] = fmaf(qr[2][dd], kv, acc[2][s]);
                acc[3][s] = fmaf(qr[3][dd], kv, acc[3][s]);
            }
        }
    }
    #pragma unroll
    for (int s = 0; s < 8; ++s) {
        int jj = tid + 256 * s;
        #pragma unroll
        for (int rr = 0; rr < 4; ++rr) scores[rr][jj] = acc[rr][s];
    }
    __syncthreads();

    const int lane = tid & 63, wid = tid >> 6;
    #pragma unroll
    for (int rr = 0; rr < 4; ++rr) {
        float m = -3.0e38f;
        #pragma unroll
        for (int s = 0; s < 8; ++s) m = fmaxf(m, scores[rr][tid + 256 * s]);
        m = wave_max_f(m);
        if (lane == 0) redm[rr][wid] = m;
    }
    __syncthreads();
    float mx[4];
    #pragma unroll
    for (int rr = 0; rr < 4; ++rr)
        mx[rr] = fmaxf(fmaxf(redm[rr][0], redm[rr][1]), fmaxf(redm[rr][2], redm[rr][3]));
    #pragma unroll
    for (int rr = 0; rr < 4; ++rr) {
        float sm = 0.f;
        #pragma unroll
        for (int s = 0; s < 8; ++s) {
            int jj = tid + 256 * s;
            float p = expf(scores[rr][jj] - mx[rr]);
            scores[rr][jj] = p;
            sm += p;
        }
        sm = wave_sum_f(sm);
        if (lane == 0) reds[rr][wid] = sm;
    }
    __syncthreads();
    #pragma unroll
    for (int rr = 0; rr < 4; ++rr) {
        float iv = 1.f / (reds[rr][0] + reds[rr][1] + reds[rr][2] + reds[rr][3]);
        #pragma unroll
        for (int s = 0; s < 8; ++s) {
            int jj = tid + 256 * s;
            ADJ[((size_t)b * 2048 + r0 + rr) * 2048 + jj] = scores[rr][jj] * iv;
        }
    }
}

// ---------------------------------------------------------------------------
// Top-k (k=1365) + masked re-softmax, one wave per row, in-place on ADJ.
// adj values are positive => u32 bit pattern order == float order.
// ---------------------------------------------------------------------------
__global__ __launch_bounds__(256) void topk_k(float* __restrict__ ADJ)
{
    const int lane = threadIdx.x & 63;
    const int wid = threadIdx.x >> 6;
    const int row = blockIdx.x * 4 + wid;      // 0..4095
    float* rp = ADJ + (size_t)row * 2048;

    unsigned k_[32];
    float mx = -3.0e38f;
    #pragma unroll
    for (int i = 0; i < 32; ++i) {
        float x = rp[lane + i * 64];
        k_[i] = __float_as_uint(x);
        mx = fmaxf(mx, x);
    }
    mx = wave_max_f(mx);

    // binary search for the KK_TOP-th largest key (values < 2.0 => bit 29 down)
    unsigned thr = 0u;
    for (int bit = 29; bit >= 0; --bit) {
        unsigned cand = thr | (1u << bit);
        int cnt = 0;
        #pragma unroll
        for (int i = 0; i < 32; ++i) cnt += (k_[i] >= cand) ? 1 : 0;
        cnt = wave_sum_i(cnt);
        if (cnt >= KK_TOP) thr = cand;
    }

    int gt_c = 0;
    #pragma unroll
    for (int i = 0; i < 32; ++i) gt_c += (k_[i] > thr) ? 1 : 0;
    gt_c = wave_sum_i(gt_c);
    const int need = KK_TOP - gt_c;   // >= 1 ties to keep (lowest index first)

    unsigned keepmask = 0u;
    int running = 0;
    const unsigned long long ltmask = (lane == 0) ? 0ull : (~0ull >> (64 - lane));
    #pragma unroll
    for (int i = 0; i < 32; ++i) {
        bool tie = (k_[i] == thr);
        unsigned long long bal = __ballot(tie);
        int before = running + (int)__popcll(bal & ltmask);
        bool keep = (k_[i] > thr) || (tie && before < need);
        running += (int)__popcll(bal);
        if (keep) keepmask |= (1u << i);
    }

    float sm = 0.f;
    #pragma unroll
    for (int i = 0; i < 32; ++i)
        if ((keepmask >> i) & 1u) sm += expf(__uint_as_float(k_[i]) - mx);
    sm = wave_sum_f(sm);
    const float iv = 1.f / sm;

    #pragma unroll
    for (int i = 0; i < 32; ++i) {
        float o = ((keepmask >> i) & 1u) ? expf(__uint_as_float(k_[i]) - mx) * iv : 0.f;
        rp[lane + i * 64] = o;
    }
}

// ---------------------------------------------------------------------------
// Fused weight for support path: MT[c][k] = sum_i cv_w[i,k]*gc_w[i,c];
// B2[c] = sum_i cv_b[i]*gc_w[i,c].
// ---------------------------------------------------------------------------
__global__ __launch_bounds__(256) void fusew_k(
    const float* __restrict__ cv_w, const float* __restrict__ cv_b,
    const float* __restrict__ gc_w, float* __restrict__ MT, float* __restrict__ B2)
{
    int c = blockIdx.x * 2 + (threadIdx.x >> 7);
    int k = threadIdx.x & 127;
    float a = 0.f;
    for (int i = 0; i < 128; ++i) a += cv_w[(size_t)i * 128 + k] * gc_w[(size_t)i * 128 + c];
    MT[(size_t)c * 128 + k] = a;
    if (blockIdx.x == 0 && threadIdx.x < 128) {
        float s = 0.f;
        for (int i = 0; i < 128; ++i) s += cv_b[i] * gc_w[(size_t)i * 128 + threadIdx.x];
        B2[threadIdx.x] = s;
    }
}

// ---------------------------------------------------------------------------
// Final GEMM: OUT[b,n,c] = sum_m ADJ[b,n,m]*SUP[b,m,c] + gc_b[c]
// BM=32, BN=64, BK=32, thread tile 2x4.
// ---------------------------------------------------------------------------
__global__ __launch_bounds__(256) void outgemm_k(
    const float* __restrict__ ADJ, const float* __restrict__ SUP,
    const float* __restrict__ gcb, float* __restrict__ OUT)
{
    __shared__ __align__(16) float As[32][36];
    __shared__ __align__(16) float Bs[64][36];
    const int tid = threadIdx.x;
    const int m0 = blockIdx.x * 32;
    const int n0 = blockIdx.y * 64;
    const int b = blockIdx.z;
    const float* Ab = ADJ + (size_t)b * 2048 * 2048;
    const float* Sb = SUP + (size_t)b * 2048 * 128;

    const int r = tid >> 4, c = tid & 15;
    float acc[2][4] = {{0.f,0.f,0.f,0.f},{0.f,0.f,0.f,0.f}};

    for (int k0 = 0; k0 < 2048; k0 += 32) {
        #pragma unroll
        for (int i = 0; i < 4; ++i) {
            int idx = tid + i * 256;
            int row = idx >> 5, kk = idx & 31;
            As[row][kk] = Ab[(size_t)(m0 + row) * 2048 + k0 + kk];
        }
        #pragma unroll
        for (int i = 0; i < 8; ++i) {
            int idx = tid + i * 256;
            int kr = idx >> 6, ccol = idx & 63;
            Bs[ccol][kr] = Sb[(size_t)(k0 + kr) * 128 + n0 + ccol];
        }
        __syncthreads();
        #pragma unroll
        for (int k = 0; k < 32; k += 4) {
            float4 a0 = *(const float4*)&As[r][k];
            float4 a1 = *(const float4*)&As[r + 16][k];
            #pragma unroll
            for (int jj = 0; jj < 4; ++jj) {
                float4 bv = *(const float4*)&Bs[c + 16 * jj][k];
                acc[0][jj] += a0.x * bv.x + a0.y * bv.y + a0.z * bv.z + a0.w * bv.w;
                acc[1][jj] += a1.x * bv.x + a1.y * bv.y + a1.z * bv.z + a1.w * bv.w;
            }
        }
        __syncthreads();
    }
    #pragma unroll
    for (int i = 0; i < 2; ++i)
        #pragma unroll
        for (int jj = 0; jj < 4; ++jj) {
            int m = m0 + r + 16 * i;
            int ccol = n0 + c + 16 * jj;
            OUT[((size_t)b * 2048 + m) * 128 + ccol] = acc[i][jj] + gcb[ccol];
        }
}

// ---------------------------------------------------------------------------
extern "C" void kernel_launch(void* const* d_in, const int* in_sizes, int n_in,
                              void* d_out, int out_size, void* d_ws, size_t ws_size,
                              hipStream_t stream)
{
    const float* x       = (const float*)d_in[0];
    const int*   A       = (const int*)d_in[1];
    const float* q_w1    = (const float*)d_in[2];
    const float* kv_w1   = (const float*)d_in[3];
    const float* proj_w1 = (const float*)d_in[4];
    const float* proj_b1 = (const float*)d_in[5];
    const float* q_w2    = (const float*)d_in[6];
    const float* kv_w2   = (const float*)d_in[7];
    const float* proj_w2 = (const float*)d_in[8];
    const float* proj_b2 = (const float*)d_in[9];
    const float* cq_w    = (const float*)d_in[10];
    const float* cq_b    = (const float*)d_in[11];
    const float* ck_w    = (const float*)d_in[12];
    const float* ck_b    = (const float*)d_in[13];
    const float* cv_w    = (const float*)d_in[14];
    const float* cv_b    = (const float*)d_in[15];
    const float* gc_w    = (const float*)d_in[16];
    const float* gc_b    = (const float*)d_in[17];
    float* out = (float*)d_out;

    // Workspace layout (floats). ADJ aliases the attention scratch region,
    // which is dead by the time ADJ is written. Total ~38.9 MB.
    float* W   = (float*)d_ws;
    const size_t SZ = (size_t)BB * NN * CC;       // 524288
    float* Q   = W;                                // phase A scratch
    float* Kt  = W + SZ;
    float* V   = W + 2 * SZ;
    float* O   = W + 3 * SZ;
    float* X1  = W + 4 * SZ;
    float* ADJ = W;                                // 8388608 floats, overlays Q..X1 (dead)
    float* X2  = W + 8388608;
    float* QgT = X2 + SZ;                          // 131072
    float* Kg  = QgT + 131072;                     // 131072
    float* SUP = Kg + 131072;                      // 524288
    float* MT  = SUP + SZ;                         // 16384
    float* B2  = MT + 16384;                       // 128

    dim3 blk(256);

    // fused support weight (independent)
    hipLaunchKernelGGL(fusew_k, dim3(64), blk, 0, stream, cv_w, cv_b, gc_w, MT, B2);

    // ---- attention block 1 ----
    hipLaunchKernelGGL((gemm128_k<MODE_QKV>), dim3(64, 12), blk, 0, stream,
                       x, q_w1, kv_w1, nullptr, nullptr, Q, Kt, V);
    hipLaunchKernelGGL(attn_k, dim3(4096), blk, 0, stream, Q, Kt, V, A, O);
    hipLaunchKernelGGL((gemm128_k<MODE_PROJ>), dim3(64, 4), blk, 0, stream,
                       O, proj_w1, nullptr, proj_b1, x, X1, nullptr, nullptr);

    // ---- attention block 2 ----
    hipLaunchKernelGGL((gemm128_k<MODE_QKV>), dim3(64, 12), blk, 0, stream,
                       X1, q_w2, kv_w2, nullptr, nullptr, Q, Kt, V);
    hipLaunchKernelGGL(attn_k, dim3(4096), blk, 0, stream, Q, Kt, V, A, O);
    hipLaunchKernelGGL((gemm128_k<MODE_PROJ>), dim3(64, 4), blk, 0, stream,
                       O, proj_w2, nullptr, proj_b2, X1, X2, nullptr, nullptr);

    // ---- graph conv ----
    hipLaunchKernelGGL((gemm128_k<MODE_QG>), dim3(64, 1), blk, 0, stream,
                       X2, cq_w, nullptr, cq_b, nullptr, QgT, nullptr, nullptr);
    hipLaunchKernelGGL((gemm128_k<MODE_KG>), dim3(64, 1), blk, 0, stream,
                       X2, ck_w, nullptr, ck_b, nullptr, Kg, nullptr, nullptr);
    hipLaunchKernelGGL((gemm128_k<MODE_SUP>), dim3(64, 4), blk, 0, stream,
                       X2, MT, nullptr, B2, nullptr, SUP, nullptr, nullptr);
    hipLaunchKernelGGL(gadj_k, dim3(1024), blk, 0, stream, Kg, QgT, ADJ);
    hipLaunchKernelGGL(topk_k, dim3(1024), blk, 0, stream, ADJ);
    hipLaunchKernelGGL(outgemm_k, dim3(64, 2, 2), blk, 0, stream, ADJ, SUP, gc_b, out);
}

// Round 2
// 350.488 us; speedup vs baseline: 2.4130x; 2.4130x over previous
//
#include <hip/hip_runtime.h>
#include <hip/hip_bf16.h>
#include <math.h>

#define BB 2
#define NN 2048
#define CC 128
#define HH 4
#define HD 32
#define KK_TOP 1365   // int(2048/3*2)

typedef __attribute__((ext_vector_type(8))) short v8s;
typedef __attribute__((ext_vector_type(4))) float f32x4;

#define MFMA16(a, b, c) __builtin_amdgcn_mfma_f32_16x16x32_bf16(a, b, c, 0, 0, 0)

__device__ inline float wave_max_f(float v) {
    #pragma unroll
    for (int m = 1; m < 64; m <<= 1) v = fmaxf(v, __shfl_xor(v, m));
    return v;
}
__device__ inline float wave_sum_f(float v) {
    #pragma unroll
    for (int m = 1; m < 64; m <<= 1) v += __shfl_xor(v, m);
    return v;
}
__device__ inline int wave_sum_i(int v) {
    #pragma unroll
    for (int m = 1; m < 64; m <<= 1) v += __shfl_xor(v, m);
    return v;
}

// ---------------------------------------------------------------------------
// Pack mask A (int32 [2048][2048]) into transposed bitmask:
// bit r of AbT[key][w] = A[w*32+r][key] > 0
// ---------------------------------------------------------------------------
__global__ __launch_bounds__(256) void packA_k(const int* __restrict__ A,
                                               unsigned* __restrict__ AbT)
{
    const int key = blockIdx.x * 256 + threadIdx.x;
    const int wrow = blockIdx.y;   // 0..63
    unsigned word = 0u;
    #pragma unroll 4
    for (int r = 0; r < 32; ++r)
        word |= (A[(size_t)(wrow * 32 + r) * 2048 + key] > 0 ? 1u : 0u) << r;
    AbT[(size_t)key * 64 + wrow] = word;
}

// ---------------------------------------------------------------------------
// Generic 128-K GEMM (f32 VALU): out = X[M,128] @ W[NC,128]^T + epilogues.
// QKV mode emits bf16 Q,K (row-major [bh][n][32]) and bf16 Vt ([bh][32][n]).
// SUP mode emits bf16 SUPt ([b][c][n]).
// ---------------------------------------------------------------------------
enum { MODE_QKV = 0, MODE_PROJ = 1, MODE_QG = 2, MODE_KG = 3, MODE_SUP = 4 };

template <int MODE>
__global__ __launch_bounds__(256) void gemm128_k(
    const float* __restrict__ X, const float* __restrict__ W0,
    const float* __restrict__ W1, const float* __restrict__ bias,
    const float* __restrict__ resid, void* __restrict__ out0v,
    void* __restrict__ out1v, void* __restrict__ out2v)
{
    __shared__ __align__(16) float Xs[64][132];
    __shared__ __align__(16) float Ws[32][132];
    const int tid = threadIdx.x;
    const int m0 = blockIdx.x * 64;
    const int n0 = blockIdx.y * 32;

    #pragma unroll
    for (int i = 0; i < 32; ++i) {
        int idx = tid + i * 256;
        int row = idx >> 7, col = idx & 127;
        Xs[row][col] = X[(size_t)(m0 + row) * 128 + col];
    }
    #pragma unroll
    for (int i = 0; i < 16; ++i) {
        int idx = tid + i * 256;
        int r = idx >> 7, col = idx & 127;
        int gr = n0 + r;
        const float* wp;
        if (MODE == MODE_QKV)
            wp = (gr < 128) ? (W0 + (size_t)gr * 128) : (W1 + (size_t)(gr - 128) * 128);
        else
            wp = W0 + (size_t)gr * 128;
        Ws[r][col] = wp[col];
    }
    __syncthreads();

    const int r = tid >> 4;
    const int c = tid & 15;
    float acc[4][2] = {{0.f, 0.f}, {0.f, 0.f}, {0.f, 0.f}, {0.f, 0.f}};

    #pragma unroll
    for (int k = 0; k < 128; k += 4) {
        float4 w0 = *(const float4*)&Ws[c][k];
        float4 w1 = *(const float4*)&Ws[c + 16][k];
        #pragma unroll
        for (int i = 0; i < 4; ++i) {
            float4 xv = *(const float4*)&Xs[r + 16 * i][k];
            acc[i][0] += xv.x * w0.x + xv.y * w0.y + xv.z * w0.z + xv.w * w0.w;
            acc[i][1] += xv.x * w1.x + xv.y * w1.y + xv.z * w1.z + xv.w * w1.w;
        }
    }

    #pragma unroll
    for (int i = 0; i < 4; ++i) {
        int m = m0 + r + 16 * i;
        int b = m >> 11, n = m & 2047;
        #pragma unroll
        for (int jj = 0; jj < 2; ++jj) {
            int ccol = n0 + c + 16 * jj;
            float v = acc[i][jj];
            if (MODE == MODE_QKV) {
                __hip_bfloat16 hv = __float2bfloat16(v);
                if (ccol < 128) {
                    int hh = ccol >> 5, d = ccol & 31;
                    ((__hip_bfloat16*)out0v)[((size_t)(b * 4 + hh) * 2048 + n) * 32 + d] = hv;  // Qb
                } else if (ccol < 256) {
                    int c2 = ccol - 128; int hh = c2 >> 5, d = c2 & 31;
                    ((__hip_bfloat16*)out1v)[((size_t)(b * 4 + hh) * 2048 + n) * 32 + d] = hv;  // Kb
                } else {
                    int c2 = ccol - 256; int hh = c2 >> 5, d = c2 & 31;
                    ((__hip_bfloat16*)out2v)[((size_t)(b * 4 + hh) * 32 + d) * 2048 + n] = hv;  // Vt
                }
            } else if (MODE == MODE_PROJ) {
                ((float*)out0v)[(size_t)m * 128 + ccol] = v + bias[ccol] + resid[(size_t)m * 128 + ccol];
            } else if (MODE == MODE_QG) {
                ((float*)out0v)[((size_t)b * 32 + ccol) * 2048 + n] = v + bias[ccol];   // QgT [b,o,n]
            } else if (MODE == MODE_KG) {
                ((float*)out0v)[(size_t)m * 32 + ccol] = v + bias[ccol];                // Kg [b,n,o]
            } else { // MODE_SUP -> SUPt bf16 [b][c][n]
                ((__hip_bfloat16*)out0v)[((size_t)b * 128 + ccol) * 2048 + n] = __float2bfloat16(v + bias[ccol]);
            }
        }
    }
}

// ---------------------------------------------------------------------------
// MFMA attention. Block = 4 indep waves; wave = 16 q-rows of one (b,h).
// Online softmax in t = s*scale*log2e domain; P via wave-private LDS tile.
// ---------------------------------------------------------------------------
__global__ __launch_bounds__(256) void attn_mfma_k(
    const short* __restrict__ Qb, const short* __restrict__ Kb,
    const short* __restrict__ Vt, const unsigned* __restrict__ AbT,
    float* __restrict__ O)
{
    __shared__ __hip_bfloat16 Plds[4][16 * 32];
    const int tid = threadIdx.x;
    const int w = tid >> 6, lane = tid & 63;
    const int g = lane >> 4, c = lane & 15;
    const int wg = blockIdx.x;                 // 0..255
    const int b = wg >> 7, h = (wg >> 5) & 3, rt = wg & 31;
    const int bh = b * 4 + h;
    const int r0w = rt * 64 + w * 16;

    const v8s qf = *(const v8s*)(Qb + ((size_t)bh * 2048 + r0w + c) * 32 + g * 8);
    const short* Kp = Kb + (size_t)bh * 2048 * 32;
    const short* Vp = Vt + (size_t)bh * 32 * 2048;
    const unsigned* Mp = AbT + (r0w >> 5);
    const int bb = (r0w & 16) + 4 * g;

    f32x4 o0 = {0.f, 0.f, 0.f, 0.f}, o1 = {0.f, 0.f, 0.f, 0.f};
    float m_[4] = {-3e38f, -3e38f, -3e38f, -3e38f};
    float l_[4] = {0.f, 0.f, 0.f, 0.f};
    const float SC2 = 0.25503487f;  // 32^-0.5 * log2(e)

    __hip_bfloat16* Pw = &Plds[w][0];

    #pragma unroll 2
    for (int kt = 0; kt < 64; ++kt) {
        const int key0 = kt * 32;
        v8s kf0 = *(const v8s*)(Kp + (size_t)(key0 + c) * 32 + g * 8);
        v8s kf1 = *(const v8s*)(Kp + (size_t)(key0 + 16 + c) * 32 + g * 8);
        const f32x4 z = {0.f, 0.f, 0.f, 0.f};
        f32x4 s0 = MFMA16(qf, kf0, z);
        f32x4 s1 = MFMA16(qf, kf1, z);
        unsigned mw0 = Mp[(size_t)(key0 + c) * 64];
        unsigned mw1 = Mp[(size_t)(key0 + 16 + c) * 64];

        float t0[4], t1[4], tmax[4];
        bool u0[4], u1[4];
        #pragma unroll
        for (int r = 0; r < 4; ++r) {
            u0[r] = (mw0 >> (bb + r)) & 1u;
            u1[r] = (mw1 >> (bb + r)) & 1u;
            t0[r] = u0[r] ? s0[r] * SC2 : -3e38f;
            t1[r] = u1[r] ? s1[r] * SC2 : -3e38f;
            tmax[r] = fmaxf(t0[r], t1[r]);
        }
        #pragma unroll
        for (int msk = 1; msk <= 8; msk <<= 1)
            #pragma unroll
            for (int r = 0; r < 4; ++r)
                tmax[r] = fmaxf(tmax[r], __shfl_xor(tmax[r], msk));

        #pragma unroll
        for (int r = 0; r < 4; ++r) {
            float mn = fmaxf(m_[r], tmax[r]);
            float al = exp2f(m_[r] - mn);
            m_[r] = mn;
            float p0 = u0[r] ? exp2f(t0[r] - mn) : 0.f;
            float p1 = u1[r] ? exp2f(t1[r] - mn) : 0.f;
            o0[r] *= al;
            o1[r] *= al;
            l_[r] = l_[r] * al + p0 + p1;
            Pw[(4 * g + r) * 32 + c] = __float2bfloat16(p0);
            Pw[(4 * g + r) * 32 + c + 16] = __float2bfloat16(p1);
        }

        v8s pf = *(const v8s*)((const short*)Pw + c * 32 + g * 8);
        v8s vf0 = *(const v8s*)(Vp + (size_t)c * 2048 + key0 + g * 8);
        v8s vf1 = *(const v8s*)(Vp + (size_t)(16 + c) * 2048 + key0 + g * 8);
        o0 = MFMA16(pf, vf0, o0);
        o1 = MFMA16(pf, vf1, o1);
    }

    #pragma unroll
    for (int msk = 1; msk <= 8; msk <<= 1)
        #pragma unroll
        for (int r = 0; r < 4; ++r)
            l_[r] += __shfl_xor(l_[r], msk);

    #pragma unroll
    for (int r = 0; r < 4; ++r) {
        float inv = 1.f / l_[r];
        size_t base = ((size_t)b * 2048 + r0w + 4 * g + r) * 128 + h * 32;
        O[base + c]      = o0[r] * inv;
        O[base + 16 + c] = o1[r] * inv;
    }
}

// ---------------------------------------------------------------------------
// Graph adjacency + fused top-k + masked re-softmax -> bf16 ADJb.
// Block: 4 rows; logits f32 VALU; wave w owns row w for top-k.
// ---------------------------------------------------------------------------
__global__ __launch_bounds__(256) void gadjtopk_k(
    const float* __restrict__ Kg, const float* __restrict__ QgT,
    __hip_bfloat16* __restrict__ ADJb)
{
    __shared__ float kg_s[4][32];
    __shared__ float scores[4][2048];
    __shared__ float redm[4][4], reds[4][4];

    const int tid = threadIdx.x;
    const int wg = blockIdx.x;     // 0..1023
    const int b = wg >> 9;
    const int r0 = (wg & 511) << 2;

    if (tid < 128) {
        int rr = tid >> 5, d = tid & 31;
        kg_s[rr][d] = Kg[((size_t)b * 2048 + r0 + rr) * 32 + d];
    }
    __syncthreads();

    const float* Qp = QgT + (size_t)b * 32 * 2048;
    float acc[4][8];
    #pragma unroll
    for (int rr = 0; rr < 4; ++rr)
        #pragma unroll
        for (int s = 0; s < 8; ++s) acc[rr][s] = 0.f;

    #pragma unroll
    for (int d0 = 0; d0 < 32; d0 += 8) {
        float qr[4][8];
        #pragma unroll
        for (int rr = 0; rr < 4; ++rr)
            #pragma unroll
            for (int dd = 0; dd < 8; ++dd) qr[rr][dd] = kg_s[rr][d0 + dd];
        #pragma unroll
        for (int dd = 0; dd < 8; ++dd) {
            const float* kp = Qp + (size_t)(d0 + dd) * 2048 + tid;
            #pragma unroll
            for (int s = 0; s < 8; ++s) {
                float kv = kp[s * 256];
                acc[0][s] = fmaf(qr[0][dd], kv, acc[0][s]);
                acc[1][s] = fmaf(qr[1][dd], kv, acc[1][s]);
                acc[2][s] = fmaf(qr[2][dd], kv, acc[2][s]);
                acc[3][s] = fmaf(qr[3][dd], kv, acc[3][s]);
            }
        }
    }
    #pragma unroll
    for (int s = 0; s < 8; ++s) {
        int jj = tid + 256 * s;
        #pragma unroll
        for (int rr = 0; rr < 4; ++rr) scores[rr][jj] = acc[rr][s];
    }
    __syncthreads();

    const int lane = tid & 63, wid = tid >> 6;
    #pragma unroll
    for (int rr = 0; rr < 4; ++rr) {
        float m = -3.0e38f;
        #pragma unroll
        for (int s = 0; s < 8; ++s) m = fmaxf(m, scores[rr][tid + 256 * s]);
        m = wave_max_f(m);
        if (lane == 0) redm[rr][wid] = m;
    }
    __syncthreads();
    float mx[4];
    #pragma unroll
    for (int rr = 0; rr < 4; ++rr)
        mx[rr] = fmaxf(fmaxf(redm[rr][0], redm[rr][1]), fmaxf(redm[rr][2], redm[rr][3]));
    #pragma unroll
    for (int rr = 0; rr < 4; ++rr) {
        float sm = 0.f;
        #pragma unroll
        for (int s = 0; s < 8; ++s) {
            int jj = tid + 256 * s;
            float p = expf(scores[rr][jj] - mx[rr]);
            scores[rr][jj] = p;
            sm += p;
        }
        sm = wave_sum_f(sm);
        if (lane == 0) reds[rr][wid] = sm;
    }
    __syncthreads();

    // ---- fused top-k: wave `wid` owns row r0+wid ----
    const float ivw = 1.f / (reds[wid][0] + reds[wid][1] + reds[wid][2] + reds[wid][3]);
    unsigned k_[32];
    float mxp = 0.f;
    #pragma unroll
    for (int i = 0; i < 32; ++i) {
        float p = scores[wid][lane + i * 64] * ivw;
        k_[i] = __float_as_uint(p);
        mxp = fmaxf(mxp, p);
    }
    mxp = wave_max_f(mxp);

    unsigned thr = 0u;
    for (int bit = 29; bit >= 0; --bit) {
        unsigned cand = thr | (1u << bit);
        int cnt = 0;
        #pragma unroll
        for (int i = 0; i < 32; ++i) cnt += (k_[i] >= cand) ? 1 : 0;
        cnt = wave_sum_i(cnt);
        if (cnt >= KK_TOP) thr = cand;
    }

    int gt_c = 0;
    #pragma unroll
    for (int i = 0; i < 32; ++i) gt_c += (k_[i] > thr) ? 1 : 0;
    gt_c = wave_sum_i(gt_c);
    const int need = KK_TOP - gt_c;

    unsigned keepmask = 0u;
    int running = 0;
    const unsigned long long ltmask = (lane == 0) ? 0ull : (~0ull >> (64 - lane));
    #pragma unroll
    for (int i = 0; i < 32; ++i) {
        bool tie = (k_[i] == thr);
        unsigned long long bal = __ballot(tie);
        int before = running + (int)__popcll(bal & ltmask);
        bool keep = (k_[i] > thr) || (tie && before < need);
        running += (int)__popcll(bal);
        if (keep) keepmask |= (1u << i);
    }

    const float LOG2E = 1.4426950408889634f;
    float sm = 0.f;
    #pragma unroll
    for (int i = 0; i < 32; ++i)
        if ((keepmask >> i) & 1u)
            sm += exp2f((__uint_as_float(k_[i]) - mxp) * LOG2E);
    sm = wave_sum_f(sm);
    const float ivs = 1.f / sm;

    __hip_bfloat16* rp = ADJb + (size_t)(b * 2048 + r0 + wid) * 2048;
    #pragma unroll
    for (int i = 0; i < 32; ++i) {
        float o = ((keepmask >> i) & 1u)
                    ? exp2f((__uint_as_float(k_[i]) - mxp) * LOG2E) * ivs : 0.f;
        rp[lane + i * 64] = __float2bfloat16(o);
    }
}

// ---------------------------------------------------------------------------
// Fused support weight: MT[c][k] = sum_i cv_w[i,k]*gc_w[i,c]; B2 likewise.
// ---------------------------------------------------------------------------
__global__ __launch_bounds__(256) void fusew_k(
    const float* __restrict__ cv_w, const float* __restrict__ cv_b,
    const float* __restrict__ gc_w, float* __restrict__ MT, float* __restrict__ B2)
{
    int c = blockIdx.x * 2 + (threadIdx.x >> 7);
    int k = threadIdx.x & 127;
    float a = 0.f;
    for (int i = 0; i < 128; ++i) a += cv_w[(size_t)i * 128 + k] * gc_w[(size_t)i * 128 + c];
    MT[(size_t)c * 128 + k] = a;
    if (blockIdx.x == 0 && threadIdx.x < 128) {
        float s = 0.f;
        for (int i = 0; i < 128; ++i) s += cv_b[i] * gc_w[(size_t)i * 128 + threadIdx.x];
        B2[threadIdx.x] = s;
    }
}

// ---------------------------------------------------------------------------
// Final GEMM (MFMA): OUT[row,c] = sum_m ADJb[row][m]*SUPt[b][c][m] + gcb[c].
// One wave per block, 16 rows, all 128 cols, K=2048. Register-resident.
// ---------------------------------------------------------------------------
__global__ __launch_bounds__(64) void outgemm_mfma_k(
    const short* __restrict__ ADJb, const short* __restrict__ SUPt,
    const float* __restrict__ gcb, float* __restrict__ OUT)
{
    const int lane = threadIdx.x;
    const int g = lane >> 4, c = lane & 15;
    const int r0w = blockIdx.x * 16;          // 0..4080
    const int b = r0w >> 11;
    const short* Bp = SUPt + (size_t)b * 128 * 2048;

    f32x4 acc[8];
    #pragma unroll
    for (int f = 0; f < 8; ++f) acc[f] = (f32x4){0.f, 0.f, 0.f, 0.f};

    #pragma unroll 2
    for (int k0 = 0; k0 < 2048; k0 += 32) {
        v8s af = *(const v8s*)(ADJb + (size_t)(r0w + c) * 2048 + k0 + g * 8);
        #pragma unroll
        for (int f = 0; f < 8; ++f) {
            v8s bf_ = *(const v8s*)(Bp + (size_t)(f * 16 + c) * 2048 + k0 + g * 8);
            acc[f] = MFMA16(af, bf_, acc[f]);
        }
    }

    #pragma unroll
    for (int f = 0; f < 8; ++f) {
        float bias = gcb[f * 16 + c];
        #pragma unroll
        for (int r = 0; r < 4; ++r)
            OUT[(size_t)(r0w + 4 * g + r) * 128 + f * 16 + c] = acc[f][r] + bias;
    }
}

// ---------------------------------------------------------------------------
extern "C" void kernel_launch(void* const* d_in, const int* in_sizes, int n_in,
                              void* d_out, int out_size, void* d_ws, size_t ws_size,
                              hipStream_t stream)
{
    const float* x       = (const float*)d_in[0];
    const int*   A       = (const int*)d_in[1];
    const float* q_w1    = (const float*)d_in[2];
    const float* kv_w1   = (const float*)d_in[3];
    const float* proj_w1 = (const float*)d_in[4];
    const float* proj_b1 = (const float*)d_in[5];
    const float* q_w2    = (const float*)d_in[6];
    const float* kv_w2   = (const float*)d_in[7];
    const float* proj_w2 = (const float*)d_in[8];
    const float* proj_b2 = (const float*)d_in[9];
    const float* cq_w    = (const float*)d_in[10];
    const float* cq_b    = (const float*)d_in[11];
    const float* ck_w    = (const float*)d_in[12];
    const float* ck_b    = (const float*)d_in[13];
    const float* cv_w    = (const float*)d_in[14];
    const float* cv_b    = (const float*)d_in[15];
    const float* gc_w    = (const float*)d_in[16];
    const float* gc_b    = (const float*)d_in[17];
    float* out = (float*)d_out;

    // Workspace layout (bytes, 256-aligned). Total ~27.6 MB.
    char* ws = (char*)d_ws;
    __hip_bfloat16* Qb   = (__hip_bfloat16*)(ws + 0);          // 1 MB
    __hip_bfloat16* Kb   = (__hip_bfloat16*)(ws + 1048576);    // 1 MB
    __hip_bfloat16* Vt   = (__hip_bfloat16*)(ws + 2097152);    // 1 MB
    __hip_bfloat16* ADJb = (__hip_bfloat16*)(ws + 3145728);    // 16 MB
    unsigned*       AbT  = (unsigned*)      (ws + 19922944);   // 512 KB
    float*          O    = (float*)         (ws + 20447232);   // 2 MB
    float*          X1   = (float*)         (ws + 22544384);   // 2 MB
    float*          X2   = (float*)         (ws + 24641536);   // 2 MB
    float*          QgT  = (float*)         (ws + 26738688);   // 512 KB
    float*          Kg   = (float*)         (ws + 27262976);   // 512 KB
    __hip_bfloat16* SUPt = (__hip_bfloat16*)(ws + 27787264);   // 1 MB
    float*          MT   = (float*)         (ws + 28835840);   // 64 KB
    float*          B2   = (float*)         (ws + 28901376);   // 512 B

    dim3 blk(256);

    hipLaunchKernelGGL(packA_k, dim3(8, 64), blk, 0, stream, A, AbT);
    hipLaunchKernelGGL(fusew_k, dim3(64), blk, 0, stream, cv_w, cv_b, gc_w, MT, B2);

    // ---- attention block 1 ----
    hipLaunchKernelGGL((gemm128_k<MODE_QKV>), dim3(64, 12), blk, 0, stream,
                       x, q_w1, kv_w1, nullptr, nullptr, Qb, Kb, Vt);
    hipLaunchKernelGGL(attn_mfma_k, dim3(256), blk, 0, stream,
                       (const short*)Qb, (const short*)Kb, (const short*)Vt, AbT, O);
    hipLaunchKernelGGL((gemm128_k<MODE_PROJ>), dim3(64, 4), blk, 0, stream,
                       O, proj_w1, nullptr, proj_b1, x, X1, nullptr, nullptr);

    // ---- attention block 2 ----
    hipLaunchKernelGGL((gemm128_k<MODE_QKV>), dim3(64, 12), blk, 0, stream,
                       X1, q_w2, kv_w2, nullptr, nullptr, Qb, Kb, Vt);
    hipLaunchKernelGGL(attn_mfma_k, dim3(256), blk, 0, stream,
                       (const short*)Qb, (const short*)Kb, (const short*)Vt, AbT, O);
    hipLaunchKernelGGL((gemm128_k<MODE_PROJ>), dim3(64, 4), blk, 0, stream,
                       O, proj_w2, nullptr, proj_b2, X1, X2, nullptr, nullptr);

    // ---- graph conv ----
    hipLaunchKernelGGL((gemm128_k<MODE_QG>), dim3(64, 1), blk, 0, stream,
                       X2, cq_w, nullptr, cq_b, nullptr, QgT, nullptr, nullptr);
    hipLaunchKernelGGL((gemm128_k<MODE_KG>), dim3(64, 1), blk, 0, stream,
                       X2, ck_w, nullptr, ck_b, nullptr, Kg, nullptr, nullptr);
    hipLaunchKernelGGL((gemm128_k<MODE_SUP>), dim3(64, 4), blk, 0, stream,
                       X2, MT, nullptr, B2, nullptr, SUPt, nullptr, nullptr);
    hipLaunchKernelGGL(gadjtopk_k, dim3(1024), blk, 0, stream, Kg, QgT, ADJb);
    hipLaunchKernelGGL(outgemm_mfma_k, dim3(256), dim3(64), 0, stream,
                       (const short*)ADJb, (const short*)SUPt, gc_b, out);
}

// Round 3
// 318.654 us; speedup vs baseline: 2.6541x; 1.0999x over previous
//
#include <hip/hip_runtime.h>
#include <hip/hip_bf16.h>
#include <math.h>

#define BB 2
#define NN 2048
#define CC 128
#define HH 4
#define HD 32
#define KK_TOP 1365   // int(2048/3*2)

typedef __attribute__((ext_vector_type(8))) short v8s;
typedef __attribute__((ext_vector_type(4))) float f32x4;

#define MFMA16(a, b, c) __builtin_amdgcn_mfma_f32_16x16x32_bf16(a, b, c, 0, 0, 0)

__device__ inline float wave_max_f(float v) {
    #pragma unroll
    for (int m = 1; m < 64; m <<= 1) v = fmaxf(v, __shfl_xor(v, m));
    return v;
}
__device__ inline float wave_sum_f(float v) {
    #pragma unroll
    for (int m = 1; m < 64; m <<= 1) v += __shfl_xor(v, m);
    return v;
}
__device__ inline int wave_sum_i(int v) {
    #pragma unroll
    for (int m = 1; m < 64; m <<= 1) v += __shfl_xor(v, m);
    return v;
}
__device__ inline unsigned short bf16bits(float x) {
    __hip_bfloat16 h = __float2bfloat16(x);
    return *reinterpret_cast<unsigned short*>(&h);
}

// ---------------------------------------------------------------------------
// Pack mask A (int32 [2048][2048]) row-major bitwords:
// bit t of Ab2[q*64 + kw] = A[q][kw*32 + t] > 0
// ---------------------------------------------------------------------------
__global__ __launch_bounds__(256) void packA2_k(const int* __restrict__ A,
                                                unsigned* __restrict__ Ab2)
{
    const int lane = threadIdx.x & 63;
    const int w = threadIdx.x >> 6;
    const int row = blockIdx.x * 4 + w;
    const int* rp = A + (size_t)row * 2048;
    for (int i = 0; i < 32; ++i) {
        unsigned long long bal = __ballot(rp[i * 64 + lane] > 0);
        if (lane == 0)  Ab2[(size_t)row * 64 + 2 * i]     = (unsigned)bal;
        if (lane == 32) Ab2[(size_t)row * 64 + 2 * i + 1] = (unsigned)(bal >> 32);
    }
}

// ---------------------------------------------------------------------------
// Generic 128-K GEMM (f32 VALU): out = X[M,128] @ W[NC,128]^T + epilogues.
// (unchanged numerics from round 2)
// ---------------------------------------------------------------------------
enum { MODE_QKV = 0, MODE_PROJ = 1, MODE_QG = 2, MODE_KG = 3, MODE_SUP = 4 };

template <int MODE>
__global__ __launch_bounds__(256) void gemm128_k(
    const float* __restrict__ X, const float* __restrict__ W0,
    const float* __restrict__ W1, const float* __restrict__ bias,
    const float* __restrict__ resid, void* __restrict__ out0v,
    void* __restrict__ out1v, void* __restrict__ out2v)
{
    __shared__ __align__(16) float Xs[64][132];
    __shared__ __align__(16) float Ws[32][132];
    const int tid = threadIdx.x;
    const int m0 = blockIdx.x * 64;
    const int n0 = blockIdx.y * 32;

    #pragma unroll
    for (int i = 0; i < 32; ++i) {
        int idx = tid + i * 256;
        int row = idx >> 7, col = idx & 127;
        Xs[row][col] = X[(size_t)(m0 + row) * 128 + col];
    }
    #pragma unroll
    for (int i = 0; i < 16; ++i) {
        int idx = tid + i * 256;
        int r = idx >> 7, col = idx & 127;
        int gr = n0 + r;
        const float* wp;
        if (MODE == MODE_QKV)
            wp = (gr < 128) ? (W0 + (size_t)gr * 128) : (W1 + (size_t)(gr - 128) * 128);
        else
            wp = W0 + (size_t)gr * 128;
        Ws[r][col] = wp[col];
    }
    __syncthreads();

    const int r = tid >> 4;
    const int c = tid & 15;
    float acc[4][2] = {{0.f, 0.f}, {0.f, 0.f}, {0.f, 0.f}, {0.f, 0.f}};

    #pragma unroll
    for (int k = 0; k < 128; k += 4) {
        float4 w0 = *(const float4*)&Ws[c][k];
        float4 w1 = *(const float4*)&Ws[c + 16][k];
        #pragma unroll
        for (int i = 0; i < 4; ++i) {
            float4 xv = *(const float4*)&Xs[r + 16 * i][k];
            acc[i][0] += xv.x * w0.x + xv.y * w0.y + xv.z * w0.z + xv.w * w0.w;
            acc[i][1] += xv.x * w1.x + xv.y * w1.y + xv.z * w1.z + xv.w * w1.w;
        }
    }

    #pragma unroll
    for (int i = 0; i < 4; ++i) {
        int m = m0 + r + 16 * i;
        int b = m >> 11, n = m & 2047;
        #pragma unroll
        for (int jj = 0; jj < 2; ++jj) {
            int ccol = n0 + c + 16 * jj;
            float v = acc[i][jj];
            if (MODE == MODE_QKV) {
                __hip_bfloat16 hv = __float2bfloat16(v);
                if (ccol < 128) {
                    int hh = ccol >> 5, d = ccol & 31;
                    ((__hip_bfloat16*)out0v)[((size_t)(b * 4 + hh) * 2048 + n) * 32 + d] = hv;  // Qb
                } else if (ccol < 256) {
                    int c2 = ccol - 128; int hh = c2 >> 5, d = c2 & 31;
                    ((__hip_bfloat16*)out1v)[((size_t)(b * 4 + hh) * 2048 + n) * 32 + d] = hv;  // Kb
                } else {
                    int c2 = ccol - 256; int hh = c2 >> 5, d = c2 & 31;
                    ((__hip_bfloat16*)out2v)[((size_t)(b * 4 + hh) * 32 + d) * 2048 + n] = hv;  // Vt
                }
            } else if (MODE == MODE_PROJ) {
                ((float*)out0v)[(size_t)m * 128 + ccol] = v + bias[ccol] + resid[(size_t)m * 128 + ccol];
            } else if (MODE == MODE_QG) {
                ((float*)out0v)[((size_t)b * 32 + ccol) * 2048 + n] = v + bias[ccol];   // QgT [b,o,n]
            } else if (MODE == MODE_KG) {
                ((float*)out0v)[(size_t)m * 32 + ccol] = v + bias[ccol];                // Kg [b,n,o]
            } else { // MODE_SUP -> SUPt bf16 [b][c][n]
                ((__hip_bfloat16*)out0v)[((size_t)b * 128 + ccol) * 2048 + n] = __float2bfloat16(v + bias[ccol]);
            }
        }
    }
}

// ---------------------------------------------------------------------------
// MFMA attention v2. Block = one (b,h,16-row q-tile); 4 waves K-split (512
// keys each, interleaved). No-max softmax (logits bounded): p = exp2(s*c),
// partials combine by pure addition. S^T = mfma(K,Q) keeps P lane-local per
// q-column; P->B-frag transpose via ds_bpermute (bank-conflict-free).
// ---------------------------------------------------------------------------
__global__ __launch_bounds__(256) void attn_mfma_k(
    const short* __restrict__ Qb, const short* __restrict__ Kb,
    const short* __restrict__ Vt, const unsigned* __restrict__ Ab2,
    float* __restrict__ O)
{
    __shared__ __align__(16) float OLDS[4][64][8];
    __shared__ float lred[4][16];

    const int tid = threadIdx.x;
    const int w = tid >> 6, lane = tid & 63;
    const int g = lane >> 4, c = lane & 15;
    const int bb = 4 * g;
    const int wg = blockIdx.x;                 // 0..1023
    const int b = wg >> 9, h = (wg >> 7) & 3, r0w = (wg & 127) << 4;
    const int bh = b * 4 + h;

    const v8s qf = *(const v8s*)(Qb + ((size_t)bh * 2048 + r0w + c) * 32 + g * 8);
    const short* Kp = Kb + (size_t)bh * 2048 * 32;
    const short* Vp = Vt + (size_t)bh * 32 * 2048;
    const unsigned* Mrow = Ab2 + (size_t)(r0w + c) * 64;

    f32x4 o0 = {0.f, 0.f, 0.f, 0.f}, o1 = {0.f, 0.f, 0.f, 0.f};
    float lsum = 0.f;
    const float SC2 = 0.25503487f;   // 32^-0.5 * log2(e)
    const bool lo = (g < 2);
    const int aA = (32 * (g & 1) + c) * 4;
    const int aB = aA + 64;

    #pragma unroll 2
    for (int t = 0; t < 16; ++t) {
        const int kt = t * 4 + w;
        const int key0 = kt * 32;
        v8s kf0 = *(const v8s*)(Kp + (size_t)(key0 + c) * 32 + g * 8);
        v8s kf1 = *(const v8s*)(Kp + (size_t)(key0 + 16 + c) * 32 + g * 8);
        unsigned mw = Mrow[kt];
        const f32x4 z = {0.f, 0.f, 0.f, 0.f};
        f32x4 s0 = MFMA16(kf0, qf, z);       // S^T: lane(g,c) r -> (key0+4g+r, q=r0w+c)
        f32x4 s1 = MFMA16(kf1, qf, z);

        float p0[4], p1[4];
        #pragma unroll
        for (int r = 0; r < 4; ++r) {
            p0[r] = ((mw >> (bb + r)) & 1u)      ? exp2f(s0[r] * SC2) : 0.f;
            p1[r] = ((mw >> (16 + bb + r)) & 1u) ? exp2f(s1[r] * SC2) : 0.f;
        }
        lsum += p0[0] + p0[1] + p0[2] + p0[3] + p1[0] + p1[1] + p1[2] + p1[3];

        int w00 = (int)bf16bits(p0[0]) | ((int)bf16bits(p0[1]) << 16);
        int w01 = (int)bf16bits(p0[2]) | ((int)bf16bits(p0[3]) << 16);
        int w10 = (int)bf16bits(p1[0]) | ((int)bf16bits(p1[1]) << 16);
        int w11 = (int)bf16bits(p1[2]) | ((int)bf16bits(p1[3]) << 16);

        // gather B-frag: lane(g,c) needs P[q=r0w+c][key0 + 8g + j], j=0..7
        int e0, e1;
        union { int wv[4]; v8s v; } pf;
        e0 = __builtin_amdgcn_ds_bpermute(aA, w00);
        e1 = __builtin_amdgcn_ds_bpermute(aA, w10);
        pf.wv[0] = lo ? e0 : e1;
        e0 = __builtin_amdgcn_ds_bpermute(aA, w01);
        e1 = __builtin_amdgcn_ds_bpermute(aA, w11);
        pf.wv[1] = lo ? e0 : e1;
        e0 = __builtin_amdgcn_ds_bpermute(aB, w00);
        e1 = __builtin_amdgcn_ds_bpermute(aB, w10);
        pf.wv[2] = lo ? e0 : e1;
        e0 = __builtin_amdgcn_ds_bpermute(aB, w01);
        e1 = __builtin_amdgcn_ds_bpermute(aB, w11);
        pf.wv[3] = lo ? e0 : e1;

        v8s vf0 = *(const v8s*)(Vp + (size_t)c * 2048 + key0 + g * 8);
        v8s vf1 = *(const v8s*)(Vp + (size_t)(16 + c) * 2048 + key0 + g * 8);
        o0 = MFMA16(pf.v, vf0, o0);
        o1 = MFMA16(pf.v, vf1, o1);
    }

    lsum += __shfl_xor(lsum, 16);
    lsum += __shfl_xor(lsum, 32);   // all lanes (.,c): partial l for q=r0w+c

    *(f32x4*)&OLDS[w][lane][0] = o0;
    *(f32x4*)&OLDS[w][lane][4] = o1;
    if (lane < 16) lred[w][lane] = lsum;
    __syncthreads();

    if (tid < 64) {
        float iv[4];
        #pragma unroll
        for (int r = 0; r < 4; ++r) {
            float s = lred[0][bb + r] + lred[1][bb + r] + lred[2][bb + r] + lred[3][bb + r];
            iv[r] = 1.f / s;
        }
        f32x4 a0 = *(f32x4*)&OLDS[0][lane][0];
        f32x4 a1 = *(f32x4*)&OLDS[0][lane][4];
        #pragma unroll
        for (int ww = 1; ww < 4; ++ww) {
            a0 += *(f32x4*)&OLDS[ww][lane][0];
            a1 += *(f32x4*)&OLDS[ww][lane][4];
        }
        #pragma unroll
        for (int r = 0; r < 4; ++r) {
            size_t base = ((size_t)b * 2048 + r0w + bb + r) * 128 + h * 32;
            O[base + c]      = a0[r] * iv[r];
            O[base + 16 + c] = a1[r] * iv[r];
        }
    }
}

// ---------------------------------------------------------------------------
// Graph adjacency + fused top-k + masked re-softmax -> bf16 ADJb.
// (unchanged numerics from round 2)
// ---------------------------------------------------------------------------
__global__ __launch_bounds__(256) void gadjtopk_k(
    const float* __restrict__ Kg, const float* __restrict__ QgT,
    __hip_bfloat16* __restrict__ ADJb)
{
    __shared__ float kg_s[4][32];
    __shared__ float scores[4][2048];
    __shared__ float redm[4][4], reds[4][4];

    const int tid = threadIdx.x;
    const int wg = blockIdx.x;     // 0..1023
    const int b = wg >> 9;
    const int r0 = (wg & 511) << 2;

    if (tid < 128) {
        int rr = tid >> 5, d = tid & 31;
        kg_s[rr][d] = Kg[((size_t)b * 2048 + r0 + rr) * 32 + d];
    }
    __syncthreads();

    const float* Qp = QgT + (size_t)b * 32 * 2048;
    float acc[4][8];
    #pragma unroll
    for (int rr = 0; rr < 4; ++rr)
        #pragma unroll
        for (int s = 0; s < 8; ++s) acc[rr][s] = 0.f;

    #pragma unroll
    for (int d0 = 0; d0 < 32; d0 += 8) {
        float qr[4][8];
        #pragma unroll
        for (int rr = 0; rr < 4; ++rr)
            #pragma unroll
            for (int dd = 0; dd < 8; ++dd) qr[rr][dd] = kg_s[rr][d0 + dd];
        #pragma unroll
        for (int dd = 0; dd < 8; ++dd) {
            const float* kp = Qp + (size_t)(d0 + dd) * 2048 + tid;
            #pragma unroll
            for (int s = 0; s < 8; ++s) {
                float kv = kp[s * 256];
                acc[0][s] = fmaf(qr[0][dd], kv, acc[0][s]);
                acc[1][s] = fmaf(qr[1][dd], kv, acc[1][s]);
                acc[2][s] = fmaf(qr[2][dd], kv, acc[2][s]);
                acc[3][s] = fmaf(qr[3][dd], kv, acc[3][s]);
            }
        }
    }
    #pragma unroll
    for (int s = 0; s < 8; ++s) {
        int jj = tid + 256 * s;
        #pragma unroll
        for (int rr = 0; rr < 4; ++rr) scores[rr][jj] = acc[rr][s];
    }
    __syncthreads();

    const int lane = tid & 63, wid = tid >> 6;
    #pragma unroll
    for (int rr = 0; rr < 4; ++rr) {
        float m = -3.0e38f;
        #pragma unroll
        for (int s = 0; s < 8; ++s) m = fmaxf(m, scores[rr][tid + 256 * s]);
        m = wave_max_f(m);
        if (lane == 0) redm[rr][wid] = m;
    }
    __syncthreads();
    float mx[4];
    #pragma unroll
    for (int rr = 0; rr < 4; ++rr)
        mx[rr] = fmaxf(fmaxf(redm[rr][0], redm[rr][1]), fmaxf(redm[rr][2], redm[rr][3]));
    #pragma unroll
    for (int rr = 0; rr < 4; ++rr) {
        float sm = 0.f;
        #pragma unroll
        for (int s = 0; s < 8; ++s) {
            int jj = tid + 256 * s;
            float p = expf(scores[rr][jj] - mx[rr]);
            scores[rr][jj] = p;
            sm += p;
        }
        sm = wave_sum_f(sm);
        if (lane == 0) reds[rr][wid] = sm;
    }
    __syncthreads();

    // ---- fused top-k: wave `wid` owns row r0+wid ----
    const float ivw = 1.f / (reds[wid][0] + reds[wid][1] + reds[wid][2] + reds[wid][3]);
    unsigned k_[32];
    float mxp = 0.f;
    #pragma unroll
    for (int i = 0; i < 32; ++i) {
        float p = scores[wid][lane + i * 64] * ivw;
        k_[i] = __float_as_uint(p);
        mxp = fmaxf(mxp, p);
    }
    mxp = wave_max_f(mxp);

    unsigned thr = 0u;
    for (int bit = 29; bit >= 0; --bit) {
        unsigned cand = thr | (1u << bit);
        int cnt = 0;
        #pragma unroll
        for (int i = 0; i < 32; ++i) cnt += (k_[i] >= cand) ? 1 : 0;
        cnt = wave_sum_i(cnt);
        if (cnt >= KK_TOP) thr = cand;
    }

    int gt_c = 0;
    #pragma unroll
    for (int i = 0; i < 32; ++i) gt_c += (k_[i] > thr) ? 1 : 0;
    gt_c = wave_sum_i(gt_c);
    const int need = KK_TOP - gt_c;

    unsigned keepmask = 0u;
    int running = 0;
    const unsigned long long ltmask = (lane == 0) ? 0ull : (~0ull >> (64 - lane));
    #pragma unroll
    for (int i = 0; i < 32; ++i) {
        bool tie = (k_[i] == thr);
        unsigned long long bal = __ballot(tie);
        int before = running + (int)__popcll(bal & ltmask);
        bool keep = (k_[i] > thr) || (tie && before < need);
        running += (int)__popcll(bal);
        if (keep) keepmask |= (1u << i);
    }

    const float LOG2E = 1.4426950408889634f;
    float sm = 0.f;
    #pragma unroll
    for (int i = 0; i < 32; ++i)
        if ((keepmask >> i) & 1u)
            sm += exp2f((__uint_as_float(k_[i]) - mxp) * LOG2E);
    sm = wave_sum_f(sm);
    const float ivs = 1.f / sm;

    __hip_bfloat16* rp = ADJb + (size_t)(b * 2048 + r0 + wid) * 2048;
    #pragma unroll
    for (int i = 0; i < 32; ++i) {
        float o = ((keepmask >> i) & 1u)
                    ? exp2f((__uint_as_float(k_[i]) - mxp) * LOG2E) * ivs : 0.f;
        rp[lane + i * 64] = __float2bfloat16(o);
    }
}

// ---------------------------------------------------------------------------
// Fused support weight: MT[c][k] = sum_i cv_w[i,k]*gc_w[i,c]; B2 likewise.
// ---------------------------------------------------------------------------
__global__ __launch_bounds__(256) void fusew_k(
    const float* __restrict__ cv_w, const float* __restrict__ cv_b,
    const float* __restrict__ gc_w, float* __restrict__ MT, float* __restrict__ B2)
{
    int c = blockIdx.x * 2 + (threadIdx.x >> 7);
    int k = threadIdx.x & 127;
    float a = 0.f;
    for (int i = 0; i < 128; ++i) a += cv_w[(size_t)i * 128 + k] * gc_w[(size_t)i * 128 + c];
    MT[(size_t)c * 128 + k] = a;
    if (blockIdx.x == 0 && threadIdx.x < 128) {
        float s = 0.f;
        for (int i = 0; i < 128; ++i) s += cv_b[i] * gc_w[(size_t)i * 128 + threadIdx.x];
        B2[threadIdx.x] = s;
    }
}

// ---------------------------------------------------------------------------
// Final GEMM (MFMA), 4-wave K-split: OUT[row,c] = sum_m ADJb[row][m]*SUPt[b][c][m].
// Block = 16 rows x 128 cols; wave w covers k in [w*512,(w+1)*512); LDS combine.
// ---------------------------------------------------------------------------
__global__ __launch_bounds__(256) void outgemm_mfma_k(
    const short* __restrict__ ADJb, const short* __restrict__ SUPt,
    const float* __restrict__ gcb, float* __restrict__ OUT)
{
    __shared__ __align__(16) float OL[4][64][32];
    const int tid = threadIdx.x;
    const int w = tid >> 6, lane = tid & 63;
    const int g = lane >> 4, c = lane & 15;
    const int r0w = blockIdx.x * 16;          // 0..4080 (global row incl. batch)
    const int b = r0w >> 11;
    const short* Bp = SUPt + (size_t)b * 128 * 2048;

    f32x4 acc[8];
    #pragma unroll
    for (int f = 0; f < 8; ++f) acc[f] = (f32x4){0.f, 0.f, 0.f, 0.f};

    #pragma unroll 2
    for (int i = 0; i < 16; ++i) {
        const int k0 = w * 512 + i * 32;
        v8s af = *(const v8s*)(ADJb + (size_t)(r0w + c) * 2048 + k0 + g * 8);
        #pragma unroll
        for (int f = 0; f < 8; ++f) {
            v8s bf_ = *(const v8s*)(Bp + (size_t)(f * 16 + c) * 2048 + k0 + g * 8);
            acc[f] = MFMA16(af, bf_, acc[f]);
        }
    }

    #pragma unroll
    for (int f = 0; f < 8; ++f) *(f32x4*)&OL[w][lane][f * 4] = acc[f];
    __syncthreads();

    // thread (w,lane) reduces slots s = w*8 .. w*8+7 of its lane
    const int sbase = w * 8;
    #pragma unroll
    for (int u = 0; u < 8; ++u) {
        int s = sbase + u;
        float v = OL[0][lane][s] + OL[1][lane][s] + OL[2][lane][s] + OL[3][lane][s];
        int f = s >> 2, r = s & 3;
        int row = r0w + 4 * g + r;
        int col = f * 16 + c;
        OUT[(size_t)row * 128 + col] = v + gcb[col];
    }
}

// ---------------------------------------------------------------------------
extern "C" void kernel_launch(void* const* d_in, const int* in_sizes, int n_in,
                              void* d_out, int out_size, void* d_ws, size_t ws_size,
                              hipStream_t stream)
{
    const float* x       = (const float*)d_in[0];
    const int*   A       = (const int*)d_in[1];
    const float* q_w1    = (const float*)d_in[2];
    const float* kv_w1   = (const float*)d_in[3];
    const float* proj_w1 = (const float*)d_in[4];
    const float* proj_b1 = (const float*)d_in[5];
    const float* q_w2    = (const float*)d_in[6];
    const float* kv_w2   = (const float*)d_in[7];
    const float* proj_w2 = (const float*)d_in[8];
    const float* proj_b2 = (const float*)d_in[9];
    const float* cq_w    = (const float*)d_in[10];
    const float* cq_b    = (const float*)d_in[11];
    const float* ck_w    = (const float*)d_in[12];
    const float* ck_b    = (const float*)d_in[13];
    const float* cv_w    = (const float*)d_in[14];
    const float* cv_b    = (const float*)d_in[15];
    const float* gc_w    = (const float*)d_in[16];
    const float* gc_b    = (const float*)d_in[17];
    float* out = (float*)d_out;

    // Workspace layout (bytes, 256-aligned). Total ~28.9 MB.
    char* ws = (char*)d_ws;
    __hip_bfloat16* Qb   = (__hip_bfloat16*)(ws + 0);          // 1 MB
    __hip_bfloat16* Kb   = (__hip_bfloat16*)(ws + 1048576);    // 1 MB
    __hip_bfloat16* Vt   = (__hip_bfloat16*)(ws + 2097152);    // 1 MB
    __hip_bfloat16* ADJb = (__hip_bfloat16*)(ws + 3145728);    // 16 MB
    unsigned*       Ab2  = (unsigned*)      (ws + 19922944);   // 512 KB
    float*          O    = (float*)         (ws + 20447232);   // 2 MB
    float*          X1   = (float*)         (ws + 22544384);   // 2 MB
    float*          X2   = (float*)         (ws + 24641536);   // 2 MB
    float*          QgT  = (float*)         (ws + 26738688);   // 512 KB
    float*          Kg   = (float*)         (ws + 27262976);   // 512 KB
    __hip_bfloat16* SUPt = (__hip_bfloat16*)(ws + 27787264);   // 1 MB
    float*          MT   = (float*)         (ws + 28835840);   // 64 KB
    float*          B2   = (float*)         (ws + 28901376);   // 512 B

    dim3 blk(256);

    hipLaunchKernelGGL(packA2_k, dim3(512), blk, 0, stream, A, Ab2);
    hipLaunchKernelGGL(fusew_k, dim3(64), blk, 0, stream, cv_w, cv_b, gc_w, MT, B2);

    // ---- attention block 1 ----
    hipLaunchKernelGGL((gemm128_k<MODE_QKV>), dim3(64, 12), blk, 0, stream,
                       x, q_w1, kv_w1, nullptr, nullptr, Qb, Kb, Vt);
    hipLaunchKernelGGL(attn_mfma_k, dim3(1024), blk, 0, stream,
                       (const short*)Qb, (const short*)Kb, (const short*)Vt, Ab2, O);
    hipLaunchKernelGGL((gemm128_k<MODE_PROJ>), dim3(64, 4), blk, 0, stream,
                       O, proj_w1, nullptr, proj_b1, x, X1, nullptr, nullptr);

    // ---- attention block 2 ----
    hipLaunchKernelGGL((gemm128_k<MODE_QKV>), dim3(64, 12), blk, 0, stream,
                       X1, q_w2, kv_w2, nullptr, nullptr, Qb, Kb, Vt);
    hipLaunchKernelGGL(attn_mfma_k, dim3(1024), blk, 0, stream,
                       (const short*)Qb, (const short*)Kb, (const short*)Vt, Ab2, O);
    hipLaunchKernelGGL((gemm128_k<MODE_PROJ>), dim3(64, 4), blk, 0, stream,
                       O, proj_w2, nullptr, proj_b2, X1, X2, nullptr, nullptr);

    // ---- graph conv ----
    hipLaunchKernelGGL((gemm128_k<MODE_QG>), dim3(64, 1), blk, 0, stream,
                       X2, cq_w, nullptr, cq_b, nullptr, QgT, nullptr, nullptr);
    hipLaunchKernelGGL((gemm128_k<MODE_KG>), dim3(64, 1), blk, 0, stream,
                       X2, ck_w, nullptr, ck_b, nullptr, Kg, nullptr, nullptr);
    hipLaunchKernelGGL((gemm128_k<MODE_SUP>), dim3(64, 4), blk, 0, stream,
                       X2, MT, nullptr, B2, nullptr, SUPt, nullptr, nullptr);
    hipLaunchKernelGGL(gadjtopk_k, dim3(1024), blk, 0, stream, Kg, QgT, ADJb);
    hipLaunchKernelGGL(outgemm_mfma_k, dim3(256), blk, 0, stream,
                       (const short*)ADJb, (const short*)SUPt, gc_b, out);
}

// Round 4
// 305.789 us; speedup vs baseline: 2.7657x; 1.0421x over previous
//
#include <hip/hip_runtime.h>
#include <hip/hip_bf16.h>
#include <math.h>

#define BB 2
#define NN 2048
#define CC 128
#define HH 4
#define HD 32
#define KK_TOP 1365   // int(2048/3*2)

typedef __attribute__((ext_vector_type(8))) short v8s;
typedef __attribute__((ext_vector_type(4))) float f32x4;

#define MFMA16(a, b, c) __builtin_amdgcn_mfma_f32_16x16x32_bf16(a, b, c, 0, 0, 0)

__device__ inline float wave_max_f(float v) {
    #pragma unroll
    for (int m = 1; m < 64; m <<= 1) v = fmaxf(v, __shfl_xor(v, m));
    return v;
}
__device__ inline float wave_min_f(float v) {
    #pragma unroll
    for (int m = 1; m < 64; m <<= 1) v = fminf(v, __shfl_xor(v, m));
    return v;
}
__device__ inline float wave_sum_f(float v) {
    #pragma unroll
    for (int m = 1; m < 64; m <<= 1) v += __shfl_xor(v, m);
    return v;
}
__device__ inline unsigned short bf16bits(float x) {
    __hip_bfloat16 h = __float2bfloat16(x);
    return *reinterpret_cast<unsigned short*>(&h);
}

// ---------------------------------------------------------------------------
// prep: blocks 0..511 pack mask A into row-major bitwords
//       (bit t of Ab2[q*64+kw] = A[q][kw*32+t] > 0);
//       blocks 512..575 compute fused support weight MT/B2.
// ---------------------------------------------------------------------------
__global__ __launch_bounds__(256) void prep_k(
    const int* __restrict__ A, unsigned* __restrict__ Ab2,
    const float* __restrict__ cv_w, const float* __restrict__ cv_b,
    const float* __restrict__ gc_w, float* __restrict__ MT, float* __restrict__ B2)
{
    const int bx = blockIdx.x;
    if (bx < 512) {
        const int lane = threadIdx.x & 63;
        const int w = threadIdx.x >> 6;
        const int row = bx * 4 + w;
        const int* rp = A + (size_t)row * 2048;
        for (int i = 0; i < 32; ++i) {
            unsigned long long bal = __ballot(rp[i * 64 + lane] > 0);
            if (lane == 0)  Ab2[(size_t)row * 64 + 2 * i]     = (unsigned)bal;
            if (lane == 32) Ab2[(size_t)row * 64 + 2 * i + 1] = (unsigned)(bal >> 32);
        }
    } else {
        const int b2 = bx - 512;
        const int c = b2 * 2 + (threadIdx.x >> 7);
        const int k = threadIdx.x & 127;
        float a = 0.f;
        #pragma unroll 4
        for (int i = 0; i < 128; ++i)
            a += cv_w[(size_t)i * 128 + k] * gc_w[(size_t)i * 128 + c];
        MT[(size_t)c * 128 + k] = a;
        if (b2 == 0 && threadIdx.x < 128) {
            float s = 0.f;
            #pragma unroll 4
            for (int i = 0; i < 128; ++i)
                s += cv_b[i] * gc_w[(size_t)i * 128 + threadIdx.x];
            B2[threadIdx.x] = s;
        }
    }
}

// ---------------------------------------------------------------------------
// Generic 128-K GEMM (f32 VALU): out = X[M,128] @ W[NC,128]^T + epilogues.
// ---------------------------------------------------------------------------
enum { MODE_QKV = 0, MODE_PROJ = 1 };

template <int MODE>
__global__ __launch_bounds__(256) void gemm128_k(
    const float* __restrict__ X, const float* __restrict__ W0,
    const float* __restrict__ W1, const float* __restrict__ bias,
    const float* __restrict__ resid, void* __restrict__ out0v,
    void* __restrict__ out1v, void* __restrict__ out2v)
{
    __shared__ __align__(16) float Xs[64][132];
    __shared__ __align__(16) float Ws[32][132];
    const int tid = threadIdx.x;
    const int m0 = blockIdx.x * 64;
    const int n0 = blockIdx.y * 32;

    #pragma unroll
    for (int i = 0; i < 32; ++i) {
        int idx = tid + i * 256;
        int row = idx >> 7, col = idx & 127;
        Xs[row][col] = X[(size_t)(m0 + row) * 128 + col];
    }
    #pragma unroll
    for (int i = 0; i < 16; ++i) {
        int idx = tid + i * 256;
        int r = idx >> 7, col = idx & 127;
        int gr = n0 + r;
        const float* wp;
        if (MODE == MODE_QKV)
            wp = (gr < 128) ? (W0 + (size_t)gr * 128) : (W1 + (size_t)(gr - 128) * 128);
        else
            wp = W0 + (size_t)gr * 128;
        Ws[r][col] = wp[col];
    }
    __syncthreads();

    const int r = tid >> 4;
    const int c = tid & 15;
    float acc[4][2] = {{0.f, 0.f}, {0.f, 0.f}, {0.f, 0.f}, {0.f, 0.f}};

    #pragma unroll
    for (int k = 0; k < 128; k += 4) {
        float4 w0 = *(const float4*)&Ws[c][k];
        float4 w1 = *(const float4*)&Ws[c + 16][k];
        #pragma unroll
        for (int i = 0; i < 4; ++i) {
            float4 xv = *(const float4*)&Xs[r + 16 * i][k];
            acc[i][0] += xv.x * w0.x + xv.y * w0.y + xv.z * w0.z + xv.w * w0.w;
            acc[i][1] += xv.x * w1.x + xv.y * w1.y + xv.z * w1.z + xv.w * w1.w;
        }
    }

    #pragma unroll
    for (int i = 0; i < 4; ++i) {
        int m = m0 + r + 16 * i;
        int b = m >> 11, n = m & 2047;
        #pragma unroll
        for (int jj = 0; jj < 2; ++jj) {
            int ccol = n0 + c + 16 * jj;
            float v = acc[i][jj];
            if (MODE == MODE_QKV) {
                __hip_bfloat16 hv = __float2bfloat16(v);
                if (ccol < 128) {
                    int hh = ccol >> 5, d = ccol & 31;
                    ((__hip_bfloat16*)out0v)[((size_t)(b * 4 + hh) * 2048 + n) * 32 + d] = hv;  // Qb
                } else if (ccol < 256) {
                    int c2 = ccol - 128; int hh = c2 >> 5, d = c2 & 31;
                    ((__hip_bfloat16*)out1v)[((size_t)(b * 4 + hh) * 2048 + n) * 32 + d] = hv;  // Kb
                } else {
                    int c2 = ccol - 256; int hh = c2 >> 5, d = c2 & 31;
                    ((__hip_bfloat16*)out2v)[((size_t)(b * 4 + hh) * 32 + d) * 2048 + n] = hv;  // Vt
                }
            } else { // MODE_PROJ
                ((float*)out0v)[(size_t)m * 128 + ccol] = v + bias[ccol] + resid[(size_t)m * 128 + ccol];
            }
        }
    }
}

// ---------------------------------------------------------------------------
// Merged QG + KG + SUP GEMM on X2. blockIdx.y: 0=QG, 1=KG, 2..5=SUP cols.
// Inner loop/staging identical to gemm128_k -> bit-identical QG/KG values.
// ---------------------------------------------------------------------------
__global__ __launch_bounds__(256) void graphmm_k(
    const float* __restrict__ X, const float* __restrict__ cq_w,
    const float* __restrict__ cq_b, const float* __restrict__ ck_w,
    const float* __restrict__ ck_b, const float* __restrict__ MT,
    const float* __restrict__ B2, float* __restrict__ QgT,
    float* __restrict__ Kg, __hip_bfloat16* __restrict__ SUPt)
{
    __shared__ __align__(16) float Xs[64][132];
    __shared__ __align__(16) float Ws[32][132];
    const int tid = threadIdx.x;
    const int m0 = blockIdx.x * 64;
    const int y = blockIdx.y;
    const float* W0   = (y == 0) ? cq_w : (y == 1) ? ck_w : MT;
    const float* bias = (y == 0) ? cq_b : (y == 1) ? ck_b : B2;
    const int n0 = (y < 2) ? 0 : (y - 2) * 32;

    #pragma unroll
    for (int i = 0; i < 32; ++i) {
        int idx = tid + i * 256;
        int row = idx >> 7, col = idx & 127;
        Xs[row][col] = X[(size_t)(m0 + row) * 128 + col];
    }
    #pragma unroll
    for (int i = 0; i < 16; ++i) {
        int idx = tid + i * 256;
        int r = idx >> 7, col = idx & 127;
        Ws[r][col] = W0[(size_t)(n0 + r) * 128 + col];
    }
    __syncthreads();

    const int r = tid >> 4;
    const int c = tid & 15;
    float acc[4][2] = {{0.f, 0.f}, {0.f, 0.f}, {0.f, 0.f}, {0.f, 0.f}};

    #pragma unroll
    for (int k = 0; k < 128; k += 4) {
        float4 w0 = *(const float4*)&Ws[c][k];
        float4 w1 = *(const float4*)&Ws[c + 16][k];
        #pragma unroll
        for (int i = 0; i < 4; ++i) {
            float4 xv = *(const float4*)&Xs[r + 16 * i][k];
            acc[i][0] += xv.x * w0.x + xv.y * w0.y + xv.z * w0.z + xv.w * w0.w;
            acc[i][1] += xv.x * w1.x + xv.y * w1.y + xv.z * w1.z + xv.w * w1.w;
        }
    }

    #pragma unroll
    for (int i = 0; i < 4; ++i) {
        int m = m0 + r + 16 * i;
        int b = m >> 11, n = m & 2047;
        #pragma unroll
        for (int jj = 0; jj < 2; ++jj) {
            int ccol = n0 + c + 16 * jj;
            float v = acc[i][jj];
            if (y == 0) {
                QgT[((size_t)b * 32 + ccol) * 2048 + n] = v + bias[ccol];
            } else if (y == 1) {
                Kg[(size_t)m * 32 + ccol] = v + bias[ccol];
            } else {
                SUPt[((size_t)b * 128 + ccol) * 2048 + n] = __float2bfloat16(v + bias[ccol]);
            }
        }
    }
}

// ---------------------------------------------------------------------------
// MFMA attention (unchanged from round 3).
// ---------------------------------------------------------------------------
__global__ __launch_bounds__(256) void attn_mfma_k(
    const short* __restrict__ Qb, const short* __restrict__ Kb,
    const short* __restrict__ Vt, const unsigned* __restrict__ Ab2,
    float* __restrict__ O)
{
    __shared__ __align__(16) float OLDS[4][64][8];
    __shared__ float lred[4][16];

    const int tid = threadIdx.x;
    const int w = tid >> 6, lane = tid & 63;
    const int g = lane >> 4, c = lane & 15;
    const int bb = 4 * g;
    const int wg = blockIdx.x;                 // 0..1023
    const int b = wg >> 9, h = (wg >> 7) & 3, r0w = (wg & 127) << 4;
    const int bh = b * 4 + h;

    const v8s qf = *(const v8s*)(Qb + ((size_t)bh * 2048 + r0w + c) * 32 + g * 8);
    const short* Kp = Kb + (size_t)bh * 2048 * 32;
    const short* Vp = Vt + (size_t)bh * 32 * 2048;
    const unsigned* Mrow = Ab2 + (size_t)(r0w + c) * 64;

    f32x4 o0 = {0.f, 0.f, 0.f, 0.f}, o1 = {0.f, 0.f, 0.f, 0.f};
    float lsum = 0.f;
    const float SC2 = 0.25503487f;   // 32^-0.5 * log2(e)
    const bool lo = (g < 2);
    const int aA = (32 * (g & 1) + c) * 4;
    const int aB = aA + 64;

    #pragma unroll 2
    for (int t = 0; t < 16; ++t) {
        const int kt = t * 4 + w;
        const int key0 = kt * 32;
        v8s kf0 = *(const v8s*)(Kp + (size_t)(key0 + c) * 32 + g * 8);
        v8s kf1 = *(const v8s*)(Kp + (size_t)(key0 + 16 + c) * 32 + g * 8);
        unsigned mw = Mrow[kt];
        const f32x4 z = {0.f, 0.f, 0.f, 0.f};
        f32x4 s0 = MFMA16(kf0, qf, z);
        f32x4 s1 = MFMA16(kf1, qf, z);

        float p0[4], p1[4];
        #pragma unroll
        for (int r = 0; r < 4; ++r) {
            p0[r] = ((mw >> (bb + r)) & 1u)      ? exp2f(s0[r] * SC2) : 0.f;
            p1[r] = ((mw >> (16 + bb + r)) & 1u) ? exp2f(s1[r] * SC2) : 0.f;
        }
        lsum += p0[0] + p0[1] + p0[2] + p0[3] + p1[0] + p1[1] + p1[2] + p1[3];

        int w00 = (int)bf16bits(p0[0]) | ((int)bf16bits(p0[1]) << 16);
        int w01 = (int)bf16bits(p0[2]) | ((int)bf16bits(p0[3]) << 16);
        int w10 = (int)bf16bits(p1[0]) | ((int)bf16bits(p1[1]) << 16);
        int w11 = (int)bf16bits(p1[2]) | ((int)bf16bits(p1[3]) << 16);

        int e0, e1;
        union { int wv[4]; v8s v; } pf;
        e0 = __builtin_amdgcn_ds_bpermute(aA, w00);
        e1 = __builtin_amdgcn_ds_bpermute(aA, w10);
        pf.wv[0] = lo ? e0 : e1;
        e0 = __builtin_amdgcn_ds_bpermute(aA, w01);
        e1 = __builtin_amdgcn_ds_bpermute(aA, w11);
        pf.wv[1] = lo ? e0 : e1;
        e0 = __builtin_amdgcn_ds_bpermute(aB, w00);
        e1 = __builtin_amdgcn_ds_bpermute(aB, w10);
        pf.wv[2] = lo ? e0 : e1;
        e0 = __builtin_amdgcn_ds_bpermute(aB, w01);
        e1 = __builtin_amdgcn_ds_bpermute(aB, w11);
        pf.wv[3] = lo ? e0 : e1;

        v8s vf0 = *(const v8s*)(Vp + (size_t)c * 2048 + key0 + g * 8);
        v8s vf1 = *(const v8s*)(Vp + (size_t)(16 + c) * 2048 + key0 + g * 8);
        o0 = MFMA16(pf.v, vf0, o0);
        o1 = MFMA16(pf.v, vf1, o1);
    }

    lsum += __shfl_xor(lsum, 16);
    lsum += __shfl_xor(lsum, 32);

    *(f32x4*)&OLDS[w][lane][0] = o0;
    *(f32x4*)&OLDS[w][lane][4] = o1;
    if (lane < 16) lred[w][lane] = lsum;
    __syncthreads();

    if (tid < 64) {
        float iv[4];
        #pragma unroll
        for (int r = 0; r < 4; ++r) {
            float s = lred[0][bb + r] + lred[1][bb + r] + lred[2][bb + r] + lred[3][bb + r];
            iv[r] = 1.f / s;
        }
        f32x4 a0 = *(f32x4*)&OLDS[0][lane][0];
        f32x4 a1 = *(f32x4*)&OLDS[0][lane][4];
        #pragma unroll
        for (int ww = 1; ww < 4; ++ww) {
            a0 += *(f32x4*)&OLDS[ww][lane][0];
            a1 += *(f32x4*)&OLDS[ww][lane][4];
        }
        #pragma unroll
        for (int r = 0; r < 4; ++r) {
            size_t base = ((size_t)b * 2048 + r0w + bb + r) * 128 + h * 32;
            O[base + c]      = a0[r] * iv[r];
            O[base + 16 + c] = a1[r] * iv[r];
        }
    }
}

// ---------------------------------------------------------------------------
// Graph adjacency + fused top-k + masked re-softmax -> bf16 ADJb.
// GEMM phase: thread owns 8 consecutive cols (float4 loads); per-output fmaf
// chains keep dd=0..31 ascending -> values bit-identical to round 3.
// Softmax phase reads strided (original pattern) -> sums bit-identical.
// Select: ballot+popcount counting (exact) + common-prefix skip (exact).
// ---------------------------------------------------------------------------
__global__ __launch_bounds__(256) void gadjtopk_k(
    const float* __restrict__ Kg, const float* __restrict__ QgT,
    __hip_bfloat16* __restrict__ ADJb)
{
    __shared__ float kg_s[4][32];
    __shared__ float scores[4][2048];
    __shared__ float redm[4][4], reds[4][4];

    const int tid = threadIdx.x;
    const int wg = blockIdx.x;     // 0..1023
    const int b = wg >> 9;
    const int r0 = (wg & 511) << 2;

    if (tid < 128) {
        int rr = tid >> 5, d = tid & 31;
        kg_s[rr][d] = Kg[((size_t)b * 2048 + r0 + rr) * 32 + d];
    }
    __syncthreads();

    const float* Qp = QgT + (size_t)b * 32 * 2048;
    const int ncol = tid * 8;
    float acc[4][8];
    #pragma unroll
    for (int rr = 0; rr < 4; ++rr)
        #pragma unroll
        for (int j = 0; j < 8; ++j) acc[rr][j] = 0.f;

    #pragma unroll
    for (int d0 = 0; d0 < 32; d0 += 8) {
        float qr[4][8];
        #pragma unroll
        for (int rr = 0; rr < 4; ++rr) {
            float4 qa = *(const float4*)&kg_s[rr][d0];
            float4 qb = *(const float4*)&kg_s[rr][d0 + 4];
            qr[rr][0] = qa.x; qr[rr][1] = qa.y; qr[rr][2] = qa.z; qr[rr][3] = qa.w;
            qr[rr][4] = qb.x; qr[rr][5] = qb.y; qr[rr][6] = qb.z; qr[rr][7] = qb.w;
        }
        #pragma unroll
        for (int dd = 0; dd < 8; ++dd) {
            const float* kp = Qp + (size_t)(d0 + dd) * 2048 + ncol;
            float4 v0 = *(const float4*)kp;
            float4 v1 = *(const float4*)(kp + 4);
            float kv[8] = {v0.x, v0.y, v0.z, v0.w, v1.x, v1.y, v1.z, v1.w};
            #pragma unroll
            for (int rr = 0; rr < 4; ++rr)
                #pragma unroll
                for (int j = 0; j < 8; ++j)
                    acc[rr][j] = fmaf(qr[rr][dd], kv[j], acc[rr][j]);
        }
    }
    #pragma unroll
    for (int rr = 0; rr < 4; ++rr) {
        *(float4*)&scores[rr][ncol]     = (float4){acc[rr][0], acc[rr][1], acc[rr][2], acc[rr][3]};
        *(float4*)&scores[rr][ncol + 4] = (float4){acc[rr][4], acc[rr][5], acc[rr][6], acc[rr][7]};
    }
    __syncthreads();

    const int lane = tid & 63, wid = tid >> 6;
    #pragma unroll
    for (int rr = 0; rr < 4; ++rr) {
        float m = -3.0e38f;
        #pragma unroll
        for (int s = 0; s < 8; ++s) m = fmaxf(m, scores[rr][tid + 256 * s]);
        m = wave_max_f(m);
        if (lane == 0) redm[rr][wid] = m;
    }
    __syncthreads();
    float mx[4];
    #pragma unroll
    for (int rr = 0; rr < 4; ++rr)
        mx[rr] = fmaxf(fmaxf(redm[rr][0], redm[rr][1]), fmaxf(redm[rr][2], redm[rr][3]));
    #pragma unroll
    for (int rr = 0; rr < 4; ++rr) {
        float sm = 0.f;
        #pragma unroll
        for (int s = 0; s < 8; ++s) {
            int jj = tid + 256 * s;
            float p = expf(scores[rr][jj] - mx[rr]);
            scores[rr][jj] = p;
            sm += p;
        }
        sm = wave_sum_f(sm);
        if (lane == 0) reds[rr][wid] = sm;
    }
    __syncthreads();

    // ---- fused top-k: wave `wid` owns row r0+wid ----
    const float ivw = 1.f / (reds[wid][0] + reds[wid][1] + reds[wid][2] + reds[wid][3]);
    unsigned k_[32];
    float mxp = 0.f, mnp = 3.0e38f;
    #pragma unroll
    for (int i = 0; i < 32; ++i) {
        float p = scores[wid][lane + i * 64] * ivw;
        k_[i] = __float_as_uint(p);
        mxp = fmaxf(mxp, p);
        mnp = fminf(mnp, p);
    }
    mxp = wave_max_f(mxp);
    mnp = wave_min_f(mnp);

    unsigned thr = __float_as_uint(mnp);
    const unsigned umax = __float_as_uint(mxp);
    const unsigned diff = thr ^ umax;
    if (diff != 0u) {
        const int hb = 31 - __builtin_clz(diff);
        thr = (umax >> (hb + 1)) << (hb + 1);   // common prefix of [min,max]
        for (int bit = hb; bit >= 0; --bit) {
            unsigned cand = thr | (1u << bit);
            int cnt = 0;
            #pragma unroll
            for (int i = 0; i < 32; ++i)
                cnt += (int)__popcll(__ballot(k_[i] >= cand));
            if (cnt >= KK_TOP) thr = cand;
        }
    }

    int gt_c = 0;
    #pragma unroll
    for (int i = 0; i < 32; ++i)
        gt_c += (int)__popcll(__ballot(k_[i] > thr));
    const int need = KK_TOP - gt_c;

    unsigned keepmask = 0u;
    int running = 0;
    const unsigned long long ltmask = (lane == 0) ? 0ull : (~0ull >> (64 - lane));
    #pragma unroll
    for (int i = 0; i < 32; ++i) {
        bool tie = (k_[i] == thr);
        unsigned long long bal = __ballot(tie);
        int before = running + (int)__popcll(bal & ltmask);
        bool keep = (k_[i] > thr) || (tie && before < need);
        running += (int)__popcll(bal);
        if (keep) keepmask |= (1u << i);
    }

    const float LOG2E = 1.4426950408889634f;
    float e_[32];
    #pragma unroll
    for (int i = 0; i < 32; ++i)
        e_[i] = exp2f((__uint_as_float(k_[i]) - mxp) * LOG2E);
    float sm = 0.f;
    #pragma unroll
    for (int i = 0; i < 32; ++i)
        sm += ((keepmask >> i) & 1u) ? e_[i] : 0.f;
    sm = wave_sum_f(sm);
    const float ivs = 1.f / sm;

    __hip_bfloat16* rp = ADJb + (size_t)(b * 2048 + r0 + wid) * 2048;
    #pragma unroll
    for (int i = 0; i < 32; ++i) {
        float o = ((keepmask >> i) & 1u) ? e_[i] * ivs : 0.f;
        rp[lane + i * 64] = __float2bfloat16(o);
    }
}

// ---------------------------------------------------------------------------
// Final GEMM (MFMA), 4-wave K-split, 2-way col-split:
// OUT[row, n0+..] = sum_m ADJb[row][m] * SUPt[b][col][m] + gcb[col].
// ---------------------------------------------------------------------------
__global__ __launch_bounds__(256) void outgemm_mfma_k(
    const short* __restrict__ ADJb, const short* __restrict__ SUPt,
    const float* __restrict__ gcb, float* __restrict__ OUT)
{
    __shared__ __align__(16) float OL[4][64][16];
    const int tid = threadIdx.x;
    const int w = tid >> 6, lane = tid & 63;
    const int g = lane >> 4, c = lane & 15;
    const int r0w = blockIdx.x * 16;          // 0..4080 (global row incl. batch)
    const int n0 = blockIdx.y * 64;
    const int b = r0w >> 11;
    const short* Bp = SUPt + (size_t)b * 128 * 2048;

    f32x4 acc[4];
    #pragma unroll
    for (int f = 0; f < 4; ++f) acc[f] = (f32x4){0.f, 0.f, 0.f, 0.f};

    #pragma unroll 2
    for (int i = 0; i < 16; ++i) {
        const int k0 = w * 512 + i * 32;
        v8s af = *(const v8s*)(ADJb + (size_t)(r0w + c) * 2048 + k0 + g * 8);
        #pragma unroll
        for (int f = 0; f < 4; ++f) {
            v8s bf_ = *(const v8s*)(Bp + (size_t)(n0 + f * 16 + c) * 2048 + k0 + g * 8);
            acc[f] = MFMA16(af, bf_, acc[f]);
        }
    }

    #pragma unroll
    for (int f = 0; f < 4; ++f) *(f32x4*)&OL[w][lane][f * 4] = acc[f];
    __syncthreads();

    #pragma unroll
    for (int u = 0; u < 4; ++u) {
        int idx = tid + u * 256;        // 0..1023
        int ls = idx >> 4, s = idx & 15;
        float v = OL[0][ls][s] + OL[1][ls][s] + OL[2][ls][s] + OL[3][ls][s];
        int f = s >> 2, r = s & 3;
        int row = r0w + 4 * (ls >> 4) + r;
        int col = n0 + f * 16 + (ls & 15);
        OUT[(size_t)row * 128 + col] = v + gcb[col];
    }
}

// ---------------------------------------------------------------------------
extern "C" void kernel_launch(void* const* d_in, const int* in_sizes, int n_in,
                              void* d_out, int out_size, void* d_ws, size_t ws_size,
                              hipStream_t stream)
{
    const float* x       = (const float*)d_in[0];
    const int*   A       = (const int*)d_in[1];
    const float* q_w1    = (const float*)d_in[2];
    const float* kv_w1   = (const float*)d_in[3];
    const float* proj_w1 = (const float*)d_in[4];
    const float* proj_b1 = (const float*)d_in[5];
    const float* q_w2    = (const float*)d_in[6];
    const float* kv_w2   = (const float*)d_in[7];
    const float* proj_w2 = (const float*)d_in[8];
    const float* proj_b2 = (const float*)d_in[9];
    const float* cq_w    = (const float*)d_in[10];
    const float* cq_b    = (const float*)d_in[11];
    const float* ck_w    = (const float*)d_in[12];
    const float* ck_b    = (const float*)d_in[13];
    const float* cv_w    = (const float*)d_in[14];
    const float* cv_b    = (const float*)d_in[15];
    const float* gc_w    = (const float*)d_in[16];
    const float* gc_b    = (const float*)d_in[17];
    float* out = (float*)d_out;

    // Workspace layout (bytes, 256-aligned). Total ~28.9 MB.
    char* ws = (char*)d_ws;
    __hip_bfloat16* Qb   = (__hip_bfloat16*)(ws + 0);          // 1 MB
    __hip_bfloat16* Kb   = (__hip_bfloat16*)(ws + 1048576);    // 1 MB
    __hip_bfloat16* Vt   = (__hip_bfloat16*)(ws + 2097152);    // 1 MB
    __hip_bfloat16* ADJb = (__hip_bfloat16*)(ws + 3145728);    // 16 MB
    unsigned*       Ab2  = (unsigned*)      (ws + 19922944);   // 512 KB
    float*          O    = (float*)         (ws + 20447232);   // 2 MB
    float*          X1   = (float*)         (ws + 22544384);   // 2 MB
    float*          X2   = (float*)         (ws + 24641536);   // 2 MB
    float*          QgT  = (float*)         (ws + 26738688);   // 512 KB
    float*          Kg   = (float*)         (ws + 27262976);   // 512 KB
    __hip_bfloat16* SUPt = (__hip_bfloat16*)(ws + 27787264);   // 1 MB
    float*          MT   = (float*)         (ws + 28835840);   // 64 KB
    float*          B2   = (float*)         (ws + 28901376);   // 512 B

    dim3 blk(256);

    hipLaunchKernelGGL(prep_k, dim3(576), blk, 0, stream, A, Ab2, cv_w, cv_b, gc_w, MT, B2);

    // ---- attention block 1 ----
    hipLaunchKernelGGL((gemm128_k<MODE_QKV>), dim3(64, 12), blk, 0, stream,
                       x, q_w1, kv_w1, nullptr, nullptr, Qb, Kb, Vt);
    hipLaunchKernelGGL(attn_mfma_k, dim3(1024), blk, 0, stream,
                       (const short*)Qb, (const short*)Kb, (const short*)Vt, Ab2, O);
    hipLaunchKernelGGL((gemm128_k<MODE_PROJ>), dim3(64, 4), blk, 0, stream,
                       O, proj_w1, nullptr, proj_b1, x, X1, nullptr, nullptr);

    // ---- attention block 2 ----
    hipLaunchKernelGGL((gemm128_k<MODE_QKV>), dim3(64, 12), blk, 0, stream,
                       X1, q_w2, kv_w2, nullptr, nullptr, Qb, Kb, Vt);
    hipLaunchKernelGGL(attn_mfma_k, dim3(1024), blk, 0, stream,
                       (const short*)Qb, (const short*)Kb, (const short*)Vt, Ab2, O);
    hipLaunchKernelGGL((gemm128_k<MODE_PROJ>), dim3(64, 4), blk, 0, stream,
                       O, proj_w2, nullptr, proj_b2, X1, X2, nullptr, nullptr);

    // ---- graph conv ----
    hipLaunchKernelGGL(graphmm_k, dim3(64, 6), blk, 0, stream,
                       X2, cq_w, cq_b, ck_w, ck_b, MT, B2, QgT, Kg, SUPt);
    hipLaunchKernelGGL(gadjtopk_k, dim3(1024), blk, 0, stream, Kg, QgT, ADJb);
    hipLaunchKernelGGL(outgemm_mfma_k, dim3(256, 2), blk, 0, stream,
                       (const short*)ADJb, (const short*)SUPt, gc_b, out);
}

// Round 5
// 296.911 us; speedup vs baseline: 2.8484x; 1.0299x over previous
//
#include <hip/hip_runtime.h>
#include <hip/hip_bf16.h>
#include <math.h>

#define BB 2
#define NN 2048
#define CC 128
#define HH 4
#define HD 32
#define KK_TOP 1365   // int(2048/3*2)

typedef __attribute__((ext_vector_type(8))) short v8s;
typedef __attribute__((ext_vector_type(4))) float f32x4;

#define MFMA16(a, b, c) __builtin_amdgcn_mfma_f32_16x16x32_bf16(a, b, c, 0, 0, 0)

__device__ inline float wave_max_f(float v) {
    #pragma unroll
    for (int m = 1; m < 64; m <<= 1) v = fmaxf(v, __shfl_xor(v, m));
    return v;
}
__device__ inline float wave_min_f(float v) {
    #pragma unroll
    for (int m = 1; m < 64; m <<= 1) v = fminf(v, __shfl_xor(v, m));
    return v;
}
__device__ inline float wave_sum_f(float v) {
    #pragma unroll
    for (int m = 1; m < 64; m <<= 1) v += __shfl_xor(v, m);
    return v;
}
__device__ inline unsigned short bf16bits(float x) {
    __hip_bfloat16 h = __float2bfloat16(x);
    return *reinterpret_cast<unsigned short*>(&h);
}

// ---------------------------------------------------------------------------
// prep: blocks 0..511 pack mask A into row-major bitwords
//       (bit t of Ab2[q*64+kw] = A[q][kw*32+t] > 0);
//       blocks 512..575 compute fused support weight MT/B2.
// ---------------------------------------------------------------------------
__global__ __launch_bounds__(256) void prep_k(
    const int* __restrict__ A, unsigned* __restrict__ Ab2,
    const float* __restrict__ cv_w, const float* __restrict__ cv_b,
    const float* __restrict__ gc_w, float* __restrict__ MT, float* __restrict__ B2)
{
    const int bx = blockIdx.x;
    if (bx < 512) {
        const int lane = threadIdx.x & 63;
        const int w = threadIdx.x >> 6;
        const int row = bx * 4 + w;
        const int* rp = A + (size_t)row * 2048;
        for (int i = 0; i < 32; ++i) {
            unsigned long long bal = __ballot(rp[i * 64 + lane] > 0);
            if (lane == 0)  Ab2[(size_t)row * 64 + 2 * i]     = (unsigned)bal;
            if (lane == 32) Ab2[(size_t)row * 64 + 2 * i + 1] = (unsigned)(bal >> 32);
        }
    } else {
        const int b2 = bx - 512;
        const int c = b2 * 2 + (threadIdx.x >> 7);
        const int k = threadIdx.x & 127;
        float a = 0.f;
        #pragma unroll 4
        for (int i = 0; i < 128; ++i)
            a += cv_w[(size_t)i * 128 + k] * gc_w[(size_t)i * 128 + c];
        MT[(size_t)c * 128 + k] = a;
        if (b2 == 0 && threadIdx.x < 128) {
            float s = 0.f;
            #pragma unroll 4
            for (int i = 0; i < 128; ++i)
                s += cv_b[i] * gc_w[(size_t)i * 128 + threadIdx.x];
            B2[threadIdx.x] = s;
        }
    }
}

// ---------------------------------------------------------------------------
// Generic 128-K GEMM (f32 VALU): out = X[M,128] @ W[NC,128]^T + epilogues.
// ---------------------------------------------------------------------------
enum { MODE_QKV = 0, MODE_PROJ = 1 };

template <int MODE>
__global__ __launch_bounds__(256) void gemm128_k(
    const float* __restrict__ X, const float* __restrict__ W0,
    const float* __restrict__ W1, const float* __restrict__ bias,
    const float* __restrict__ resid, void* __restrict__ out0v,
    void* __restrict__ out1v, void* __restrict__ out2v)
{
    __shared__ __align__(16) float Xs[64][132];
    __shared__ __align__(16) float Ws[32][132];
    const int tid = threadIdx.x;
    const int m0 = blockIdx.x * 64;
    const int n0 = blockIdx.y * 32;

    #pragma unroll
    for (int i = 0; i < 32; ++i) {
        int idx = tid + i * 256;
        int row = idx >> 7, col = idx & 127;
        Xs[row][col] = X[(size_t)(m0 + row) * 128 + col];
    }
    #pragma unroll
    for (int i = 0; i < 16; ++i) {
        int idx = tid + i * 256;
        int r = idx >> 7, col = idx & 127;
        int gr = n0 + r;
        const float* wp;
        if (MODE == MODE_QKV)
            wp = (gr < 128) ? (W0 + (size_t)gr * 128) : (W1 + (size_t)(gr - 128) * 128);
        else
            wp = W0 + (size_t)gr * 128;
        Ws[r][col] = wp[col];
    }
    __syncthreads();

    const int r = tid >> 4;
    const int c = tid & 15;
    float acc[4][2] = {{0.f, 0.f}, {0.f, 0.f}, {0.f, 0.f}, {0.f, 0.f}};

    #pragma unroll
    for (int k = 0; k < 128; k += 4) {
        float4 w0 = *(const float4*)&Ws[c][k];
        float4 w1 = *(const float4*)&Ws[c + 16][k];
        #pragma unroll
        for (int i = 0; i < 4; ++i) {
            float4 xv = *(const float4*)&Xs[r + 16 * i][k];
            acc[i][0] += xv.x * w0.x + xv.y * w0.y + xv.z * w0.z + xv.w * w0.w;
            acc[i][1] += xv.x * w1.x + xv.y * w1.y + xv.z * w1.z + xv.w * w1.w;
        }
    }

    #pragma unroll
    for (int i = 0; i < 4; ++i) {
        int m = m0 + r + 16 * i;
        int b = m >> 11, n = m & 2047;
        #pragma unroll
        for (int jj = 0; jj < 2; ++jj) {
            int ccol = n0 + c + 16 * jj;
            float v = acc[i][jj];
            if (MODE == MODE_QKV) {
                __hip_bfloat16 hv = __float2bfloat16(v);
                if (ccol < 128) {
                    int hh = ccol >> 5, d = ccol & 31;
                    ((__hip_bfloat16*)out0v)[((size_t)(b * 4 + hh) * 2048 + n) * 32 + d] = hv;  // Qb
                } else if (ccol < 256) {
                    int c2 = ccol - 128; int hh = c2 >> 5, d = c2 & 31;
                    ((__hip_bfloat16*)out1v)[((size_t)(b * 4 + hh) * 2048 + n) * 32 + d] = hv;  // Kb
                } else {
                    int c2 = ccol - 256; int hh = c2 >> 5, d = c2 & 31;
                    ((__hip_bfloat16*)out2v)[((size_t)(b * 4 + hh) * 32 + d) * 2048 + n] = hv;  // Vt
                }
            } else { // MODE_PROJ
                ((float*)out0v)[(size_t)m * 128 + ccol] = v + bias[ccol] + resid[(size_t)m * 128 + ccol];
            }
        }
    }
}

// ---------------------------------------------------------------------------
// Merged QG + KG + SUP GEMM on X2. blockIdx.y: 0=QG, 1=KG, 2..5=SUP cols.
// ---------------------------------------------------------------------------
__global__ __launch_bounds__(256) void graphmm_k(
    const float* __restrict__ X, const float* __restrict__ cq_w,
    const float* __restrict__ cq_b, const float* __restrict__ ck_w,
    const float* __restrict__ ck_b, const float* __restrict__ MT,
    const float* __restrict__ B2, float* __restrict__ QgT,
    float* __restrict__ Kg, __hip_bfloat16* __restrict__ SUPt)
{
    __shared__ __align__(16) float Xs[64][132];
    __shared__ __align__(16) float Ws[32][132];
    const int tid = threadIdx.x;
    const int m0 = blockIdx.x * 64;
    const int y = blockIdx.y;
    const float* W0   = (y == 0) ? cq_w : (y == 1) ? ck_w : MT;
    const float* bias = (y == 0) ? cq_b : (y == 1) ? ck_b : B2;
    const int n0 = (y < 2) ? 0 : (y - 2) * 32;

    #pragma unroll
    for (int i = 0; i < 32; ++i) {
        int idx = tid + i * 256;
        int row = idx >> 7, col = idx & 127;
        Xs[row][col] = X[(size_t)(m0 + row) * 128 + col];
    }
    #pragma unroll
    for (int i = 0; i < 16; ++i) {
        int idx = tid + i * 256;
        int r = idx >> 7, col = idx & 127;
        Ws[r][col] = W0[(size_t)(n0 + r) * 128 + col];
    }
    __syncthreads();

    const int r = tid >> 4;
    const int c = tid & 15;
    float acc[4][2] = {{0.f, 0.f}, {0.f, 0.f}, {0.f, 0.f}, {0.f, 0.f}};

    #pragma unroll
    for (int k = 0; k < 128; k += 4) {
        float4 w0 = *(const float4*)&Ws[c][k];
        float4 w1 = *(const float4*)&Ws[c + 16][k];
        #pragma unroll
        for (int i = 0; i < 4; ++i) {
            float4 xv = *(const float4*)&Xs[r + 16 * i][k];
            acc[i][0] += xv.x * w0.x + xv.y * w0.y + xv.z * w0.z + xv.w * w0.w;
            acc[i][1] += xv.x * w1.x + xv.y * w1.y + xv.z * w1.z + xv.w * w1.w;
        }
    }

    #pragma unroll
    for (int i = 0; i < 4; ++i) {
        int m = m0 + r + 16 * i;
        int b = m >> 11, n = m & 2047;
        #pragma unroll
        for (int jj = 0; jj < 2; ++jj) {
            int ccol = n0 + c + 16 * jj;
            float v = acc[i][jj];
            if (y == 0) {
                QgT[((size_t)b * 32 + ccol) * 2048 + n] = v + bias[ccol];
            } else if (y == 1) {
                Kg[(size_t)m * 32 + ccol] = v + bias[ccol];
            } else {
                SUPt[((size_t)b * 128 + ccol) * 2048 + n] = __float2bfloat16(v + bias[ccol]);
            }
        }
    }
}

// ---------------------------------------------------------------------------
// MFMA attention v3: 8 waves, 8-way K-split (256 keys each, interleaved).
// Same per-key numerics as v2; only the partial-sum combine order changes
// (4 -> 8 partials), a ~1e-7 relative effect.
// ---------------------------------------------------------------------------
__global__ __launch_bounds__(512, 8) void attn_mfma_k(
    const short* __restrict__ Qb, const short* __restrict__ Kb,
    const short* __restrict__ Vt, const unsigned* __restrict__ Ab2,
    float* __restrict__ O)
{
    __shared__ __align__(16) float OLDS[8][64][8];
    __shared__ float lred[8][16];

    const int tid = threadIdx.x;
    const int w = tid >> 6, lane = tid & 63;
    const int g = lane >> 4, c = lane & 15;
    const int bb = 4 * g;
    const int wg = blockIdx.x;                 // 0..1023
    const int b = wg >> 9, h = (wg >> 7) & 3, r0w = (wg & 127) << 4;
    const int bh = b * 4 + h;

    const v8s qf = *(const v8s*)(Qb + ((size_t)bh * 2048 + r0w + c) * 32 + g * 8);
    const short* Kp = Kb + (size_t)bh * 2048 * 32;
    const short* Vp = Vt + (size_t)bh * 32 * 2048;
    const unsigned* Mrow = Ab2 + (size_t)(r0w + c) * 64;

    f32x4 o0 = {0.f, 0.f, 0.f, 0.f}, o1 = {0.f, 0.f, 0.f, 0.f};
    float lsum = 0.f;
    const float SC2 = 0.25503487f;   // 32^-0.5 * log2(e)
    const bool lo = (g < 2);
    const int aA = (32 * (g & 1) + c) * 4;
    const int aB = aA + 64;

    #pragma unroll 2
    for (int t = 0; t < 8; ++t) {
        const int kt = t * 8 + w;
        const int key0 = kt * 32;
        v8s kf0 = *(const v8s*)(Kp + (size_t)(key0 + c) * 32 + g * 8);
        v8s kf1 = *(const v8s*)(Kp + (size_t)(key0 + 16 + c) * 32 + g * 8);
        unsigned mw = Mrow[kt];
        const f32x4 z = {0.f, 0.f, 0.f, 0.f};
        f32x4 s0 = MFMA16(kf0, qf, z);
        f32x4 s1 = MFMA16(kf1, qf, z);

        float p0[4], p1[4];
        #pragma unroll
        for (int r = 0; r < 4; ++r) {
            p0[r] = ((mw >> (bb + r)) & 1u)      ? exp2f(s0[r] * SC2) : 0.f;
            p1[r] = ((mw >> (16 + bb + r)) & 1u) ? exp2f(s1[r] * SC2) : 0.f;
        }
        lsum += p0[0] + p0[1] + p0[2] + p0[3] + p1[0] + p1[1] + p1[2] + p1[3];

        int w00 = (int)bf16bits(p0[0]) | ((int)bf16bits(p0[1]) << 16);
        int w01 = (int)bf16bits(p0[2]) | ((int)bf16bits(p0[3]) << 16);
        int w10 = (int)bf16bits(p1[0]) | ((int)bf16bits(p1[1]) << 16);
        int w11 = (int)bf16bits(p1[2]) | ((int)bf16bits(p1[3]) << 16);

        int e0, e1;
        union { int wv[4]; v8s v; } pf;
        e0 = __builtin_amdgcn_ds_bpermute(aA, w00);
        e1 = __builtin_amdgcn_ds_bpermute(aA, w10);
        pf.wv[0] = lo ? e0 : e1;
        e0 = __builtin_amdgcn_ds_bpermute(aA, w01);
        e1 = __builtin_amdgcn_ds_bpermute(aA, w11);
        pf.wv[1] = lo ? e0 : e1;
        e0 = __builtin_amdgcn_ds_bpermute(aB, w00);
        e1 = __builtin_amdgcn_ds_bpermute(aB, w10);
        pf.wv[2] = lo ? e0 : e1;
        e0 = __builtin_amdgcn_ds_bpermute(aB, w01);
        e1 = __builtin_amdgcn_ds_bpermute(aB, w11);
        pf.wv[3] = lo ? e0 : e1;

        v8s vf0 = *(const v8s*)(Vp + (size_t)c * 2048 + key0 + g * 8);
        v8s vf1 = *(const v8s*)(Vp + (size_t)(16 + c) * 2048 + key0 + g * 8);
        o0 = MFMA16(pf.v, vf0, o0);
        o1 = MFMA16(pf.v, vf1, o1);
    }

    lsum += __shfl_xor(lsum, 16);
    lsum += __shfl_xor(lsum, 32);

    *(f32x4*)&OLDS[w][lane][0] = o0;
    *(f32x4*)&OLDS[w][lane][4] = o1;
    if (lane < 16) lred[w][lane] = lsum;
    __syncthreads();

    if (tid < 64) {
        float iv[4];
        #pragma unroll
        for (int r = 0; r < 4; ++r) {
            float s = lred[0][bb + r];
            #pragma unroll
            for (int ww = 1; ww < 8; ++ww) s += lred[ww][bb + r];
            iv[r] = 1.f / s;
        }
        f32x4 a0 = *(f32x4*)&OLDS[0][lane][0];
        f32x4 a1 = *(f32x4*)&OLDS[0][lane][4];
        #pragma unroll
        for (int ww = 1; ww < 8; ++ww) {
            a0 += *(f32x4*)&OLDS[ww][lane][0];
            a1 += *(f32x4*)&OLDS[ww][lane][4];
        }
        #pragma unroll
        for (int r = 0; r < 4; ++r) {
            size_t base = ((size_t)b * 2048 + r0w + bb + r) * 128 + h * 32;
            O[base + c]      = a0[r] * iv[r];
            O[base + 16 + c] = a1[r] * iv[r];
        }
    }
}

// ---------------------------------------------------------------------------
// Graph adjacency + fused top-k + masked re-softmax -> bf16 ADJb.
// v5: 512 threads. GEMM phase on all 8 waves (per-output fmaf chain over
// dd=0..31 ascending -> bit-identical regardless of owning thread; scalar
// strided loads/stores, conflict-free). Softmax + top-k phases run on waves
// 0-3 ONLY with the exact round-3 code/mappings -> bit-identical sums.
// ---------------------------------------------------------------------------
__global__ __launch_bounds__(512, 8) void gadjtopk_k(
    const float* __restrict__ Kg, const float* __restrict__ QgT,
    __hip_bfloat16* __restrict__ ADJb)
{
    __shared__ float kg_s[4][32];
    __shared__ float scores[4][2048];
    __shared__ float redm[4][4], reds[4][4];

    const int tid = threadIdx.x;
    const int wg = blockIdx.x;     // 0..1023
    const int b = wg >> 9;
    const int r0 = (wg & 511) << 2;

    if (tid < 128) {
        int rr = tid >> 5, d = tid & 31;
        kg_s[rr][d] = Kg[((size_t)b * 2048 + r0 + rr) * 32 + d];
    }
    __syncthreads();

    // ---- phase 1: logits GEMM, all 512 threads; thread owns cols tid+512*s ----
    const float* Qp = QgT + (size_t)b * 32 * 2048;
    float acc[4][4];
    #pragma unroll
    for (int rr = 0; rr < 4; ++rr)
        #pragma unroll
        for (int s = 0; s < 4; ++s) acc[rr][s] = 0.f;

    #pragma unroll 4
    for (int dd = 0; dd < 32; ++dd) {
        float q0 = kg_s[0][dd], q1 = kg_s[1][dd], q2 = kg_s[2][dd], q3 = kg_s[3][dd];
        const float* kp = Qp + (size_t)dd * 2048 + tid;
        #pragma unroll
        for (int s = 0; s < 4; ++s) {
            float kv = kp[s * 512];
            acc[0][s] = fmaf(q0, kv, acc[0][s]);
            acc[1][s] = fmaf(q1, kv, acc[1][s]);
            acc[2][s] = fmaf(q2, kv, acc[2][s]);
            acc[3][s] = fmaf(q3, kv, acc[3][s]);
        }
    }
    #pragma unroll
    for (int s = 0; s < 4; ++s) {
        int jj = tid + 512 * s;
        #pragma unroll
        for (int rr = 0; rr < 4; ++rr) scores[rr][jj] = acc[rr][s];
    }
    __syncthreads();

    const int lane = tid & 63, wid = tid >> 6;

    // ---- phase 2a: row max (waves 0-3; identical to round 3) ----
    if (tid < 256) {
        #pragma unroll
        for (int rr = 0; rr < 4; ++rr) {
            float m = -3.0e38f;
            #pragma unroll
            for (int s = 0; s < 8; ++s) m = fmaxf(m, scores[rr][tid + 256 * s]);
            m = wave_max_f(m);
            if (lane == 0) redm[rr][wid] = m;
        }
    }
    __syncthreads();

    // ---- phase 2b: exp + row sum (waves 0-3; identical to round 3) ----
    if (tid < 256) {
        float mx[4];
        #pragma unroll
        for (int rr = 0; rr < 4; ++rr)
            mx[rr] = fmaxf(fmaxf(redm[rr][0], redm[rr][1]), fmaxf(redm[rr][2], redm[rr][3]));
        #pragma unroll
        for (int rr = 0; rr < 4; ++rr) {
            float sm = 0.f;
            #pragma unroll
            for (int s = 0; s < 8; ++s) {
                int jj = tid + 256 * s;
                float p = expf(scores[rr][jj] - mx[rr]);
                scores[rr][jj] = p;
                sm += p;
            }
            sm = wave_sum_f(sm);
            if (lane == 0) reds[rr][wid] = sm;
        }
    }
    __syncthreads();

    // ---- phase 3: top-k, wave wid owns row r0+wid (waves 0-3) ----
    if (tid < 256) {
        const float ivw = 1.f / (reds[wid][0] + reds[wid][1] + reds[wid][2] + reds[wid][3]);
        unsigned k_[32];
        float mxp = 0.f, mnp = 3.0e38f;
        #pragma unroll
        for (int i = 0; i < 32; ++i) {
            float p = scores[wid][lane + i * 64] * ivw;
            k_[i] = __float_as_uint(p);
            mxp = fmaxf(mxp, p);
            mnp = fminf(mnp, p);
        }
        mxp = wave_max_f(mxp);
        mnp = wave_min_f(mnp);

        unsigned thr = __float_as_uint(mnp);
        const unsigned umax = __float_as_uint(mxp);
        const unsigned diff = thr ^ umax;
        if (diff != 0u) {
            const int hb = 31 - __builtin_clz(diff);
            thr = (umax >> (hb + 1)) << (hb + 1);   // common prefix of [min,max]
            for (int bit = hb; bit >= 0; --bit) {
                unsigned cand = thr | (1u << bit);
                int cnt = 0;
                #pragma unroll
                for (int i = 0; i < 32; ++i)
                    cnt += (int)__popcll(__ballot(k_[i] >= cand));
                if (cnt >= KK_TOP) thr = cand;
            }
        }

        int gt_c = 0;
        #pragma unroll
        for (int i = 0; i < 32; ++i)
            gt_c += (int)__popcll(__ballot(k_[i] > thr));
        const int need = KK_TOP - gt_c;

        unsigned keepmask = 0u;
        int running = 0;
        const unsigned long long ltmask = (lane == 0) ? 0ull : (~0ull >> (64 - lane));
        #pragma unroll
        for (int i = 0; i < 32; ++i) {
            bool tie = (k_[i] == thr);
            unsigned long long bal = __ballot(tie);
            int before = running + (int)__popcll(bal & ltmask);
            bool keep = (k_[i] > thr) || (tie && before < need);
            running += (int)__popcll(bal);
            if (keep) keepmask |= (1u << i);
        }

        const float LOG2E = 1.4426950408889634f;
        float sm = 0.f;
        #pragma unroll
        for (int i = 0; i < 32; ++i)
            if ((keepmask >> i) & 1u)
                sm += exp2f((__uint_as_float(k_[i]) - mxp) * LOG2E);
        sm = wave_sum_f(sm);
        const float ivs = 1.f / sm;

        __hip_bfloat16* rp = ADJb + (size_t)(b * 2048 + r0 + wid) * 2048;
        #pragma unroll
        for (int i = 0; i < 32; ++i) {
            float o = ((keepmask >> i) & 1u)
                        ? exp2f((__uint_as_float(k_[i]) - mxp) * LOG2E) * ivs : 0.f;
            rp[lane + i * 64] = __float2bfloat16(o);
        }
    }
}

// ---------------------------------------------------------------------------
// Final GEMM (MFMA), 4-wave K-split, 2-way col-split.
// ---------------------------------------------------------------------------
__global__ __launch_bounds__(256) void outgemm_mfma_k(
    const short* __restrict__ ADJb, const short* __restrict__ SUPt,
    const float* __restrict__ gcb, float* __restrict__ OUT)
{
    __shared__ __align__(16) float OL[4][64][16];
    const int tid = threadIdx.x;
    const int w = tid >> 6, lane = tid & 63;
    const int g = lane >> 4, c = lane & 15;
    const int r0w = blockIdx.x * 16;          // 0..4080 (global row incl. batch)
    const int n0 = blockIdx.y * 64;
    const int b = r0w >> 11;
    const short* Bp = SUPt + (size_t)b * 128 * 2048;

    f32x4 acc[4];
    #pragma unroll
    for (int f = 0; f < 4; ++f) acc[f] = (f32x4){0.f, 0.f, 0.f, 0.f};

    #pragma unroll 2
    for (int i = 0; i < 16; ++i) {
        const int k0 = w * 512 + i * 32;
        v8s af = *(const v8s*)(ADJb + (size_t)(r0w + c) * 2048 + k0 + g * 8);
        #pragma unroll
        for (int f = 0; f < 4; ++f) {
            v8s bf_ = *(const v8s*)(Bp + (size_t)(n0 + f * 16 + c) * 2048 + k0 + g * 8);
            acc[f] = MFMA16(af, bf_, acc[f]);
        }
    }

    #pragma unroll
    for (int f = 0; f < 4; ++f) *(f32x4*)&OL[w][lane][f * 4] = acc[f];
    __syncthreads();

    #pragma unroll
    for (int u = 0; u < 4; ++u) {
        int idx = tid + u * 256;        // 0..1023
        int ls = idx >> 4, s = idx & 15;
        float v = OL[0][ls][s] + OL[1][ls][s] + OL[2][ls][s] + OL[3][ls][s];
        int f = s >> 2, r = s & 3;
        int row = r0w + 4 * (ls >> 4) + r;
        int col = n0 + f * 16 + (ls & 15);
        OUT[(size_t)row * 128 + col] = v + gcb[col];
    }
}

// ---------------------------------------------------------------------------
extern "C" void kernel_launch(void* const* d_in, const int* in_sizes, int n_in,
                              void* d_out, int out_size, void* d_ws, size_t ws_size,
                              hipStream_t stream)
{
    const float* x       = (const float*)d_in[0];
    const int*   A       = (const int*)d_in[1];
    const float* q_w1    = (const float*)d_in[2];
    const float* kv_w1   = (const float*)d_in[3];
    const float* proj_w1 = (const float*)d_in[4];
    const float* proj_b1 = (const float*)d_in[5];
    const float* q_w2    = (const float*)d_in[6];
    const float* kv_w2   = (const float*)d_in[7];
    const float* proj_w2 = (const float*)d_in[8];
    const float* proj_b2 = (const float*)d_in[9];
    const float* cq_w    = (const float*)d_in[10];
    const float* cq_b    = (const float*)d_in[11];
    const float* ck_w    = (const float*)d_in[12];
    const float* ck_b    = (const float*)d_in[13];
    const float* cv_w    = (const float*)d_in[14];
    const float* cv_b    = (const float*)d_in[15];
    const float* gc_w    = (const float*)d_in[16];
    const float* gc_b    = (const float*)d_in[17];
    float* out = (float*)d_out;

    // Workspace layout (bytes, 256-aligned). Total ~28.9 MB.
    char* ws = (char*)d_ws;
    __hip_bfloat16* Qb   = (__hip_bfloat16*)(ws + 0);          // 1 MB
    __hip_bfloat16* Kb   = (__hip_bfloat16*)(ws + 1048576);    // 1 MB
    __hip_bfloat16* Vt   = (__hip_bfloat16*)(ws + 2097152);    // 1 MB
    __hip_bfloat16* ADJb = (__hip_bfloat16*)(ws + 3145728);    // 16 MB
    unsigned*       Ab2  = (unsigned*)      (ws + 19922944);   // 512 KB
    float*          O    = (float*)         (ws + 20447232);   // 2 MB
    float*          X1   = (float*)         (ws + 22544384);   // 2 MB
    float*          X2   = (float*)         (ws + 24641536);   // 2 MB
    float*          QgT  = (float*)         (ws + 26738688);   // 512 KB
    float*          Kg   = (float*)         (ws + 27262976);   // 512 KB
    __hip_bfloat16* SUPt = (__hip_bfloat16*)(ws + 27787264);   // 1 MB
    float*          MT   = (float*)         (ws + 28835840);   // 64 KB
    float*          B2   = (float*)         (ws + 28901376);   // 512 B

    dim3 blk(256);
    dim3 blk512(512);

    hipLaunchKernelGGL(prep_k, dim3(576), blk, 0, stream, A, Ab2, cv_w, cv_b, gc_w, MT, B2);

    // ---- attention block 1 ----
    hipLaunchKernelGGL((gemm128_k<MODE_QKV>), dim3(64, 12), blk, 0, stream,
                       x, q_w1, kv_w1, nullptr, nullptr, Qb, Kb, Vt);
    hipLaunchKernelGGL(attn_mfma_k, dim3(1024), blk512, 0, stream,
                       (const short*)Qb, (const short*)Kb, (const short*)Vt, Ab2, O);
    hipLaunchKernelGGL((gemm128_k<MODE_PROJ>), dim3(64, 4), blk, 0, stream,
                       O, proj_w1, nullptr, proj_b1, x, X1, nullptr, nullptr);

    // ---- attention block 2 ----
    hipLaunchKernelGGL((gemm128_k<MODE_QKV>), dim3(64, 12), blk, 0, stream,
                       X1, q_w2, kv_w2, nullptr, nullptr, Qb, Kb, Vt);
    hipLaunchKernelGGL(attn_mfma_k, dim3(1024), blk512, 0, stream,
                       (const short*)Qb, (const short*)Kb, (const short*)Vt, Ab2, O);
    hipLaunchKernelGGL((gemm128_k<MODE_PROJ>), dim3(64, 4), blk, 0, stream,
                       O, proj_w2, nullptr, proj_b2, X1, X2, nullptr, nullptr);

    // ---- graph conv ----
    hipLaunchKernelGGL(graphmm_k, dim3(64, 6), blk, 0, stream,
                       X2, cq_w, cq_b, ck_w, ck_b, MT, B2, QgT, Kg, SUPt);
    hipLaunchKernelGGL(gadjtopk_k, dim3(1024), blk512, 0, stream, Kg, QgT, ADJb);
    hipLaunchKernelGGL(outgemm_mfma_k, dim3(256, 2), blk, 0, stream,
                       (const short*)ADJb, (const short*)SUPt, gc_b, out);
}

// Round 6
// 286.647 us; speedup vs baseline: 2.9504x; 1.0358x over previous
//
#include <hip/hip_runtime.h>
#include <hip/hip_bf16.h>
#include <math.h>

#define BB 2
#define NN 2048
#define CC 128
#define HH 4
#define HD 32
#define KK_TOP 1365   // int(2048/3*2)

typedef __attribute__((ext_vector_type(8))) short v8s;
typedef __attribute__((ext_vector_type(4))) float f32x4;

#define MFMA16(a, b, c) __builtin_amdgcn_mfma_f32_16x16x32_bf16(a, b, c, 0, 0, 0)

__device__ inline float wave_max_f(float v) {
    #pragma unroll
    for (int m = 1; m < 64; m <<= 1) v = fmaxf(v, __shfl_xor(v, m));
    return v;
}
__device__ inline float wave_min_f(float v) {
    #pragma unroll
    for (int m = 1; m < 64; m <<= 1) v = fminf(v, __shfl_xor(v, m));
    return v;
}
__device__ inline float wave_sum_f(float v) {
    #pragma unroll
    for (int m = 1; m < 64; m <<= 1) v += __shfl_xor(v, m);
    return v;
}
__device__ inline unsigned short bf16bits(float x) {
    __hip_bfloat16 h = __float2bfloat16(x);
    return *reinterpret_cast<unsigned short*>(&h);
}

// ---------------------------------------------------------------------------
// prep: blocks 0..511 pack mask A into row-major bitwords
//       (bit t of Ab2[q*64+kw] = A[q][kw*32+t] > 0);
//       blocks 512..575 compute fused support weight MT/B2.
// ---------------------------------------------------------------------------
__global__ __launch_bounds__(256) void prep_k(
    const int* __restrict__ A, unsigned* __restrict__ Ab2,
    const float* __restrict__ cv_w, const float* __restrict__ cv_b,
    const float* __restrict__ gc_w, float* __restrict__ MT, float* __restrict__ B2)
{
    const int bx = blockIdx.x;
    if (bx < 512) {
        const int lane = threadIdx.x & 63;
        const int w = threadIdx.x >> 6;
        const int row = bx * 4 + w;
        const int* rp = A + (size_t)row * 2048;
        for (int i = 0; i < 32; ++i) {
            unsigned long long bal = __ballot(rp[i * 64 + lane] > 0);
            if (lane == 0)  Ab2[(size_t)row * 64 + 2 * i]     = (unsigned)bal;
            if (lane == 32) Ab2[(size_t)row * 64 + 2 * i + 1] = (unsigned)(bal >> 32);
        }
    } else {
        const int b2 = bx - 512;
        const int c = b2 * 2 + (threadIdx.x >> 7);
        const int k = threadIdx.x & 127;
        float a = 0.f;
        #pragma unroll 4
        for (int i = 0; i < 128; ++i)
            a += cv_w[(size_t)i * 128 + k] * gc_w[(size_t)i * 128 + c];
        MT[(size_t)c * 128 + k] = a;
        if (b2 == 0 && threadIdx.x < 128) {
            float s = 0.f;
            #pragma unroll 4
            for (int i = 0; i < 128; ++i)
                s += cv_b[i] * gc_w[(size_t)i * 128 + threadIdx.x];
            B2[threadIdx.x] = s;
        }
    }
}

// ---------------------------------------------------------------------------
// Generic 128-K GEMM (f32 VALU): out = X[M,128] @ W[NC,128]^T + epilogues.
// ---------------------------------------------------------------------------
enum { MODE_QKV = 0, MODE_PROJ = 1 };

template <int MODE>
__global__ __launch_bounds__(256) void gemm128_k(
    const float* __restrict__ X, const float* __restrict__ W0,
    const float* __restrict__ W1, const float* __restrict__ bias,
    const float* __restrict__ resid, void* __restrict__ out0v,
    void* __restrict__ out1v, void* __restrict__ out2v)
{
    __shared__ __align__(16) float Xs[64][132];
    __shared__ __align__(16) float Ws[32][132];
    const int tid = threadIdx.x;
    const int m0 = blockIdx.x * 64;
    const int n0 = blockIdx.y * 32;

    #pragma unroll
    for (int i = 0; i < 32; ++i) {
        int idx = tid + i * 256;
        int row = idx >> 7, col = idx & 127;
        Xs[row][col] = X[(size_t)(m0 + row) * 128 + col];
    }
    #pragma unroll
    for (int i = 0; i < 16; ++i) {
        int idx = tid + i * 256;
        int r = idx >> 7, col = idx & 127;
        int gr = n0 + r;
        const float* wp;
        if (MODE == MODE_QKV)
            wp = (gr < 128) ? (W0 + (size_t)gr * 128) : (W1 + (size_t)(gr - 128) * 128);
        else
            wp = W0 + (size_t)gr * 128;
        Ws[r][col] = wp[col];
    }
    __syncthreads();

    const int r = tid >> 4;
    const int c = tid & 15;
    float acc[4][2] = {{0.f, 0.f}, {0.f, 0.f}, {0.f, 0.f}, {0.f, 0.f}};

    #pragma unroll
    for (int k = 0; k < 128; k += 4) {
        float4 w0 = *(const float4*)&Ws[c][k];
        float4 w1 = *(const float4*)&Ws[c + 16][k];
        #pragma unroll
        for (int i = 0; i < 4; ++i) {
            float4 xv = *(const float4*)&Xs[r + 16 * i][k];
            acc[i][0] += xv.x * w0.x + xv.y * w0.y + xv.z * w0.z + xv.w * w0.w;
            acc[i][1] += xv.x * w1.x + xv.y * w1.y + xv.z * w1.z + xv.w * w1.w;
        }
    }

    #pragma unroll
    for (int i = 0; i < 4; ++i) {
        int m = m0 + r + 16 * i;
        int b = m >> 11, n = m & 2047;
        #pragma unroll
        for (int jj = 0; jj < 2; ++jj) {
            int ccol = n0 + c + 16 * jj;
            float v = acc[i][jj];
            if (MODE == MODE_QKV) {
                __hip_bfloat16 hv = __float2bfloat16(v);
                if (ccol < 128) {
                    int hh = ccol >> 5, d = ccol & 31;
                    ((__hip_bfloat16*)out0v)[((size_t)(b * 4 + hh) * 2048 + n) * 32 + d] = hv;  // Qb
                } else if (ccol < 256) {
                    int c2 = ccol - 128; int hh = c2 >> 5, d = c2 & 31;
                    ((__hip_bfloat16*)out1v)[((size_t)(b * 4 + hh) * 2048 + n) * 32 + d] = hv;  // Kb
                } else {
                    int c2 = ccol - 256; int hh = c2 >> 5, d = c2 & 31;
                    ((__hip_bfloat16*)out2v)[((size_t)(b * 4 + hh) * 32 + d) * 2048 + n] = hv;  // Vt
                }
            } else { // MODE_PROJ
                ((float*)out0v)[(size_t)m * 128 + ccol] = v + bias[ccol] + resid[(size_t)m * 128 + ccol];
            }
        }
    }
}

// ---------------------------------------------------------------------------
// Merged QG + KG + SUP GEMM on X2. blockIdx.y: 0=QG, 1=KG, 2..5=SUP cols.
// ---------------------------------------------------------------------------
__global__ __launch_bounds__(256) void graphmm_k(
    const float* __restrict__ X, const float* __restrict__ cq_w,
    const float* __restrict__ cq_b, const float* __restrict__ ck_w,
    const float* __restrict__ ck_b, const float* __restrict__ MT,
    const float* __restrict__ B2, float* __restrict__ QgT,
    float* __restrict__ Kg, __hip_bfloat16* __restrict__ SUPt)
{
    __shared__ __align__(16) float Xs[64][132];
    __shared__ __align__(16) float Ws[32][132];
    const int tid = threadIdx.x;
    const int m0 = blockIdx.x * 64;
    const int y = blockIdx.y;
    const float* W0   = (y == 0) ? cq_w : (y == 1) ? ck_w : MT;
    const float* bias = (y == 0) ? cq_b : (y == 1) ? ck_b : B2;
    const int n0 = (y < 2) ? 0 : (y - 2) * 32;

    #pragma unroll
    for (int i = 0; i < 32; ++i) {
        int idx = tid + i * 256;
        int row = idx >> 7, col = idx & 127;
        Xs[row][col] = X[(size_t)(m0 + row) * 128 + col];
    }
    #pragma unroll
    for (int i = 0; i < 16; ++i) {
        int idx = tid + i * 256;
        int r = idx >> 7, col = idx & 127;
        Ws[r][col] = W0[(size_t)(n0 + r) * 128 + col];
    }
    __syncthreads();

    const int r = tid >> 4;
    const int c = tid & 15;
    float acc[4][2] = {{0.f, 0.f}, {0.f, 0.f}, {0.f, 0.f}, {0.f, 0.f}};

    #pragma unroll
    for (int k = 0; k < 128; k += 4) {
        float4 w0 = *(const float4*)&Ws[c][k];
        float4 w1 = *(const float4*)&Ws[c + 16][k];
        #pragma unroll
        for (int i = 0; i < 4; ++i) {
            float4 xv = *(const float4*)&Xs[r + 16 * i][k];
            acc[i][0] += xv.x * w0.x + xv.y * w0.y + xv.z * w0.z + xv.w * w0.w;
            acc[i][1] += xv.x * w1.x + xv.y * w1.y + xv.z * w1.z + xv.w * w1.w;
        }
    }

    #pragma unroll
    for (int i = 0; i < 4; ++i) {
        int m = m0 + r + 16 * i;
        int b = m >> 11, n = m & 2047;
        #pragma unroll
        for (int jj = 0; jj < 2; ++jj) {
            int ccol = n0 + c + 16 * jj;
            float v = acc[i][jj];
            if (y == 0) {
                QgT[((size_t)b * 32 + ccol) * 2048 + n] = v + bias[ccol];
            } else if (y == 1) {
                Kg[(size_t)m * 32 + ccol] = v + bias[ccol];
            } else {
                SUPt[((size_t)b * 128 + ccol) * 2048 + n] = __float2bfloat16(v + bias[ccol]);
            }
        }
    }
}

// ---------------------------------------------------------------------------
// MFMA attention: 8 waves, 8-way K-split (256 keys each, interleaved).
// ---------------------------------------------------------------------------
__global__ __launch_bounds__(512, 8) void attn_mfma_k(
    const short* __restrict__ Qb, const short* __restrict__ Kb,
    const short* __restrict__ Vt, const unsigned* __restrict__ Ab2,
    float* __restrict__ O)
{
    __shared__ __align__(16) float OLDS[8][64][8];
    __shared__ float lred[8][16];

    const int tid = threadIdx.x;
    const int w = tid >> 6, lane = tid & 63;
    const int g = lane >> 4, c = lane & 15;
    const int bb = 4 * g;
    const int wg = blockIdx.x;                 // 0..1023
    const int b = wg >> 9, h = (wg >> 7) & 3, r0w = (wg & 127) << 4;
    const int bh = b * 4 + h;

    const v8s qf = *(const v8s*)(Qb + ((size_t)bh * 2048 + r0w + c) * 32 + g * 8);
    const short* Kp = Kb + (size_t)bh * 2048 * 32;
    const short* Vp = Vt + (size_t)bh * 32 * 2048;
    const unsigned* Mrow = Ab2 + (size_t)(r0w + c) * 64;

    f32x4 o0 = {0.f, 0.f, 0.f, 0.f}, o1 = {0.f, 0.f, 0.f, 0.f};
    float lsum = 0.f;
    const float SC2 = 0.25503487f;   // 32^-0.5 * log2(e)
    const bool lo = (g < 2);
    const int aA = (32 * (g & 1) + c) * 4;
    const int aB = aA + 64;

    #pragma unroll 2
    for (int t = 0; t < 8; ++t) {
        const int kt = t * 8 + w;
        const int key0 = kt * 32;
        v8s kf0 = *(const v8s*)(Kp + (size_t)(key0 + c) * 32 + g * 8);
        v8s kf1 = *(const v8s*)(Kp + (size_t)(key0 + 16 + c) * 32 + g * 8);
        unsigned mw = Mrow[kt];
        const f32x4 z = {0.f, 0.f, 0.f, 0.f};
        f32x4 s0 = MFMA16(kf0, qf, z);
        f32x4 s1 = MFMA16(kf1, qf, z);

        float p0[4], p1[4];
        #pragma unroll
        for (int r = 0; r < 4; ++r) {
            p0[r] = ((mw >> (bb + r)) & 1u)      ? exp2f(s0[r] * SC2) : 0.f;
            p1[r] = ((mw >> (16 + bb + r)) & 1u) ? exp2f(s1[r] * SC2) : 0.f;
        }
        lsum += p0[0] + p0[1] + p0[2] + p0[3] + p1[0] + p1[1] + p1[2] + p1[3];

        int w00 = (int)bf16bits(p0[0]) | ((int)bf16bits(p0[1]) << 16);
        int w01 = (int)bf16bits(p0[2]) | ((int)bf16bits(p0[3]) << 16);
        int w10 = (int)bf16bits(p1[0]) | ((int)bf16bits(p1[1]) << 16);
        int w11 = (int)bf16bits(p1[2]) | ((int)bf16bits(p1[3]) << 16);

        int e0, e1;
        union { int wv[4]; v8s v; } pf;
        e0 = __builtin_amdgcn_ds_bpermute(aA, w00);
        e1 = __builtin_amdgcn_ds_bpermute(aA, w10);
        pf.wv[0] = lo ? e0 : e1;
        e0 = __builtin_amdgcn_ds_bpermute(aA, w01);
        e1 = __builtin_amdgcn_ds_bpermute(aA, w11);
        pf.wv[1] = lo ? e0 : e1;
        e0 = __builtin_amdgcn_ds_bpermute(aB, w00);
        e1 = __builtin_amdgcn_ds_bpermute(aB, w10);
        pf.wv[2] = lo ? e0 : e1;
        e0 = __builtin_amdgcn_ds_bpermute(aB, w01);
        e1 = __builtin_amdgcn_ds_bpermute(aB, w11);
        pf.wv[3] = lo ? e0 : e1;

        v8s vf0 = *(const v8s*)(Vp + (size_t)c * 2048 + key0 + g * 8);
        v8s vf1 = *(const v8s*)(Vp + (size_t)(16 + c) * 2048 + key0 + g * 8);
        o0 = MFMA16(pf.v, vf0, o0);
        o1 = MFMA16(pf.v, vf1, o1);
    }

    lsum += __shfl_xor(lsum, 16);
    lsum += __shfl_xor(lsum, 32);

    *(f32x4*)&OLDS[w][lane][0] = o0;
    *(f32x4*)&OLDS[w][lane][4] = o1;
    if (lane < 16) lred[w][lane] = lsum;
    __syncthreads();

    if (tid < 64) {
        float iv[4];
        #pragma unroll
        for (int r = 0; r < 4; ++r) {
            float s = lred[0][bb + r];
            #pragma unroll
            for (int ww = 1; ww < 8; ++ww) s += lred[ww][bb + r];
            iv[r] = 1.f / s;
        }
        f32x4 a0 = *(f32x4*)&OLDS[0][lane][0];
        f32x4 a1 = *(f32x4*)&OLDS[0][lane][4];
        #pragma unroll
        for (int ww = 1; ww < 8; ++ww) {
            a0 += *(f32x4*)&OLDS[ww][lane][0];
            a1 += *(f32x4*)&OLDS[ww][lane][4];
        }
        #pragma unroll
        for (int r = 0; r < 4; ++r) {
            size_t base = ((size_t)b * 2048 + r0w + bb + r) * 128 + h * 32;
            O[base + c]      = a0[r] * iv[r];
            O[base + 16 + c] = a1[r] * iv[r];
        }
    }
}

// ---------------------------------------------------------------------------
// Graph adjacency + fused top-k + masked re-softmax -> bf16 ADJb.
// v6: 8 rows/block, 512 threads, launch_bounds(512,4) so k_[32] stays in
// VGPRs. Phase 1 GEMM on all waves (per-output fmaf chain over dd ascending
// -> logits bit-identical). Phases 2-3: wave w owns row w entirely:
//   - row max: exact (order-invariant fmax)
//   - per-element expf inputs identical -> p bit-identical
//   - row-sum tree differs -> ivw off by ~1 ulp, a UNIFORM scale on the row
//     -> bit-pattern order preserved -> identical top-k selection.
// Early exit when cnt == KK_TOP: {x >= cand} is exactly the top-K set.
// ---------------------------------------------------------------------------
__global__ __launch_bounds__(512, 4) void gadjtopk_k(
    const float* __restrict__ Kg, const float* __restrict__ QgT,
    __hip_bfloat16* __restrict__ ADJb)
{
    __shared__ float kg_s[8][32];
    __shared__ float scores[8][2048];

    const int tid = threadIdx.x;
    const int wg = blockIdx.x;     // 0..511
    const int b = wg >> 8;
    const int r0 = (wg & 255) << 3;

    if (tid < 256) {
        int rr = tid >> 5, d = tid & 31;
        kg_s[rr][d] = Kg[((size_t)b * 2048 + r0 + rr) * 32 + d];
    }
    __syncthreads();

    // ---- phase 1: logits GEMM; thread owns cols tid + 512*s for 8 rows ----
    const float* Qp = QgT + (size_t)b * 32 * 2048;
    float acc[8][4];
    #pragma unroll
    for (int rr = 0; rr < 8; ++rr)
        #pragma unroll
        for (int s = 0; s < 4; ++s) acc[rr][s] = 0.f;

    for (int dd = 0; dd < 32; ++dd) {
        float qv[8];
        #pragma unroll
        for (int rr = 0; rr < 8; ++rr) qv[rr] = kg_s[rr][dd];
        const float* kp = Qp + (size_t)dd * 2048 + tid;
        #pragma unroll
        for (int s = 0; s < 4; ++s) {
            float kv = kp[s * 512];
            #pragma unroll
            for (int rr = 0; rr < 8; ++rr)
                acc[rr][s] = fmaf(qv[rr], kv, acc[rr][s]);
        }
    }
    #pragma unroll
    for (int s = 0; s < 4; ++s) {
        int jj = tid + 512 * s;
        #pragma unroll
        for (int rr = 0; rr < 8; ++rr) scores[rr][jj] = acc[rr][s];
    }
    __syncthreads();

    // ---- phases 2-3: wave w owns row r0 + w; no further barriers ----
    const int lane = tid & 63, w = tid >> 6;

    float mx = -3.0e38f;
    #pragma unroll
    for (int i = 0; i < 32; ++i) mx = fmaxf(mx, scores[w][lane + i * 64]);
    mx = wave_max_f(mx);

    float sm0 = 0.f;
    #pragma unroll
    for (int i = 0; i < 32; ++i) {
        float p = expf(scores[w][lane + i * 64] - mx);
        scores[w][lane + i * 64] = p;
        sm0 += p;
    }
    sm0 = wave_sum_f(sm0);
    const float ivw = 1.f / sm0;

    unsigned k_[32];
    float mxp = 0.f, mnp = 3.0e38f;
    #pragma unroll
    for (int i = 0; i < 32; ++i) {
        float p = scores[w][lane + i * 64] * ivw;
        k_[i] = __float_as_uint(p);
        mxp = fmaxf(mxp, p);
        mnp = fminf(mnp, p);
    }
    mxp = wave_max_f(mxp);
    mnp = wave_min_f(mnp);

    unsigned thr = __float_as_uint(mnp);
    const unsigned umax = __float_as_uint(mxp);
    const unsigned diff = thr ^ umax;
    if (diff != 0u) {
        const int hb = 31 - __builtin_clz(diff);
        thr = (umax >> (hb + 1)) << (hb + 1);   // common prefix of [min,max]
        for (int bit = hb; bit >= 0; --bit) {
            unsigned cand = thr | (1u << bit);
            int cnt = 0;
            #pragma unroll
            for (int i = 0; i < 32; ++i)
                cnt += (int)__popcll(__ballot(k_[i] >= cand));
            if (cnt == KK_TOP) { thr = cand; break; }
            if (cnt > KK_TOP) thr = cand;
        }
    }

    int gt_c = 0;
    #pragma unroll
    for (int i = 0; i < 32; ++i)
        gt_c += (int)__popcll(__ballot(k_[i] > thr));
    const int need = KK_TOP - gt_c;

    unsigned keepmask = 0u;
    int running = 0;
    const unsigned long long ltmask = (lane == 0) ? 0ull : (~0ull >> (64 - lane));
    #pragma unroll
    for (int i = 0; i < 32; ++i) {
        bool tie = (k_[i] == thr);
        unsigned long long bal = __ballot(tie);
        int before = running + (int)__popcll(bal & ltmask);
        bool keep = (k_[i] > thr) || (tie && before < need);
        running += (int)__popcll(bal);
        if (keep) keepmask |= (1u << i);
    }

    const float LOG2E = 1.4426950408889634f;
    float sm = 0.f;
    #pragma unroll
    for (int i = 0; i < 32; ++i)
        if ((keepmask >> i) & 1u)
            sm += exp2f((__uint_as_float(k_[i]) - mxp) * LOG2E);
    sm = wave_sum_f(sm);
    const float ivs = 1.f / sm;

    __hip_bfloat16* rp = ADJb + (size_t)(b * 2048 + r0 + w) * 2048;
    #pragma unroll
    for (int i = 0; i < 32; ++i) {
        float o = ((keepmask >> i) & 1u)
                    ? exp2f((__uint_as_float(k_[i]) - mxp) * LOG2E) * ivs : 0.f;
        rp[lane + i * 64] = __float2bfloat16(o);
    }
}

// ---------------------------------------------------------------------------
// Final GEMM (MFMA), 8-wave K-split, 2-way col-split.
// ---------------------------------------------------------------------------
__global__ __launch_bounds__(512, 8) void outgemm_mfma_k(
    const short* __restrict__ ADJb, const short* __restrict__ SUPt,
    const float* __restrict__ gcb, float* __restrict__ OUT)
{
    __shared__ __align__(16) float OL[8][64][16];
    const int tid = threadIdx.x;
    const int w = tid >> 6, lane = tid & 63;
    const int g = lane >> 4, c = lane & 15;
    const int r0w = blockIdx.x * 16;          // 0..4080 (global row incl. batch)
    const int n0 = blockIdx.y * 64;
    const int b = r0w >> 11;
    const short* Bp = SUPt + (size_t)b * 128 * 2048;

    f32x4 acc[4];
    #pragma unroll
    for (int f = 0; f < 4; ++f) acc[f] = (f32x4){0.f, 0.f, 0.f, 0.f};

    #pragma unroll 2
    for (int i = 0; i < 8; ++i) {
        const int k0 = w * 256 + i * 32;
        v8s af = *(const v8s*)(ADJb + (size_t)(r0w + c) * 2048 + k0 + g * 8);
        #pragma unroll
        for (int f = 0; f < 4; ++f) {
            v8s bf_ = *(const v8s*)(Bp + (size_t)(n0 + f * 16 + c) * 2048 + k0 + g * 8);
            acc[f] = MFMA16(af, bf_, acc[f]);
        }
    }

    #pragma unroll
    for (int f = 0; f < 4; ++f) *(f32x4*)&OL[w][lane][f * 4] = acc[f];
    __syncthreads();

    #pragma unroll
    for (int u = 0; u < 2; ++u) {
        int idx = tid + u * 512;        // 0..1023
        int ls = idx >> 4, s = idx & 15;
        float v = OL[0][ls][s];
        #pragma unroll
        for (int ww = 1; ww < 8; ++ww) v += OL[ww][ls][s];
        int f = s >> 2, r = s & 3;
        int row = r0w + 4 * (ls >> 4) + r;
        int col = n0 + f * 16 + (ls & 15);
        OUT[(size_t)row * 128 + col] = v + gcb[col];
    }
}

// ---------------------------------------------------------------------------
extern "C" void kernel_launch(void* const* d_in, const int* in_sizes, int n_in,
                              void* d_out, int out_size, void* d_ws, size_t ws_size,
                              hipStream_t stream)
{
    const float* x       = (const float*)d_in[0];
    const int*   A       = (const int*)d_in[1];
    const float* q_w1    = (const float*)d_in[2];
    const float* kv_w1   = (const float*)d_in[3];
    const float* proj_w1 = (const float*)d_in[4];
    const float* proj_b1 = (const float*)d_in[5];
    const float* q_w2    = (const float*)d_in[6];
    const float* kv_w2   = (const float*)d_in[7];
    const float* proj_w2 = (const float*)d_in[8];
    const float* proj_b2 = (const float*)d_in[9];
    const float* cq_w    = (const float*)d_in[10];
    const float* cq_b    = (const float*)d_in[11];
    const float* ck_w    = (const float*)d_in[12];
    const float* ck_b    = (const float*)d_in[13];
    const float* cv_w    = (const float*)d_in[14];
    const float* cv_b    = (const float*)d_in[15];
    const float* gc_w    = (const float*)d_in[16];
    const float* gc_b    = (const float*)d_in[17];
    float* out = (float*)d_out;

    // Workspace layout (bytes, 256-aligned). Total ~28.9 MB.
    char* ws = (char*)d_ws;
    __hip_bfloat16* Qb   = (__hip_bfloat16*)(ws + 0);          // 1 MB
    __hip_bfloat16* Kb   = (__hip_bfloat16*)(ws + 1048576);    // 1 MB
    __hip_bfloat16* Vt   = (__hip_bfloat16*)(ws + 2097152);    // 1 MB
    __hip_bfloat16* ADJb = (__hip_bfloat16*)(ws + 3145728);    // 16 MB
    unsigned*       Ab2  = (unsigned*)      (ws + 19922944);   // 512 KB
    float*          O    = (float*)         (ws + 20447232);   // 2 MB
    float*          X1   = (float*)         (ws + 22544384);   // 2 MB
    float*          X2   = (float*)         (ws + 24641536);   // 2 MB
    float*          QgT  = (float*)         (ws + 26738688);   // 512 KB
    float*          Kg   = (float*)         (ws + 27262976);   // 512 KB
    __hip_bfloat16* SUPt = (__hip_bfloat16*)(ws + 27787264);   // 1 MB
    float*          MT   = (float*)         (ws + 28835840);   // 64 KB
    float*          B2   = (float*)         (ws + 28901376);   // 512 B

    dim3 blk(256);
    dim3 blk512(512);

    hipLaunchKernelGGL(prep_k, dim3(576), blk, 0, stream, A, Ab2, cv_w, cv_b, gc_w, MT, B2);

    // ---- attention block 1 ----
    hipLaunchKernelGGL((gemm128_k<MODE_QKV>), dim3(64, 12), blk, 0, stream,
                       x, q_w1, kv_w1, nullptr, nullptr, Qb, Kb, Vt);
    hipLaunchKernelGGL(attn_mfma_k, dim3(1024), blk512, 0, stream,
                       (const short*)Qb, (const short*)Kb, (const short*)Vt, Ab2, O);
    hipLaunchKernelGGL((gemm128_k<MODE_PROJ>), dim3(64, 4), blk, 0, stream,
                       O, proj_w1, nullptr, proj_b1, x, X1, nullptr, nullptr);

    // ---- attention block 2 ----
    hipLaunchKernelGGL((gemm128_k<MODE_QKV>), dim3(64, 12), blk, 0, stream,
                       X1, q_w2, kv_w2, nullptr, nullptr, Qb, Kb, Vt);
    hipLaunchKernelGGL(attn_mfma_k, dim3(1024), blk512, 0, stream,
                       (const short*)Qb, (const short*)Kb, (const short*)Vt, Ab2, O);
    hipLaunchKernelGGL((gemm128_k<MODE_PROJ>), dim3(64, 4), blk, 0, stream,
                       O, proj_w2, nullptr, proj_b2, X1, X2, nullptr, nullptr);

    // ---- graph conv ----
    hipLaunchKernelGGL(graphmm_k, dim3(64, 6), blk, 0, stream,
                       X2, cq_w, cq_b, ck_w, ck_b, MT, B2, QgT, Kg, SUPt);
    hipLaunchKernelGGL(gadjtopk_k, dim3(512), blk512, 0, stream, Kg, QgT, ADJb);
    hipLaunchKernelGGL(outgemm_mfma_k, dim3(256, 2), blk512, 0, stream,
                       (const short*)ADJb, (const short*)SUPt, gc_b, out);
}

// Round 7
// 277.888 us; speedup vs baseline: 3.0434x; 1.0315x over previous
//
#include <hip/hip_runtime.h>
#include <hip/hip_bf16.h>
#include <math.h>

#define BB 2
#define NN 2048
#define CC 128
#define HH 4
#define HD 32
#define KK_TOP 1365   // int(2048/3*2)

typedef __attribute__((ext_vector_type(8))) short v8s;
typedef __attribute__((ext_vector_type(4))) float f32x4;

#define MFMA16(a, b, c) __builtin_amdgcn_mfma_f32_16x16x32_bf16(a, b, c, 0, 0, 0)

__device__ inline float wave_max_f(float v) {
    #pragma unroll
    for (int m = 1; m < 64; m <<= 1) v = fmaxf(v, __shfl_xor(v, m));
    return v;
}
__device__ inline float wave_min_f(float v) {
    #pragma unroll
    for (int m = 1; m < 64; m <<= 1) v = fminf(v, __shfl_xor(v, m));
    return v;
}
__device__ inline float wave_sum_f(float v) {
    #pragma unroll
    for (int m = 1; m < 64; m <<= 1) v += __shfl_xor(v, m);
    return v;
}
__device__ inline unsigned short bf16bits(float x) {
    __hip_bfloat16 h = __float2bfloat16(x);
    return *reinterpret_cast<unsigned short*>(&h);
}

// ---------------------------------------------------------------------------
// prep: blocks 0..511    pack mask A into row-major bitwords
//       blocks 512..575  fused support weight MT/B2
//       blocks 576..639  x (f32) -> xb (bf16)
//       blocks 640..655  6 weight matrices (f32) -> WALLb (bf16)
// WALLb layout (elems): W1b=q_w1|kv_w1 @0 (49152), P1b @49152 (16384),
//                       W2b @65536 (49152), P2b @114688 (16384)
// ---------------------------------------------------------------------------
__global__ __launch_bounds__(256) void prep_k(
    const int* __restrict__ A, unsigned* __restrict__ Ab2,
    const float* __restrict__ cv_w, const float* __restrict__ cv_b,
    const float* __restrict__ gc_w, float* __restrict__ MT, float* __restrict__ B2,
    const float* __restrict__ x, short* __restrict__ xb,
    const float* __restrict__ q_w1, const float* __restrict__ kv_w1,
    const float* __restrict__ proj_w1, const float* __restrict__ q_w2,
    const float* __restrict__ kv_w2, const float* __restrict__ proj_w2,
    short* __restrict__ WALLb)
{
    const int bx = blockIdx.x;
    if (bx < 512) {
        const int lane = threadIdx.x & 63;
        const int w = threadIdx.x >> 6;
        const int row = bx * 4 + w;
        const int* rp = A + (size_t)row * 2048;
        for (int i = 0; i < 32; ++i) {
            unsigned long long bal = __ballot(rp[i * 64 + lane] > 0);
            if (lane == 0)  Ab2[(size_t)row * 64 + 2 * i]     = (unsigned)bal;
            if (lane == 32) Ab2[(size_t)row * 64 + 2 * i + 1] = (unsigned)(bal >> 32);
        }
    } else if (bx < 576) {
        const int b2 = bx - 512;
        const int c = b2 * 2 + (threadIdx.x >> 7);
        const int k = threadIdx.x & 127;
        float a = 0.f;
        #pragma unroll 4
        for (int i = 0; i < 128; ++i)
            a += cv_w[(size_t)i * 128 + k] * gc_w[(size_t)i * 128 + c];
        MT[(size_t)c * 128 + k] = a;
        if (b2 == 0 && threadIdx.x < 128) {
            float s = 0.f;
            #pragma unroll 4
            for (int i = 0; i < 128; ++i)
                s += cv_b[i] * gc_w[(size_t)i * 128 + threadIdx.x];
            B2[threadIdx.x] = s;
        }
    } else if (bx < 640) {
        const size_t base = (size_t)(bx - 576) * 8192;
        #pragma unroll 8
        for (int i = 0; i < 32; ++i) {
            size_t e = base + threadIdx.x + i * 256;
            xb[e] = (short)bf16bits(x[e]);
        }
    } else {
        const int base = (bx - 640) * 8192;
        const float* src; int off;
        if (base < 16384)       { src = q_w1;    off = base; }
        else if (base < 49152)  { src = kv_w1;   off = base - 16384; }
        else if (base < 65536)  { src = proj_w1; off = base - 49152; }
        else if (base < 81920)  { src = q_w2;    off = base - 65536; }
        else if (base < 114688) { src = kv_w2;   off = base - 81920; }
        else                    { src = proj_w2; off = base - 114688; }
        short* dst = WALLb + base;
        #pragma unroll 8
        for (int i = 0; i < 32; ++i) {
            int e = threadIdx.x + i * 256;
            dst[e] = (short)bf16bits(src[off + e]);
        }
    }
}

// ---------------------------------------------------------------------------
// MFMA GEMM for the K=128 projections. D = Xb @ Wb^T (f32 accumulate).
// Block: 256t/4 waves; wave = 16 rows; blockIdx.x*64 rows; blockIdx.y*64 cols.
// MODE_QKV: scatter bf16 to Qb/Kb/Vt.  MODE_PROJ: f32 out = acc+bias+resid,
// optionally also bf16 copy (for next block's A operand).
// ---------------------------------------------------------------------------
enum { MODE_QKV = 0, MODE_PROJ = 1 };

template <int MODE, bool EMITB>
__global__ __launch_bounds__(256) void mfma_gemm_k(
    const short* __restrict__ Xb, const short* __restrict__ Wb,
    const float* __restrict__ bias, const float* __restrict__ resid,
    short* __restrict__ Qo, short* __restrict__ Ko, short* __restrict__ Vto,
    float* __restrict__ Fo, short* __restrict__ Bo)
{
    const int tid = threadIdx.x;
    const int w = tid >> 6, lane = tid & 63;
    const int g = lane >> 4, c = lane & 15;
    const int m0 = blockIdx.x * 64 + w * 16;
    const int nbase = blockIdx.y * 64;

    v8s af[4];
    #pragma unroll
    for (int kk = 0; kk < 4; ++kk)
        af[kk] = *(const v8s*)(Xb + (size_t)(m0 + c) * 128 + kk * 32 + g * 8);

    for (int nf = 0; nf < 4; ++nf) {
        const int n0 = nbase + nf * 16;
        f32x4 acc = {0.f, 0.f, 0.f, 0.f};
        #pragma unroll
        for (int kk = 0; kk < 4; ++kk) {
            v8s bfr = *(const v8s*)(Wb + (size_t)(n0 + c) * 128 + kk * 32 + g * 8);
            acc = MFMA16(af[kk], bfr, acc);
        }
        const int ccol = n0 + c;
        #pragma unroll
        for (int r = 0; r < 4; ++r) {
            const int m = m0 + 4 * g + r;
            const int b = m >> 11, n = m & 2047;
            if (MODE == MODE_QKV) {
                unsigned short hv = bf16bits(acc[r]);
                if (ccol < 128) {
                    int hh = ccol >> 5, d = ccol & 31;
                    Qo[((size_t)(b * 4 + hh) * 2048 + n) * 32 + d] = (short)hv;
                } else if (ccol < 256) {
                    int c2 = ccol - 128; int hh = c2 >> 5, d = c2 & 31;
                    Ko[((size_t)(b * 4 + hh) * 2048 + n) * 32 + d] = (short)hv;
                } else {
                    int c2 = ccol - 256; int hh = c2 >> 5, d = c2 & 31;
                    Vto[((size_t)(b * 4 + hh) * 32 + d) * 2048 + n] = (short)hv;
                }
            } else {
                float v = acc[r] + bias[ccol] + resid[(size_t)m * 128 + ccol];
                Fo[(size_t)m * 128 + ccol] = v;
                if (EMITB) Bo[(size_t)m * 128 + ccol] = (short)bf16bits(v);
            }
        }
    }
}

// ---------------------------------------------------------------------------
// Merged QG + KG + SUP GEMM on X2 (f32 VALU, frozen numerics).
// blockIdx.y: 0=QG, 1=KG, 2..5=SUP cols.
// ---------------------------------------------------------------------------
__global__ __launch_bounds__(256) void graphmm_k(
    const float* __restrict__ X, const float* __restrict__ cq_w,
    const float* __restrict__ cq_b, const float* __restrict__ ck_w,
    const float* __restrict__ ck_b, const float* __restrict__ MT,
    const float* __restrict__ B2, float* __restrict__ QgT,
    float* __restrict__ Kg, __hip_bfloat16* __restrict__ SUPt)
{
    __shared__ __align__(16) float Xs[64][132];
    __shared__ __align__(16) float Ws[32][132];
    const int tid = threadIdx.x;
    const int m0 = blockIdx.x * 64;
    const int y = blockIdx.y;
    const float* W0   = (y == 0) ? cq_w : (y == 1) ? ck_w : MT;
    const float* bias = (y == 0) ? cq_b : (y == 1) ? ck_b : B2;
    const int n0 = (y < 2) ? 0 : (y - 2) * 32;

    #pragma unroll
    for (int i = 0; i < 32; ++i) {
        int idx = tid + i * 256;
        int row = idx >> 7, col = idx & 127;
        Xs[row][col] = X[(size_t)(m0 + row) * 128 + col];
    }
    #pragma unroll
    for (int i = 0; i < 16; ++i) {
        int idx = tid + i * 256;
        int r = idx >> 7, col = idx & 127;
        Ws[r][col] = W0[(size_t)(n0 + r) * 128 + col];
    }
    __syncthreads();

    const int r = tid >> 4;
    const int c = tid & 15;
    float acc[4][2] = {{0.f, 0.f}, {0.f, 0.f}, {0.f, 0.f}, {0.f, 0.f}};

    #pragma unroll
    for (int k = 0; k < 128; k += 4) {
        float4 w0 = *(const float4*)&Ws[c][k];
        float4 w1 = *(const float4*)&Ws[c + 16][k];
        #pragma unroll
        for (int i = 0; i < 4; ++i) {
            float4 xv = *(const float4*)&Xs[r + 16 * i][k];
            acc[i][0] += xv.x * w0.x + xv.y * w0.y + xv.z * w0.z + xv.w * w0.w;
            acc[i][1] += xv.x * w1.x + xv.y * w1.y + xv.z * w1.z + xv.w * w1.w;
        }
    }

    #pragma unroll
    for (int i = 0; i < 4; ++i) {
        int m = m0 + r + 16 * i;
        int b = m >> 11, n = m & 2047;
        #pragma unroll
        for (int jj = 0; jj < 2; ++jj) {
            int ccol = n0 + c + 16 * jj;
            float v = acc[i][jj];
            if (y == 0) {
                QgT[((size_t)b * 32 + ccol) * 2048 + n] = v + bias[ccol];
            } else if (y == 1) {
                Kg[(size_t)m * 32 + ccol] = v + bias[ccol];
            } else {
                SUPt[((size_t)b * 128 + ccol) * 2048 + n] = __float2bfloat16(v + bias[ccol]);
            }
        }
    }
}

// ---------------------------------------------------------------------------
// MFMA attention: 8 waves, 8-way K-split; output written directly as bf16.
// ---------------------------------------------------------------------------
__global__ __launch_bounds__(512, 8) void attn_mfma_k(
    const short* __restrict__ Qb, const short* __restrict__ Kb,
    const short* __restrict__ Vt, const unsigned* __restrict__ Ab2,
    short* __restrict__ Ob)
{
    __shared__ __align__(16) float OLDS[8][64][8];
    __shared__ float lred[8][16];

    const int tid = threadIdx.x;
    const int w = tid >> 6, lane = tid & 63;
    const int g = lane >> 4, c = lane & 15;
    const int bb = 4 * g;
    const int wg = blockIdx.x;                 // 0..1023
    const int b = wg >> 9, h = (wg >> 7) & 3, r0w = (wg & 127) << 4;
    const int bh = b * 4 + h;

    const v8s qf = *(const v8s*)(Qb + ((size_t)bh * 2048 + r0w + c) * 32 + g * 8);
    const short* Kp = Kb + (size_t)bh * 2048 * 32;
    const short* Vp = Vt + (size_t)bh * 32 * 2048;
    const unsigned* Mrow = Ab2 + (size_t)(r0w + c) * 64;

    f32x4 o0 = {0.f, 0.f, 0.f, 0.f}, o1 = {0.f, 0.f, 0.f, 0.f};
    float lsum = 0.f;
    const float SC2 = 0.25503487f;   // 32^-0.5 * log2(e)
    const bool lo = (g < 2);
    const int aA = (32 * (g & 1) + c) * 4;
    const int aB = aA + 64;

    #pragma unroll 2
    for (int t = 0; t < 8; ++t) {
        const int kt = t * 8 + w;
        const int key0 = kt * 32;
        v8s kf0 = *(const v8s*)(Kp + (size_t)(key0 + c) * 32 + g * 8);
        v8s kf1 = *(const v8s*)(Kp + (size_t)(key0 + 16 + c) * 32 + g * 8);
        unsigned mw = Mrow[kt];
        const f32x4 z = {0.f, 0.f, 0.f, 0.f};
        f32x4 s0 = MFMA16(kf0, qf, z);
        f32x4 s1 = MFMA16(kf1, qf, z);

        float p0[4], p1[4];
        #pragma unroll
        for (int r = 0; r < 4; ++r) {
            p0[r] = ((mw >> (bb + r)) & 1u)      ? exp2f(s0[r] * SC2) : 0.f;
            p1[r] = ((mw >> (16 + bb + r)) & 1u) ? exp2f(s1[r] * SC2) : 0.f;
        }
        lsum += p0[0] + p0[1] + p0[2] + p0[3] + p1[0] + p1[1] + p1[2] + p1[3];

        int w00 = (int)bf16bits(p0[0]) | ((int)bf16bits(p0[1]) << 16);
        int w01 = (int)bf16bits(p0[2]) | ((int)bf16bits(p0[3]) << 16);
        int w10 = (int)bf16bits(p1[0]) | ((int)bf16bits(p1[1]) << 16);
        int w11 = (int)bf16bits(p1[2]) | ((int)bf16bits(p1[3]) << 16);

        int e0, e1;
        union { int wv[4]; v8s v; } pf;
        e0 = __builtin_amdgcn_ds_bpermute(aA, w00);
        e1 = __builtin_amdgcn_ds_bpermute(aA, w10);
        pf.wv[0] = lo ? e0 : e1;
        e0 = __builtin_amdgcn_ds_bpermute(aA, w01);
        e1 = __builtin_amdgcn_ds_bpermute(aA, w11);
        pf.wv[1] = lo ? e0 : e1;
        e0 = __builtin_amdgcn_ds_bpermute(aB, w00);
        e1 = __builtin_amdgcn_ds_bpermute(aB, w10);
        pf.wv[2] = lo ? e0 : e1;
        e0 = __builtin_amdgcn_ds_bpermute(aB, w01);
        e1 = __builtin_amdgcn_ds_bpermute(aB, w11);
        pf.wv[3] = lo ? e0 : e1;

        v8s vf0 = *(const v8s*)(Vp + (size_t)c * 2048 + key0 + g * 8);
        v8s vf1 = *(const v8s*)(Vp + (size_t)(16 + c) * 2048 + key0 + g * 8);
        o0 = MFMA16(pf.v, vf0, o0);
        o1 = MFMA16(pf.v, vf1, o1);
    }

    lsum += __shfl_xor(lsum, 16);
    lsum += __shfl_xor(lsum, 32);

    *(f32x4*)&OLDS[w][lane][0] = o0;
    *(f32x4*)&OLDS[w][lane][4] = o1;
    if (lane < 16) lred[w][lane] = lsum;
    __syncthreads();

    if (tid < 64) {
        float iv[4];
        #pragma unroll
        for (int r = 0; r < 4; ++r) {
            float s = lred[0][bb + r];
            #pragma unroll
            for (int ww = 1; ww < 8; ++ww) s += lred[ww][bb + r];
            iv[r] = 1.f / s;
        }
        f32x4 a0 = *(f32x4*)&OLDS[0][lane][0];
        f32x4 a1 = *(f32x4*)&OLDS[0][lane][4];
        #pragma unroll
        for (int ww = 1; ww < 8; ++ww) {
            a0 += *(f32x4*)&OLDS[ww][lane][0];
            a1 += *(f32x4*)&OLDS[ww][lane][4];
        }
        #pragma unroll
        for (int r = 0; r < 4; ++r) {
            size_t base = ((size_t)b * 2048 + r0w + bb + r) * 128 + h * 32;
            Ob[base + c]      = (short)bf16bits(a0[r] * iv[r]);
            Ob[base + 16 + c] = (short)bf16bits(a1[r] * iv[r]);
        }
    }
}

// ---------------------------------------------------------------------------
// Graph adjacency + fused top-k + masked re-softmax -> bf16 ADJb.
// (unchanged from round 6; frozen numerics)
// ---------------------------------------------------------------------------
__global__ __launch_bounds__(512, 4) void gadjtopk_k(
    const float* __restrict__ Kg, const float* __restrict__ QgT,
    __hip_bfloat16* __restrict__ ADJb)
{
    __shared__ float kg_s[8][32];
    __shared__ float scores[8][2048];

    const int tid = threadIdx.x;
    const int wg = blockIdx.x;     // 0..511
    const int b = wg >> 8;
    const int r0 = (wg & 255) << 3;

    if (tid < 256) {
        int rr = tid >> 5, d = tid & 31;
        kg_s[rr][d] = Kg[((size_t)b * 2048 + r0 + rr) * 32 + d];
    }
    __syncthreads();

    const float* Qp = QgT + (size_t)b * 32 * 2048;
    float acc[8][4];
    #pragma unroll
    for (int rr = 0; rr < 8; ++rr)
        #pragma unroll
        for (int s = 0; s < 4; ++s) acc[rr][s] = 0.f;

    for (int dd = 0; dd < 32; ++dd) {
        float qv[8];
        #pragma unroll
        for (int rr = 0; rr < 8; ++rr) qv[rr] = kg_s[rr][dd];
        const float* kp = Qp + (size_t)dd * 2048 + tid;
        #pragma unroll
        for (int s = 0; s < 4; ++s) {
            float kv = kp[s * 512];
            #pragma unroll
            for (int rr = 0; rr < 8; ++rr)
                acc[rr][s] = fmaf(qv[rr], kv, acc[rr][s]);
        }
    }
    #pragma unroll
    for (int s = 0; s < 4; ++s) {
        int jj = tid + 512 * s;
        #pragma unroll
        for (int rr = 0; rr < 8; ++rr) scores[rr][jj] = acc[rr][s];
    }
    __syncthreads();

    const int lane = tid & 63, w = tid >> 6;

    float mx = -3.0e38f;
    #pragma unroll
    for (int i = 0; i < 32; ++i) mx = fmaxf(mx, scores[w][lane + i * 64]);
    mx = wave_max_f(mx);

    float sm0 = 0.f;
    #pragma unroll
    for (int i = 0; i < 32; ++i) {
        float p = expf(scores[w][lane + i * 64] - mx);
        scores[w][lane + i * 64] = p;
        sm0 += p;
    }
    sm0 = wave_sum_f(sm0);
    const float ivw = 1.f / sm0;

    unsigned k_[32];
    float mxp = 0.f, mnp = 3.0e38f;
    #pragma unroll
    for (int i = 0; i < 32; ++i) {
        float p = scores[w][lane + i * 64] * ivw;
        k_[i] = __float_as_uint(p);
        mxp = fmaxf(mxp, p);
        mnp = fminf(mnp, p);
    }
    mxp = wave_max_f(mxp);
    mnp = wave_min_f(mnp);

    unsigned thr = __float_as_uint(mnp);
    const unsigned umax = __float_as_uint(mxp);
    const unsigned diff = thr ^ umax;
    if (diff != 0u) {
        const int hb = 31 - __builtin_clz(diff);
        thr = (umax >> (hb + 1)) << (hb + 1);   // common prefix of [min,max]
        for (int bit = hb; bit >= 0; --bit) {
            unsigned cand = thr | (1u << bit);
            int cnt = 0;
            #pragma unroll
            for (int i = 0; i < 32; ++i)
                cnt += (int)__popcll(__ballot(k_[i] >= cand));
            if (cnt == KK_TOP) { thr = cand; break; }
            if (cnt > KK_TOP) thr = cand;
        }
    }

    int gt_c = 0;
    #pragma unroll
    for (int i = 0; i < 32; ++i)
        gt_c += (int)__popcll(__ballot(k_[i] > thr));
    const int need = KK_TOP - gt_c;

    unsigned keepmask = 0u;
    int running = 0;
    const unsigned long long ltmask = (lane == 0) ? 0ull : (~0ull >> (64 - lane));
    #pragma unroll
    for (int i = 0; i < 32; ++i) {
        bool tie = (k_[i] == thr);
        unsigned long long bal = __ballot(tie);
        int before = running + (int)__popcll(bal & ltmask);
        bool keep = (k_[i] > thr) || (tie && before < need);
        running += (int)__popcll(bal);
        if (keep) keepmask |= (1u << i);
    }

    const float LOG2E = 1.4426950408889634f;
    float sm = 0.f;
    #pragma unroll
    for (int i = 0; i < 32; ++i)
        if ((keepmask >> i) & 1u)
            sm += exp2f((__uint_as_float(k_[i]) - mxp) * LOG2E);
    sm = wave_sum_f(sm);
    const float ivs = 1.f / sm;

    __hip_bfloat16* rp = ADJb + (size_t)(b * 2048 + r0 + w) * 2048;
    #pragma unroll
    for (int i = 0; i < 32; ++i) {
        float o = ((keepmask >> i) & 1u)
                    ? exp2f((__uint_as_float(k_[i]) - mxp) * LOG2E) * ivs : 0.f;
        rp[lane + i * 64] = __float2bfloat16(o);
    }
}

// ---------------------------------------------------------------------------
// Final GEMM (MFMA), 8-wave K-split, 2-way col-split.
// ---------------------------------------------------------------------------
__global__ __launch_bounds__(512, 8) void outgemm_mfma_k(
    const short* __restrict__ ADJb, const short* __restrict__ SUPt,
    const float* __restrict__ gcb, float* __restrict__ OUT)
{
    __shared__ __align__(16) float OL[8][64][16];
    const int tid = threadIdx.x;
    const int w = tid >> 6, lane = tid & 63;
    const int g = lane >> 4, c = lane & 15;
    const int r0w = blockIdx.x * 16;          // 0..4080 (global row incl. batch)
    const int n0 = blockIdx.y * 64;
    const int b = r0w >> 11;
    const short* Bp = SUPt + (size_t)b * 128 * 2048;

    f32x4 acc[4];
    #pragma unroll
    for (int f = 0; f < 4; ++f) acc[f] = (f32x4){0.f, 0.f, 0.f, 0.f};

    #pragma unroll 2
    for (int i = 0; i < 8; ++i) {
        const int k0 = w * 256 + i * 32;
        v8s af = *(const v8s*)(ADJb + (size_t)(r0w + c) * 2048 + k0 + g * 8);
        #pragma unroll
        for (int f = 0; f < 4; ++f) {
            v8s bf_ = *(const v8s*)(Bp + (size_t)(n0 + f * 16 + c) * 2048 + k0 + g * 8);
            acc[f] = MFMA16(af, bf_, acc[f]);
        }
    }

    #pragma unroll
    for (int f = 0; f < 4; ++f) *(f32x4*)&OL[w][lane][f * 4] = acc[f];
    __syncthreads();

    #pragma unroll
    for (int u = 0; u < 2; ++u) {
        int idx = tid + u * 512;        // 0..1023
        int ls = idx >> 4, s = idx & 15;
        float v = OL[0][ls][s];
        #pragma unroll
        for (int ww = 1; ww < 8; ++ww) v += OL[ww][ls][s];
        int f = s >> 2, r = s & 3;
        int row = r0w + 4 * (ls >> 4) + r;
        int col = n0 + f * 16 + (ls & 15);
        OUT[(size_t)row * 128 + col] = v + gcb[col];
    }
}

// ---------------------------------------------------------------------------
extern "C" void kernel_launch(void* const* d_in, const int* in_sizes, int n_in,
                              void* d_out, int out_size, void* d_ws, size_t ws_size,
                              hipStream_t stream)
{
    const float* x       = (const float*)d_in[0];
    const int*   A       = (const int*)d_in[1];
    const float* q_w1    = (const float*)d_in[2];
    const float* kv_w1   = (const float*)d_in[3];
    const float* proj_w1 = (const float*)d_in[4];
    const float* proj_b1 = (const float*)d_in[5];
    const float* q_w2    = (const float*)d_in[6];
    const float* kv_w2   = (const float*)d_in[7];
    const float* proj_w2 = (const float*)d_in[8];
    const float* proj_b2 = (const float*)d_in[9];
    const float* cq_w    = (const float*)d_in[10];
    const float* cq_b    = (const float*)d_in[11];
    const float* ck_w    = (const float*)d_in[12];
    const float* ck_b    = (const float*)d_in[13];
    const float* cv_w    = (const float*)d_in[14];
    const float* cv_b    = (const float*)d_in[15];
    const float* gc_w    = (const float*)d_in[16];
    const float* gc_b    = (const float*)d_in[17];
    float* out = (float*)d_out;

    // Workspace layout (bytes, 256-aligned). Total ~30.2 MB.
    char* ws = (char*)d_ws;
    short*          Qb   = (short*)         (ws + 0);          // 1 MB bf16
    short*          Kb   = (short*)         (ws + 1048576);    // 1 MB bf16
    short*          Vt   = (short*)         (ws + 2097152);    // 1 MB bf16
    __hip_bfloat16* ADJb = (__hip_bfloat16*)(ws + 3145728);    // 16 MB
    unsigned*       Ab2  = (unsigned*)      (ws + 19922944);   // 512 KB
    short*          Ob   = (short*)         (ws + 20447232);   // 1 MB bf16
    float*          X1   = (float*)         (ws + 21495808);   // 2 MB f32
    short*          X1b  = (short*)         (ws + 23592960);   // 1 MB bf16
    float*          X2   = (float*)         (ws + 24641536);   // 2 MB f32
    float*          QgT  = (float*)         (ws + 26738688);   // 512 KB
    float*          Kg   = (float*)         (ws + 27262976);   // 512 KB
    __hip_bfloat16* SUPt = (__hip_bfloat16*)(ws + 27787264);   // 1 MB
    float*          MT   = (float*)         (ws + 28835840);   // 64 KB
    float*          B2   = (float*)         (ws + 28901376);   // 512 B
    short*          xb   = (short*)         (ws + 28901888);   // 1 MB bf16
    short*          WALLb= (short*)         (ws + 29950464);   // 256 KB bf16

    dim3 blk(256);
    dim3 blk512(512);

    hipLaunchKernelGGL(prep_k, dim3(656), blk, 0, stream,
                       A, Ab2, cv_w, cv_b, gc_w, MT, B2,
                       x, xb, q_w1, kv_w1, proj_w1, q_w2, kv_w2, proj_w2, WALLb);

    // ---- attention block 1 ----
    hipLaunchKernelGGL((mfma_gemm_k<MODE_QKV, false>), dim3(64, 6), blk, 0, stream,
                       xb, WALLb, nullptr, nullptr, Qb, Kb, Vt, nullptr, nullptr);
    hipLaunchKernelGGL(attn_mfma_k, dim3(1024), blk512, 0, stream,
                       Qb, Kb, Vt, Ab2, Ob);
    hipLaunchKernelGGL((mfma_gemm_k<MODE_PROJ, true>), dim3(64, 2), blk, 0, stream,
                       Ob, WALLb + 49152, proj_b1, x, nullptr, nullptr, nullptr, X1, X1b);

    // ---- attention block 2 ----
    hipLaunchKernelGGL((mfma_gemm_k<MODE_QKV, false>), dim3(64, 6), blk, 0, stream,
                       X1b, WALLb + 65536, nullptr, nullptr, Qb, Kb, Vt, nullptr, nullptr);
    hipLaunchKernelGGL(attn_mfma_k, dim3(1024), blk512, 0, stream,
                       Qb, Kb, Vt, Ab2, Ob);
    hipLaunchKernelGGL((mfma_gemm_k<MODE_PROJ, false>), dim3(64, 2), blk, 0, stream,
                       Ob, WALLb + 114688, proj_b2, X1, nullptr, nullptr, nullptr, X2, nullptr);

    // ---- graph conv ----
    hipLaunchKernelGGL(graphmm_k, dim3(64, 6), blk, 0, stream,
                       X2, cq_w, cq_b, ck_w, ck_b, MT, B2, QgT, Kg, SUPt);
    hipLaunchKernelGGL(gadjtopk_k, dim3(512), blk512, 0, stream, Kg, QgT, ADJb);
    hipLaunchKernelGGL(outgemm_mfma_k, dim3(256, 2), blk512, 0, stream,
                       (const short*)ADJb, (const short*)SUPt, gc_b, out);
}

// Round 9
// 275.893 us; speedup vs baseline: 3.0654x; 1.0072x over previous
//
#include <hip/hip_runtime.h>
#include <hip/hip_bf16.h>
#include <math.h>

#define KK_TOP 1365   // int(2048/3*2)

typedef __attribute__((ext_vector_type(8))) short v8s;
typedef __attribute__((ext_vector_type(4))) float f32x4;

#define MFMA16(a, b, c) __builtin_amdgcn_mfma_f32_16x16x32_bf16(a, b, c, 0, 0, 0)

__device__ inline float wave_max_f(float v) {
    #pragma unroll
    for (int m = 1; m < 64; m <<= 1) v = fmaxf(v, __shfl_xor(v, m));
    return v;
}
__device__ inline float wave_min_f(float v) {
    #pragma unroll
    for (int m = 1; m < 64; m <<= 1) v = fminf(v, __shfl_xor(v, m));
    return v;
}
__device__ inline float wave_sum_f(float v) {
    #pragma unroll
    for (int m = 1; m < 64; m <<= 1) v += __shfl_xor(v, m);
    return v;
}
__device__ inline unsigned short bf16bits(float x) {
    __hip_bfloat16 h = __float2bfloat16(x);
    return *reinterpret_cast<unsigned short*>(&h);
}

// ---------------------------------------------------------------------------
// prep: blocks 0..511    pack mask A into row-major bitwords
//       blocks 512..575  fused support weight MT/B2
//       blocks 576..639  x (f32) -> xb (bf16)
//       blocks 640..655  6 weight matrices (f32) -> WALLb (bf16)
// ---------------------------------------------------------------------------
__global__ __launch_bounds__(256) void prep_k(
    const int* __restrict__ A, unsigned* __restrict__ Ab2,
    const float* __restrict__ cv_w, const float* __restrict__ cv_b,
    const float* __restrict__ gc_w, float* __restrict__ MT, float* __restrict__ B2,
    const float* __restrict__ x, short* __restrict__ xb,
    const float* __restrict__ q_w1, const float* __restrict__ kv_w1,
    const float* __restrict__ proj_w1, const float* __restrict__ q_w2,
    const float* __restrict__ kv_w2, const float* __restrict__ proj_w2,
    short* __restrict__ WALLb)
{
    const int bx = blockIdx.x;
    if (bx < 512) {
        const int lane = threadIdx.x & 63;
        const int w = threadIdx.x >> 6;
        const int row = bx * 4 + w;
        const int* rp = A + (size_t)row * 2048;
        for (int i = 0; i < 32; ++i) {
            unsigned long long bal = __ballot(rp[i * 64 + lane] > 0);
            if (lane == 0)  Ab2[(size_t)row * 64 + 2 * i]     = (unsigned)bal;
            if (lane == 32) Ab2[(size_t)row * 64 + 2 * i + 1] = (unsigned)(bal >> 32);
        }
    } else if (bx < 576) {
        const int b2 = bx - 512;
        const int c = b2 * 2 + (threadIdx.x >> 7);
        const int k = threadIdx.x & 127;
        float a = 0.f;
        #pragma unroll 4
        for (int i = 0; i < 128; ++i)
            a += cv_w[(size_t)i * 128 + k] * gc_w[(size_t)i * 128 + c];
        MT[(size_t)c * 128 + k] = a;
        if (b2 == 0 && threadIdx.x < 128) {
            float s = 0.f;
            #pragma unroll 4
            for (int i = 0; i < 128; ++i)
                s += cv_b[i] * gc_w[(size_t)i * 128 + threadIdx.x];
            B2[threadIdx.x] = s;
        }
    } else if (bx < 640) {
        const size_t base = (size_t)(bx - 576) * 8192;
        #pragma unroll 8
        for (int i = 0; i < 32; ++i) {
            size_t e = base + threadIdx.x + i * 256;
            xb[e] = (short)bf16bits(x[e]);
        }
    } else {
        const int base = (bx - 640) * 8192;
        const float* src; int off;
        if (base < 16384)       { src = q_w1;    off = base; }
        else if (base < 49152)  { src = kv_w1;   off = base - 16384; }
        else if (base < 65536)  { src = proj_w1; off = base - 49152; }
        else if (base < 81920)  { src = q_w2;    off = base - 65536; }
        else if (base < 114688) { src = kv_w2;   off = base - 81920; }
        else                    { src = proj_w2; off = base - 114688; }
        short* dst = WALLb + base;
        #pragma unroll 8
        for (int i = 0; i < 32; ++i) {
            int e = threadIdx.x + i * 256;
            dst[e] = (short)bf16bits(src[off + e]);
        }
    }
}

// ---------------------------------------------------------------------------
// MFMA GEMM for the K=128 projections (unchanged from round 7).
// ---------------------------------------------------------------------------
enum { MODE_QKV = 0, MODE_PROJ = 1 };

template <int MODE, bool EMITB>
__global__ __launch_bounds__(256) void mfma_gemm_k(
    const short* __restrict__ Xb, const short* __restrict__ Wb,
    const float* __restrict__ bias, const float* __restrict__ resid,
    short* __restrict__ Qo, short* __restrict__ Ko, short* __restrict__ Vto,
    float* __restrict__ Fo, short* __restrict__ Bo)
{
    const int tid = threadIdx.x;
    const int w = tid >> 6, lane = tid & 63;
    const int g = lane >> 4, c = lane & 15;
    const int m0 = blockIdx.x * 64 + w * 16;
    const int nbase = blockIdx.y * 64;

    v8s af[4];
    #pragma unroll
    for (int kk = 0; kk < 4; ++kk)
        af[kk] = *(const v8s*)(Xb + (size_t)(m0 + c) * 128 + kk * 32 + g * 8);

    for (int nf = 0; nf < 4; ++nf) {
        const int n0 = nbase + nf * 16;
        f32x4 acc = {0.f, 0.f, 0.f, 0.f};
        #pragma unroll
        for (int kk = 0; kk < 4; ++kk) {
            v8s bfr = *(const v8s*)(Wb + (size_t)(n0 + c) * 128 + kk * 32 + g * 8);
            acc = MFMA16(af[kk], bfr, acc);
        }
        const int ccol = n0 + c;
        #pragma unroll
        for (int r = 0; r < 4; ++r) {
            const int m = m0 + 4 * g + r;
            const int b = m >> 11, n = m & 2047;
            if (MODE == MODE_QKV) {
                unsigned short hv = bf16bits(acc[r]);
                if (ccol < 128) {
                    int hh = ccol >> 5, d = ccol & 31;
                    Qo[((size_t)(b * 4 + hh) * 2048 + n) * 32 + d] = (short)hv;
                } else if (ccol < 256) {
                    int c2 = ccol - 128; int hh = c2 >> 5, d = c2 & 31;
                    Ko[((size_t)(b * 4 + hh) * 2048 + n) * 32 + d] = (short)hv;
                } else {
                    int c2 = ccol - 256; int hh = c2 >> 5, d = c2 & 31;
                    Vto[((size_t)(b * 4 + hh) * 32 + d) * 2048 + n] = (short)hv;
                }
            } else {
                float v = acc[r] + bias[ccol] + resid[(size_t)m * 128 + ccol];
                Fo[(size_t)m * 128 + ccol] = v;
                if (EMITB) Bo[(size_t)m * 128 + ccol] = (short)bf16bits(v);
            }
        }
    }
}

// ---------------------------------------------------------------------------
// Merged QG + KG + SUP GEMM on X2 (frozen f32 numerics; unchanged).
// ---------------------------------------------------------------------------
__global__ __launch_bounds__(256) void graphmm_k(
    const float* __restrict__ X, const float* __restrict__ cq_w,
    const float* __restrict__ cq_b, const float* __restrict__ ck_w,
    const float* __restrict__ ck_b, const float* __restrict__ MT,
    const float* __restrict__ B2, float* __restrict__ QgT,
    float* __restrict__ Kg, __hip_bfloat16* __restrict__ SUPt)
{
    __shared__ __align__(16) float Xs[64][132];
    __shared__ __align__(16) float Ws[32][132];
    const int tid = threadIdx.x;
    const int m0 = blockIdx.x * 64;
    const int y = blockIdx.y;
    const float* W0   = (y == 0) ? cq_w : (y == 1) ? ck_w : MT;
    const float* bias = (y == 0) ? cq_b : (y == 1) ? ck_b : B2;
    const int n0 = (y < 2) ? 0 : (y - 2) * 32;

    #pragma unroll
    for (int i = 0; i < 32; ++i) {
        int idx = tid + i * 256;
        int row = idx >> 7, col = idx & 127;
        Xs[row][col] = X[(size_t)(m0 + row) * 128 + col];
    }
    #pragma unroll
    for (int i = 0; i < 16; ++i) {
        int idx = tid + i * 256;
        int r = idx >> 7, col = idx & 127;
        Ws[r][col] = W0[(size_t)(n0 + r) * 128 + col];
    }
    __syncthreads();

    const int r = tid >> 4;
    const int c = tid & 15;
    float acc[4][2] = {{0.f, 0.f}, {0.f, 0.f}, {0.f, 0.f}, {0.f, 0.f}};

    #pragma unroll
    for (int k = 0; k < 128; k += 4) {
        float4 w0 = *(const float4*)&Ws[c][k];
        float4 w1 = *(const float4*)&Ws[c + 16][k];
        #pragma unroll
        for (int i = 0; i < 4; ++i) {
            float4 xv = *(const float4*)&Xs[r + 16 * i][k];
            acc[i][0] += xv.x * w0.x + xv.y * w0.y + xv.z * w0.z + xv.w * w0.w;
            acc[i][1] += xv.x * w1.x + xv.y * w1.y + xv.z * w1.z + xv.w * w1.w;
        }
    }

    #pragma unroll
    for (int i = 0; i < 4; ++i) {
        int m = m0 + r + 16 * i;
        int b = m >> 11, n = m & 2047;
        #pragma unroll
        for (int jj = 0; jj < 2; ++jj) {
            int ccol = n0 + c + 16 * jj;
            float v = acc[i][jj];
            if (y == 0) {
                QgT[((size_t)b * 32 + ccol) * 2048 + n] = v + bias[ccol];
            } else if (y == 1) {
                Kg[(size_t)m * 32 + ccol] = v + bias[ccol];
            } else {
                SUPt[((size_t)b * 128 + ccol) * 2048 + n] = __float2bfloat16(v + bias[ccol]);
            }
        }
    }
}

// ---------------------------------------------------------------------------
// MFMA attention (unchanged from round 7).
// ---------------------------------------------------------------------------
__global__ __launch_bounds__(512, 8) void attn_mfma_k(
    const short* __restrict__ Qb, const short* __restrict__ Kb,
    const short* __restrict__ Vt, const unsigned* __restrict__ Ab2,
    short* __restrict__ Ob)
{
    __shared__ __align__(16) float OLDS[8][64][8];
    __shared__ float lred[8][16];

    const int tid = threadIdx.x;
    const int w = tid >> 6, lane = tid & 63;
    const int g = lane >> 4, c = lane & 15;
    const int bb = 4 * g;
    const int wg = blockIdx.x;                 // 0..1023
    const int b = wg >> 9, h = (wg >> 7) & 3, r0w = (wg & 127) << 4;
    const int bh = b * 4 + h;

    const v8s qf = *(const v8s*)(Qb + ((size_t)bh * 2048 + r0w + c) * 32 + g * 8);
    const short* Kp = Kb + (size_t)bh * 2048 * 32;
    const short* Vp = Vt + (size_t)bh * 32 * 2048;
    const unsigned* Mrow = Ab2 + (size_t)(r0w + c) * 64;

    f32x4 o0 = {0.f, 0.f, 0.f, 0.f}, o1 = {0.f, 0.f, 0.f, 0.f};
    float lsum = 0.f;
    const float SC2 = 0.25503487f;   // 32^-0.5 * log2(e)
    const bool lo = (g < 2);
    const int aA = (32 * (g & 1) + c) * 4;
    const int aB = aA + 64;

    #pragma unroll 2
    for (int t = 0; t < 8; ++t) {
        const int kt = t * 8 + w;
        const int key0 = kt * 32;
        v8s kf0 = *(const v8s*)(Kp + (size_t)(key0 + c) * 32 + g * 8);
        v8s kf1 = *(const v8s*)(Kp + (size_t)(key0 + 16 + c) * 32 + g * 8);
        unsigned mw = Mrow[kt];
        const f32x4 z = {0.f, 0.f, 0.f, 0.f};
        f32x4 s0 = MFMA16(kf0, qf, z);
        f32x4 s1 = MFMA16(kf1, qf, z);

        float p0[4], p1[4];
        #pragma unroll
        for (int r = 0; r < 4; ++r) {
            p0[r] = ((mw >> (bb + r)) & 1u)      ? exp2f(s0[r] * SC2) : 0.f;
            p1[r] = ((mw >> (16 + bb + r)) & 1u) ? exp2f(s1[r] * SC2) : 0.f;
        }
        lsum += p0[0] + p0[1] + p0[2] + p0[3] + p1[0] + p1[1] + p1[2] + p1[3];

        int w00 = (int)bf16bits(p0[0]) | ((int)bf16bits(p0[1]) << 16);
        int w01 = (int)bf16bits(p0[2]) | ((int)bf16bits(p0[3]) << 16);
        int w10 = (int)bf16bits(p1[0]) | ((int)bf16bits(p1[1]) << 16);
        int w11 = (int)bf16bits(p1[2]) | ((int)bf16bits(p1[3]) << 16);

        int e0, e1;
        union { int wv[4]; v8s v; } pf;
        e0 = __builtin_amdgcn_ds_bpermute(aA, w00);
        e1 = __builtin_amdgcn_ds_bpermute(aA, w10);
        pf.wv[0] = lo ? e0 : e1;
        e0 = __builtin_amdgcn_ds_bpermute(aA, w01);
        e1 = __builtin_amdgcn_ds_bpermute(aA, w11);
        pf.wv[1] = lo ? e0 : e1;
        e0 = __builtin_amdgcn_ds_bpermute(aB, w00);
        e1 = __builtin_amdgcn_ds_bpermute(aB, w10);
        pf.wv[2] = lo ? e0 : e1;
        e0 = __builtin_amdgcn_ds_bpermute(aB, w01);
        e1 = __builtin_amdgcn_ds_bpermute(aB, w11);
        pf.wv[3] = lo ? e0 : e1;

        v8s vf0 = *(const v8s*)(Vp + (size_t)c * 2048 + key0 + g * 8);
        v8s vf1 = *(const v8s*)(Vp + (size_t)(16 + c) * 2048 + key0 + g * 8);
        o0 = MFMA16(pf.v, vf0, o0);
        o1 = MFMA16(pf.v, vf1, o1);
    }

    lsum += __shfl_xor(lsum, 16);
    lsum += __shfl_xor(lsum, 32);

    *(f32x4*)&OLDS[w][lane][0] = o0;
    *(f32x4*)&OLDS[w][lane][4] = o1;
    if (lane < 16) lred[w][lane] = lsum;
    __syncthreads();

    if (tid < 64) {
        float iv[4];
        #pragma unroll
        for (int r = 0; r < 4; ++r) {
            float s = lred[0][bb + r];
            #pragma unroll
            for (int ww = 1; ww < 8; ++ww) s += lred[ww][bb + r];
            iv[r] = 1.f / s;
        }
        f32x4 a0 = *(f32x4*)&OLDS[0][lane][0];
        f32x4 a1 = *(f32x4*)&OLDS[0][lane][4];
        #pragma unroll
        for (int ww = 1; ww < 8; ++ww) {
            a0 += *(f32x4*)&OLDS[ww][lane][0];
            a1 += *(f32x4*)&OLDS[ww][lane][4];
        }
        #pragma unroll
        for (int r = 0; r < 4; ++r) {
            size_t base = ((size_t)b * 2048 + r0w + bb + r) * 128 + h * 32;
            Ob[base + c]      = (short)bf16bits(a0[r] * iv[r]);
            Ob[base + 16 + c] = (short)bf16bits(a1[r] * iv[r]);
        }
    }
}

// ---------------------------------------------------------------------------
// Graph adjacency + top-k + re-softmax + FUSED output GEMM.
// Phases 1-3 bit-identical to round 6/7 gadjtopk (frozen numerics). The ADJ
// row never hits HBM: it lands in a 32 KB XOR-swizzled LDS tile and is
// multiplied against SUPt in-kernel. OUT K-sum order changes (~1e-6).
// ---------------------------------------------------------------------------
__global__ __launch_bounds__(512, 4) void gadjout_k(
    const float* __restrict__ Kg, const float* __restrict__ QgT,
    const short* __restrict__ SUPt, const float* __restrict__ gcb,
    float* __restrict__ OUT)
{
    __shared__ __align__(16) float scores[8][2048];   // 64 KB; ADJ tile overlays
    __shared__ float kg_s[8][32];

    const int tid = threadIdx.x;
    const int wg = blockIdx.x;     // 0..511
    const int b = wg >> 8;
    const int r0 = (wg & 255) << 3;

    if (tid < 256) {
        int rr = tid >> 5, d = tid & 31;
        kg_s[rr][d] = Kg[((size_t)b * 2048 + r0 + rr) * 32 + d];
    }
    __syncthreads();

    // ---- phase 1: logits GEMM (frozen fmaf chains) ----
    const float* Qp = QgT + (size_t)b * 32 * 2048;
    {
        float acc[8][4];
        #pragma unroll
        for (int rr = 0; rr < 8; ++rr)
            #pragma unroll
            for (int s = 0; s < 4; ++s) acc[rr][s] = 0.f;

        for (int dd = 0; dd < 32; ++dd) {
            float qv[8];
            #pragma unroll
            for (int rr = 0; rr < 8; ++rr) qv[rr] = kg_s[rr][dd];
            const float* kp = Qp + (size_t)dd * 2048 + tid;
            #pragma unroll
            for (int s = 0; s < 4; ++s) {
                float kv = kp[s * 512];
                #pragma unroll
                for (int rr = 0; rr < 8; ++rr)
                    acc[rr][s] = fmaf(qv[rr], kv, acc[rr][s]);
            }
        }
        #pragma unroll
        for (int s = 0; s < 4; ++s) {
            int jj = tid + 512 * s;
            #pragma unroll
            for (int rr = 0; rr < 8; ++rr) scores[rr][jj] = acc[rr][s];
        }
    }
    __syncthreads();

    // ---- phases 2-3: wave w owns row r0 + w (frozen numerics) ----
    const int lane = tid & 63, w = tid >> 6;
    const int g = lane >> 4, c = lane & 15;

    float mx = -3.0e38f;
    #pragma unroll
    for (int i = 0; i < 32; ++i) mx = fmaxf(mx, scores[w][lane + i * 64]);
    mx = wave_max_f(mx);

    float sm0 = 0.f;
    #pragma unroll
    for (int i = 0; i < 32; ++i) {
        float p = expf(scores[w][lane + i * 64] - mx);
        scores[w][lane + i * 64] = p;
        sm0 += p;
    }
    sm0 = wave_sum_f(sm0);
    const float ivw = 1.f / sm0;

    unsigned k_[32];
    float mxp = 0.f, mnp = 3.0e38f;
    #pragma unroll
    for (int i = 0; i < 32; ++i) {
        float p = scores[w][lane + i * 64] * ivw;
        k_[i] = __float_as_uint(p);
        mxp = fmaxf(mxp, p);
        mnp = fminf(mnp, p);
    }
    mxp = wave_max_f(mxp);
    mnp = wave_min_f(mnp);
    __syncthreads();   // all waves done reading scores; LDS reusable as ADJ tile

    unsigned thr = __float_as_uint(mnp);
    const unsigned umax = __float_as_uint(mxp);
    const unsigned diff = thr ^ umax;
    if (diff != 0u) {
        const int hb = 31 - __builtin_clz(diff);
        thr = (umax >> (hb + 1)) << (hb + 1);   // common prefix of [min,max]
        for (int bit = hb; bit >= 0; --bit) {
            unsigned cand = thr | (1u << bit);
            int cnt = 0;
            #pragma unroll
            for (int i = 0; i < 32; ++i)
                cnt += (int)__popcll(__ballot(k_[i] >= cand));
            if (cnt == KK_TOP) { thr = cand; break; }
            if (cnt > KK_TOP) thr = cand;
        }
    }

    int gt_c = 0;
    #pragma unroll
    for (int i = 0; i < 32; ++i)
        gt_c += (int)__popcll(__ballot(k_[i] > thr));
    const int need = KK_TOP - gt_c;

    unsigned keepmask = 0u;
    int running = 0;
    const unsigned long long ltmask = (lane == 0) ? 0ull : (~0ull >> (64 - lane));
    #pragma unroll
    for (int i = 0; i < 32; ++i) {
        bool tie = (k_[i] == thr);
        unsigned long long bal = __ballot(tie);
        int before = running + (int)__popcll(bal & ltmask);
        bool keep = (k_[i] > thr) || (tie && before < need);
        running += (int)__popcll(bal);
        if (keep) keepmask |= (1u << i);
    }

    const float LOG2E = 1.4426950408889634f;
    float sm = 0.f;
    #pragma unroll
    for (int i = 0; i < 32; ++i)
        if ((keepmask >> i) & 1u)
            sm += exp2f((__uint_as_float(k_[i]) - mxp) * LOG2E);
    sm = wave_sum_f(sm);
    const float ivs = 1.f / sm;

    // ---- ADJ row -> swizzled LDS tile (ushort idx ^= (row&7)<<3) ----
    unsigned short* adjl = (unsigned short*)&scores[0][0];   // [8][2048] bf16
    const int wsw = (w & 7) << 3;
    #pragma unroll
    for (int i = 0; i < 32; ++i) {
        float o = ((keepmask >> i) & 1u)
                    ? exp2f((__uint_as_float(k_[i]) - mxp) * LOG2E) * ivs : 0.f;
        adjl[w * 2048 + ((lane + i * 64) ^ wsw)] = bf16bits(o);
    }
    __syncthreads();

    // ---- fused outgemm: OUT[r0..r0+7][cols w*16..] = ADJ @ SUPt^T ----
    const short* adjs = (const short*)adjl;
    const short* Bp = SUPt + (size_t)b * 128 * 2048;
    const int csw = (c & 7) << 3;
    f32x4 oa = {0.f, 0.f, 0.f, 0.f};
    const v8s zero8 = {0, 0, 0, 0, 0, 0, 0, 0};
    #pragma unroll 2
    for (int kf = 0; kf < 64; ++kf) {
        const int k0 = kf * 32;
        v8s af2 = (c < 8) ? *(const v8s*)(adjs + (c * 2048 + ((k0 + g * 8) ^ csw)))
                          : zero8;
        v8s bf2 = *(const v8s*)(Bp + (size_t)(w * 16 + c) * 2048 + k0 + g * 8);
        oa = MFMA16(af2, bf2, oa);
    }
    if (g < 2) {
        const int col = w * 16 + c;
        const float bias = gcb[col];
        #pragma unroll
        for (int r = 0; r < 4; ++r)
            OUT[((size_t)b * 2048 + r0 + 4 * g + r) * 128 + col] = oa[r] + bias;
    }
}

// ---------------------------------------------------------------------------
extern "C" void kernel_launch(void* const* d_in, const int* in_sizes, int n_in,
                              void* d_out, int out_size, void* d_ws, size_t ws_size,
                              hipStream_t stream)
{
    const float* x       = (const float*)d_in[0];
    const int*   A       = (const int*)d_in[1];
    const float* q_w1    = (const float*)d_in[2];
    const float* kv_w1   = (const float*)d_in[3];
    const float* proj_w1 = (const float*)d_in[4];
    const float* proj_b1 = (const float*)d_in[5];
    const float* q_w2    = (const float*)d_in[6];
    const float* kv_w2   = (const float*)d_in[7];
    const float* proj_w2 = (const float*)d_in[8];
    const float* proj_b2 = (const float*)d_in[9];
    const float* cq_w    = (const float*)d_in[10];
    const float* cq_b    = (const float*)d_in[11];
    const float* ck_w    = (const float*)d_in[12];
    const float* ck_b    = (const float*)d_in[13];
    const float* cv_w    = (const float*)d_in[14];
    const float* cv_b    = (const float*)d_in[15];
    const float* gc_w    = (const float*)d_in[16];
    const float* gc_b    = (const float*)d_in[17];
    float* out = (float*)d_out;

    // Workspace layout (bytes, 256-aligned). Same offsets as round 7
    // (ADJb slot now unused).
    char* ws = (char*)d_ws;
    short*          Qb   = (short*)         (ws + 0);          // 1 MB bf16
    short*          Kb   = (short*)         (ws + 1048576);    // 1 MB bf16
    short*          Vt   = (short*)         (ws + 2097152);    // 1 MB bf16
    unsigned*       Ab2  = (unsigned*)      (ws + 19922944);   // 512 KB
    short*          Ob   = (short*)         (ws + 20447232);   // 1 MB bf16
    float*          X1   = (float*)         (ws + 21495808);   // 2 MB f32
    short*          X1b  = (short*)         (ws + 23592960);   // 1 MB bf16
    float*          X2   = (float*)         (ws + 24641536);   // 2 MB f32
    float*          QgT  = (float*)         (ws + 26738688);   // 512 KB
    float*          Kg   = (float*)         (ws + 27262976);   // 512 KB
    __hip_bfloat16* SUPt = (__hip_bfloat16*)(ws + 27787264);   // 1 MB
    float*          MT   = (float*)         (ws + 28835840);   // 64 KB
    float*          B2   = (float*)         (ws + 28901376);   // 512 B
    short*          xb   = (short*)         (ws + 28901888);   // 1 MB bf16
    short*          WALLb= (short*)         (ws + 29950464);   // 256 KB bf16

    dim3 blk(256);
    dim3 blk512(512);

    hipLaunchKernelGGL(prep_k, dim3(656), blk, 0, stream,
                       A, Ab2, cv_w, cv_b, gc_w, MT, B2,
                       x, xb, q_w1, kv_w1, proj_w1, q_w2, kv_w2, proj_w2, WALLb);

    // ---- attention block 1 ----
    hipLaunchKernelGGL((mfma_gemm_k<MODE_QKV, false>), dim3(64, 6), blk, 0, stream,
                       xb, WALLb, nullptr, nullptr, Qb, Kb, Vt, nullptr, nullptr);
    hipLaunchKernelGGL(attn_mfma_k, dim3(1024), blk512, 0, stream,
                       Qb, Kb, Vt, Ab2, Ob);
    hipLaunchKernelGGL((mfma_gemm_k<MODE_PROJ, true>), dim3(64, 2), blk, 0, stream,
                       Ob, WALLb + 49152, proj_b1, x, nullptr, nullptr, nullptr, X1, X1b);

    // ---- attention block 2 ----
    hipLaunchKernelGGL((mfma_gemm_k<MODE_QKV, false>), dim3(64, 6), blk, 0, stream,
                       X1b, WALLb + 65536, nullptr, nullptr, Qb, Kb, Vt, nullptr, nullptr);
    hipLaunchKernelGGL(attn_mfma_k, dim3(1024), blk512, 0, stream,
                       Qb, Kb, Vt, Ab2, Ob);
    hipLaunchKernelGGL((mfma_gemm_k<MODE_PROJ, false>), dim3(64, 2), blk, 0, stream,
                       Ob, WALLb + 114688, proj_b2, X1, nullptr, nullptr, nullptr, X2, nullptr);

    // ---- graph conv ----
    hipLaunchKernelGGL(graphmm_k, dim3(64, 6), blk, 0, stream,
                       X2, cq_w, cq_b, ck_w, ck_b, MT, B2, QgT, Kg, SUPt);
    hipLaunchKernelGGL(gadjout_k, dim3(512), blk512, 0, stream,
                       Kg, QgT, (const short*)SUPt, gc_b, out);
}